// Round 2
// baseline (6857.433 us; speedup 1.0000x reference)
//
#include <hip/hip_runtime.h>
#include <hip/hip_bf16.h>
#include <math.h>

#define D_ 256
#define H_ 4
#define C_ 64

// ---------- helpers ----------
__device__ inline float lrelu(float v) { return v >= 0.f ? v : 0.2f * v; }

__device__ inline float wave_sum(float v) {
#pragma unroll
    for (int off = 32; off > 0; off >>= 1) v += __shfl_xor(v, off);
    return v;
}

// float -> order-preserving uint (for atomicMax), and back
__device__ inline unsigned enc_f(float f) {
    unsigned u = __float_as_uint(f);
    return (u & 0x80000000u) ? ~u : (u | 0x80000000u);
}
__device__ inline float dec_f(unsigned u) {
    return __uint_as_float((u & 0x80000000u) ? (u & 0x7FFFFFFFu) : ~u);
}

// bf16 bit helpers (avoid API differences)
__device__ inline unsigned short f2b(float f) {
    unsigned u = __float_as_uint(f);
    u = (u + 0x7FFFu + ((u >> 16) & 1u)) >> 16;   // round-to-nearest-even
    return (unsigned short)u;
}
__device__ inline float b2f(unsigned short u) {
    return __uint_as_float(((unsigned)u) << 16);
}

// ---------- GEMM: out[n][d] = sum_k A[n][k] * W[d][k] + bias[d] ----------
#define BM 128
#define BN 128
#define BK 16
template <bool BF16OUT>
__global__ __launch_bounds__(256) void gemm_xwt(
    const float* __restrict__ A, const float* __restrict__ W,
    const float* __restrict__ bias, void* __restrict__ outv, int Mrows)
{
    __shared__ float As[BK][BM];   // transposed tiles: [k][row]
    __shared__ float Bs[BK][BN];
    const int bm = blockIdx.x * BM;
    const int bn = blockIdx.y * BN;
    const int tid = threadIdx.x;
    const int lrow = tid >> 2;          // 0..63
    const int lcol = (tid & 3) << 2;    // 0,4,8,12
    const int tr = tid >> 4;            // 0..15
    const int tc = tid & 15;            // 0..15

    float acc[8][8];
#pragma unroll
    for (int i = 0; i < 8; i++)
#pragma unroll
        for (int j = 0; j < 8; j++) acc[i][j] = 0.f;

    for (int k0 = 0; k0 < D_; k0 += BK) {
        __syncthreads();
#pragma unroll
        for (int p = 0; p < 2; p++) {
            int row = lrow + p * 64;
            int gr = bm + row;
            float4 va = make_float4(0.f, 0.f, 0.f, 0.f);
            if (gr < Mrows) va = *(const float4*)&A[(size_t)gr * D_ + k0 + lcol];
            As[lcol + 0][row] = va.x; As[lcol + 1][row] = va.y;
            As[lcol + 2][row] = va.z; As[lcol + 3][row] = va.w;
            float4 vb = *(const float4*)&W[(size_t)(bn + row) * D_ + k0 + lcol];
            Bs[lcol + 0][row] = vb.x; Bs[lcol + 1][row] = vb.y;
            Bs[lcol + 2][row] = vb.z; Bs[lcol + 3][row] = vb.w;
        }
        __syncthreads();
#pragma unroll
        for (int kk = 0; kk < BK; kk++) {
            float a[8], b[8];
            *(float4*)&a[0] = *(const float4*)&As[kk][tr * 8];
            *(float4*)&a[4] = *(const float4*)&As[kk][tr * 8 + 4];
            *(float4*)&b[0] = *(const float4*)&Bs[kk][tc * 8];
            *(float4*)&b[4] = *(const float4*)&Bs[kk][tc * 8 + 4];
#pragma unroll
            for (int i = 0; i < 8; i++)
#pragma unroll
                for (int j = 0; j < 8; j++)
                    acc[i][j] = fmaf(a[i], b[j], acc[i][j]);
        }
    }

#pragma unroll
    for (int i = 0; i < 8; i++) {
        int gr = bm + tr * 8 + i;
        if (gr >= Mrows) break;
#pragma unroll
        for (int j = 0; j < 8; j += 4) {
            int gc = bn + tc * 8 + j;
            float v0 = acc[i][j + 0] + bias[gc + 0];
            float v1 = acc[i][j + 1] + bias[gc + 1];
            float v2 = acc[i][j + 2] + bias[gc + 2];
            float v3 = acc[i][j + 3] + bias[gc + 3];
            if (BF16OUT) {
                ushort4 u;
                u.x = f2b(v0); u.y = f2b(v1); u.z = f2b(v2); u.w = f2b(v3);
                *(ushort4*)&((unsigned short*)outv)[(size_t)gr * D_ + gc] = u;
            } else {
                float4 v = make_float4(v0, v1, v2, v3);
                *(float4*)&((float*)outv)[(size_t)gr * D_ + gc] = v;
            }
        }
    }
}

// ---------- per-node logit parts ----------
// ai[m][n][h] = dot(lrelu(r[n,h,:]), attn[m,h,:C])
// aj[m][n][h] = dot(lrelu(l[n,h,:]), attn[m,h,C:])
// al[n][h]    = dot(r[n,h,:], rel_l[h,:])
// ld[n][h]    = dot(l[n,h,:], rel_r[h,:])
// rd[n][h]    = dot(r[n,h,:], rel_r[h,:])
__global__ __launch_bounds__(256) void node_logits(
    const unsigned short* __restrict__ l, const float* __restrict__ r,
    const float* __restrict__ attn, const float* __restrict__ rel_l,
    const float* __restrict__ rel_r,
    float* __restrict__ ai, float* __restrict__ aj, float* __restrict__ al,
    float* __restrict__ ld, float* __restrict__ rd, int Nn)
{
    int n = blockIdx.x;
    int t = threadIdx.x;
    int h = t >> 6, c = t & 63;
    float lv = b2f(l[(size_t)n * D_ + t]);
    float rv = r[(size_t)n * D_ + t];
    float lr_r = lrelu(rv);
    float lr_l = lrelu(lv);
    float wrr = rel_r[h * C_ + c];
    float v0 = lr_r * attn[(0 * H_ + h) * 128 + c];        // ai m=0
    float v1 = lr_r * attn[(1 * H_ + h) * 128 + c];        // ai m=1
    float v2 = lr_l * attn[(0 * H_ + h) * 128 + 64 + c];   // aj m=0
    float v3 = lr_l * attn[(1 * H_ + h) * 128 + 64 + c];   // aj m=1
    float v4 = rv * rel_l[h * C_ + c];
    float v5 = lv * wrr;
    float v6 = rv * wrr;
    v0 = wave_sum(v0); v1 = wave_sum(v1); v2 = wave_sum(v2);
    v3 = wave_sum(v3); v4 = wave_sum(v4); v5 = wave_sum(v5);
    v6 = wave_sum(v6);
    if (c == 0) {
        int NH = Nn * H_;
        int nh = n * H_ + h;
        ai[0 * NH + nh] = v0;
        ai[1 * NH + nh] = v1;
        aj[0 * NH + nh] = v2;
        aj[1 * NH + nh] = v3;
        al[nh] = v4;
        ld[nh] = v5;
        rd[nh] = v6;
    }
}

// ---------- edge pass 1: segment max ----------
__global__ __launch_bounds__(256) void edge_max(
    const int* __restrict__ ei, const float* __restrict__ ai_m,
    const float* __restrict__ aj_m, unsigned* __restrict__ mx_m, int E_)
{
    int e = blockIdx.x * blockDim.x + threadIdx.x;
    if (e >= E_) return;
    int s = ei[e], t = ei[E_ + e];
    float4 av = *(const float4*)&ai_m[(size_t)t * H_];
    float4 bv = *(const float4*)&aj_m[(size_t)s * H_];
    float lg[4] = { av.x + bv.x, av.y + bv.y, av.z + bv.z, av.w + bv.w };
#pragma unroll
    for (int h = 0; h < H_; h++)
        atomicMax(&mx_m[(size_t)t * H_ + h], enc_f(lg[h]));
}

// ---------- edge pass 2: segment sum of exp ----------
__global__ __launch_bounds__(256) void edge_den(
    const int* __restrict__ ei, const float* __restrict__ ai_m,
    const float* __restrict__ aj_m, const unsigned* __restrict__ mx_m,
    float* __restrict__ den_m, int E_)
{
    int e = blockIdx.x * blockDim.x + threadIdx.x;
    if (e >= E_) return;
    int s = ei[e], t = ei[E_ + e];
    float4 av = *(const float4*)&ai_m[(size_t)t * H_];
    float4 bv = *(const float4*)&aj_m[(size_t)s * H_];
    float lg[4] = { av.x + bv.x, av.y + bv.y, av.z + bv.z, av.w + bv.w };
#pragma unroll
    for (int h = 0; h < H_; h++) {
        float mx = dec_f(mx_m[(size_t)t * H_ + h]);
        atomicAdd(&den_m[(size_t)t * H_ + h], __expf(lg[h] - mx));
    }
}

// ---------- edge pass 3: p_m[t][h] += alpha * ld[s][h]  (cheap scalar) ----------
__global__ __launch_bounds__(256) void edge_p(
    const int* __restrict__ ei, const float* __restrict__ ai_m,
    const float* __restrict__ aj_m, const unsigned* __restrict__ mx_m,
    const float* __restrict__ den_m, const float* __restrict__ ld,
    float* __restrict__ p_m, int E_)
{
    int e = blockIdx.x * blockDim.x + threadIdx.x;
    if (e >= E_) return;
    int s = ei[e], t = ei[E_ + e];
    float4 av = *(const float4*)&ai_m[(size_t)t * H_];
    float4 bv = *(const float4*)&aj_m[(size_t)s * H_];
    float4 dv = *(const float4*)&den_m[(size_t)t * H_];
    float4 lv = *(const float4*)&ld[(size_t)s * H_];
    float lg[4] = { av.x + bv.x, av.y + bv.y, av.z + bv.z, av.w + bv.w };
    float dn[4] = { dv.x, dv.y, dv.z, dv.w };
    float lw[4] = { lv.x, lv.y, lv.z, lv.w };
#pragma unroll
    for (int h = 0; h < H_; h++) {
        float mx = dec_f(mx_m[(size_t)t * H_ + h]);
        float alpha = __expf(lg[h] - mx) / (dn[h] + 1e-16f);
        atomicAdd(&p_m[(size_t)t * H_ + h], alpha * lw[h]);
    }
}

// ---------- node beta: softmax over 3 relations; fold 1/den into wm ----------
__global__ __launch_bounds__(256) void node_beta(
    const float* __restrict__ al, const float* __restrict__ p,
    const float* __restrict__ rd, const float* __restrict__ den,
    float* __restrict__ wm, float* __restrict__ beta2, int NH)
{
    int nh = blockIdx.x * blockDim.x + threadIdx.x;
    if (nh >= NH) return;
    float a = al[nh];
    float b0 = lrelu(a + p[nh]);
    float b1 = lrelu(a + p[NH + nh]);
    float b2 = lrelu(a + rd[nh]);
    float m = fmaxf(b0, fmaxf(b1, b2));
    float e0 = __expf(b0 - m), e1 = __expf(b1 - m), e2 = __expf(b2 - m);
    float inv = 1.f / (e0 + e1 + e2);
    wm[nh]      = (e0 * inv) / (den[nh] + 1e-16f);
    wm[NH + nh] = (e1 * inv) / (den[NH + nh] + 1e-16f);
    beta2[nh]   = e2 * inv;
}

// ---------- scale r (in d_out) by beta2, in place ----------
__global__ __launch_bounds__(256) void scale_r(
    float* __restrict__ out, const float* __restrict__ beta2, size_t ND)
{
    size_t i = (size_t)blockIdx.x * blockDim.x + threadIdx.x;
    if (i >= ND) return;
    out[i] *= beta2[i >> 6];
}

// ---------- fused final aggregation: out[t] += exp(lg-mx)*wm[t,h] * l[s] ----------
__global__ __launch_bounds__(256) void edge_final(
    const int* __restrict__ ei, const float* __restrict__ ai_m,
    const float* __restrict__ aj_m, const unsigned* __restrict__ mx_m,
    const float* __restrict__ wm_m, const unsigned short* __restrict__ l,
    float* __restrict__ out, int E_)
{
    int lane = threadIdx.x & 63;
    int e = blockIdx.x * 4 + (threadIdx.x >> 6);
    if (e >= E_) return;
    int s = ei[e], t = ei[E_ + e];
    int h = lane >> 4;   // (lane*4)/64
    float lg = ai_m[(size_t)t * H_ + h] + aj_m[(size_t)s * H_ + h];
    float mx = dec_f(mx_m[(size_t)t * H_ + h]);
    float w = __expf(lg - mx) * wm_m[(size_t)t * H_ + h];
    ushort4 lv = *(const ushort4*)&l[(size_t)s * D_ + lane * 4];
    float* ob = &out[(size_t)t * D_ + lane * 4];
    atomicAdd(ob + 0, b2f(lv.x) * w);
    atomicAdd(ob + 1, b2f(lv.y) * w);
    atomicAdd(ob + 2, b2f(lv.z) * w);
    atomicAdd(ob + 3, b2f(lv.w) * w);
}

// ---------- final relu, in place ----------
__global__ __launch_bounds__(256) void relu_inplace(float* __restrict__ out, size_t ND)
{
    size_t i = (size_t)blockIdx.x * blockDim.x + threadIdx.x;
    if (i >= ND) return;
    out[i] = fmaxf(out[i], 0.f);
}

extern "C" void kernel_launch(void* const* d_in, const int* in_sizes, int n_in,
                              void* d_out, int out_size, void* d_ws, size_t ws_size,
                              hipStream_t stream) {
    const float* x     = (const float*)d_in[0];
    const int*   ei0   = (const int*)d_in[1];
    const int*   ei1   = (const int*)d_in[2];
    const float* W_l   = (const float*)d_in[3];
    const float* b_l   = (const float*)d_in[4];
    const float* W_r   = (const float*)d_in[5];
    const float* b_r   = (const float*)d_in[6];
    const float* attn  = (const float*)d_in[7];
    const float* rel_l = (const float*)d_in[8];
    const float* rel_r = (const float*)d_in[9];
    float* out = (float*)d_out;   // holds r, then beta2*r + aggregation, then relu

    const int Nn = in_sizes[0] / D_;        // 100000
    const int E_ = in_sizes[1] / 2;         // 800000
    const size_t ND = (size_t)Nn * D_;
    const int NH = Nn * H_;

    // ---- workspace layout (bytes): total = ND*2 + 16*NH*4 ≈ 77 MB ----
    char* base = (char*)d_ws;
    unsigned short* l = (unsigned short*)base;            size_t off = ND * 2;
    unsigned* mx = (unsigned*)(base + off);               off += (size_t)2 * NH * 4;  // [M][N][H]
    float* den   = (float*)(base + off);                  off += (size_t)2 * NH * 4;
    float* p     = (float*)(base + off);                  off += (size_t)2 * NH * 4;
    float* ai    = (float*)(base + off);                  off += (size_t)2 * NH * 4;
    float* aj    = (float*)(base + off);                  off += (size_t)2 * NH * 4;
    float* al    = (float*)(base + off);                  off += (size_t)NH * 4;
    float* ld    = (float*)(base + off);                  off += (size_t)NH * 4;
    float* rd    = (float*)(base + off);                  off += (size_t)NH * 4;
    float* wm    = (float*)(base + off);                  off += (size_t)2 * NH * 4;
    float* beta2 = (float*)(base + off);                  off += (size_t)NH * 4;

    // zero the atomically-accumulated region: mx, den, p (contiguous)
    hipMemsetAsync(mx, 0, (size_t)6 * NH * 4, stream);

    dim3 gg((Nn + BM - 1) / BM, D_ / BN);
    gemm_xwt<true ><<<gg, 256, 0, stream>>>(x, W_l, b_l, l, Nn);    // l -> bf16 ws
    gemm_xwt<false><<<gg, 256, 0, stream>>>(x, W_r, b_r, out, Nn);  // r -> d_out

    node_logits<<<Nn, 256, 0, stream>>>(l, out, attn, rel_l, rel_r,
                                        ai, aj, al, ld, rd, Nn);

    int eb = (E_ + 255) / 256;
    for (int m = 0; m < 2; m++) {
        const int* ei = m ? ei1 : ei0;
        edge_max<<<eb, 256, 0, stream>>>(ei, ai + (size_t)m * NH, aj + (size_t)m * NH,
                                         mx + (size_t)m * NH, E_);
    }
    for (int m = 0; m < 2; m++) {
        const int* ei = m ? ei1 : ei0;
        edge_den<<<eb, 256, 0, stream>>>(ei, ai + (size_t)m * NH, aj + (size_t)m * NH,
                                         mx + (size_t)m * NH, den + (size_t)m * NH, E_);
    }
    for (int m = 0; m < 2; m++) {
        const int* ei = m ? ei1 : ei0;
        edge_p<<<eb, 256, 0, stream>>>(ei, ai + (size_t)m * NH, aj + (size_t)m * NH,
                                       mx + (size_t)m * NH, den + (size_t)m * NH,
                                       ld, p + (size_t)m * NH, E_);
    }

    node_beta<<<(NH + 255) / 256, 256, 0, stream>>>(al, p, rd, den, wm, beta2, NH);
    scale_r<<<(int)((ND + 255) / 256), 256, 0, stream>>>(out, beta2, ND);

    for (int m = 0; m < 2; m++) {
        const int* ei = m ? ei1 : ei0;
        edge_final<<<(E_ + 3) / 4, 256, 0, stream>>>(ei, ai + (size_t)m * NH,
                                                     aj + (size_t)m * NH,
                                                     mx + (size_t)m * NH,
                                                     wm + (size_t)m * NH,
                                                     l, out, E_);
    }

    relu_inplace<<<(int)((ND + 255) / 256), 256, 0, stream>>>(out, ND);
}

// Round 3
// 929.842 us; speedup vs baseline: 7.3748x; 7.3748x over previous
//
#include <hip/hip_runtime.h>
#include <hip/hip_bf16.h>
#include <math.h>

#define D_ 256
#define H_ 4
#define C_ 64

// ---------- helpers ----------
__device__ inline float lrelu(float v) { return v >= 0.f ? v : 0.2f * v; }

__device__ inline float wave_sum(float v) {
#pragma unroll
    for (int off = 32; off > 0; off >>= 1) v += __shfl_xor(v, off);
    return v;
}

// bf16 bit helpers
__device__ inline unsigned short f2b(float f) {
    unsigned u = __float_as_uint(f);
    u = (u + 0x7FFFu + ((u >> 16) & 1u)) >> 16;   // round-to-nearest-even
    return (unsigned short)u;
}
__device__ inline float b2f(unsigned short u) {
    return __uint_as_float(((unsigned)u) << 16);
}

// ---------- GEMM: out[n][d] = sum_k A[n][k] * W[d][k] + bias[d] ----------
#define BM 128
#define BN 128
#define BK 16
template <bool BF16OUT>
__global__ __launch_bounds__(256) void gemm_xwt(
    const float* __restrict__ A, const float* __restrict__ W,
    const float* __restrict__ bias, void* __restrict__ outv, int Mrows)
{
    __shared__ float As[BK][BM];   // transposed tiles: [k][row]
    __shared__ float Bs[BK][BN];
    const int bm = blockIdx.x * BM;
    const int bn = blockIdx.y * BN;
    const int tid = threadIdx.x;
    const int lrow = tid >> 2;          // 0..63
    const int lcol = (tid & 3) << 2;    // 0,4,8,12
    const int tr = tid >> 4;            // 0..15
    const int tc = tid & 15;            // 0..15

    float acc[8][8];
#pragma unroll
    for (int i = 0; i < 8; i++)
#pragma unroll
        for (int j = 0; j < 8; j++) acc[i][j] = 0.f;

    for (int k0 = 0; k0 < D_; k0 += BK) {
        __syncthreads();
#pragma unroll
        for (int p = 0; p < 2; p++) {
            int row = lrow + p * 64;
            int gr = bm + row;
            float4 va = make_float4(0.f, 0.f, 0.f, 0.f);
            if (gr < Mrows) va = *(const float4*)&A[(size_t)gr * D_ + k0 + lcol];
            As[lcol + 0][row] = va.x; As[lcol + 1][row] = va.y;
            As[lcol + 2][row] = va.z; As[lcol + 3][row] = va.w;
            float4 vb = *(const float4*)&W[(size_t)(bn + row) * D_ + k0 + lcol];
            Bs[lcol + 0][row] = vb.x; Bs[lcol + 1][row] = vb.y;
            Bs[lcol + 2][row] = vb.z; Bs[lcol + 3][row] = vb.w;
        }
        __syncthreads();
#pragma unroll
        for (int kk = 0; kk < BK; kk++) {
            float a[8], b[8];
            *(float4*)&a[0] = *(const float4*)&As[kk][tr * 8];
            *(float4*)&a[4] = *(const float4*)&As[kk][tr * 8 + 4];
            *(float4*)&b[0] = *(const float4*)&Bs[kk][tc * 8];
            *(float4*)&b[4] = *(const float4*)&Bs[kk][tc * 8 + 4];
#pragma unroll
            for (int i = 0; i < 8; i++)
#pragma unroll
                for (int j = 0; j < 8; j++)
                    acc[i][j] = fmaf(a[i], b[j], acc[i][j]);
        }
    }

#pragma unroll
    for (int i = 0; i < 8; i++) {
        int gr = bm + tr * 8 + i;
        if (gr >= Mrows) break;
#pragma unroll
        for (int j = 0; j < 8; j += 4) {
            int gc = bn + tc * 8 + j;
            float v0 = acc[i][j + 0] + bias[gc + 0];
            float v1 = acc[i][j + 1] + bias[gc + 1];
            float v2 = acc[i][j + 2] + bias[gc + 2];
            float v3 = acc[i][j + 3] + bias[gc + 3];
            if (BF16OUT) {
                ushort4 u;
                u.x = f2b(v0); u.y = f2b(v1); u.z = f2b(v2); u.w = f2b(v3);
                *(ushort4*)&((unsigned short*)outv)[(size_t)gr * D_ + gc] = u;
            } else {
                float4 v = make_float4(v0, v1, v2, v3);
                *(float4*)&((float*)outv)[(size_t)gr * D_ + gc] = v;
            }
        }
    }
}

// ---------- per-node logit parts ----------
__global__ __launch_bounds__(256) void node_logits(
    const unsigned short* __restrict__ l, const float* __restrict__ r,
    const float* __restrict__ attn, const float* __restrict__ rel_l,
    const float* __restrict__ rel_r,
    float* __restrict__ ai, float* __restrict__ aj, float* __restrict__ al,
    float* __restrict__ ld, float* __restrict__ rd, int Nn)
{
    int n = blockIdx.x;
    int t = threadIdx.x;
    int h = t >> 6, c = t & 63;
    float lv = b2f(l[(size_t)n * D_ + t]);
    float rv = r[(size_t)n * D_ + t];
    float lr_r = lrelu(rv);
    float lr_l = lrelu(lv);
    float wrr = rel_r[h * C_ + c];
    float v0 = lr_r * attn[(0 * H_ + h) * 128 + c];        // ai m=0
    float v1 = lr_r * attn[(1 * H_ + h) * 128 + c];        // ai m=1
    float v2 = lr_l * attn[(0 * H_ + h) * 128 + 64 + c];   // aj m=0
    float v3 = lr_l * attn[(1 * H_ + h) * 128 + 64 + c];   // aj m=1
    float v4 = rv * rel_l[h * C_ + c];
    float v5 = lv * wrr;
    float v6 = rv * wrr;
    v0 = wave_sum(v0); v1 = wave_sum(v1); v2 = wave_sum(v2);
    v3 = wave_sum(v3); v4 = wave_sum(v4); v5 = wave_sum(v5);
    v6 = wave_sum(v6);
    if (c == 0) {
        int NH = Nn * H_;
        int nh = n * H_ + h;
        ai[0 * NH + nh] = v0;
        ai[1 * NH + nh] = v1;
        aj[0 * NH + nh] = v2;
        aj[1 * NH + nh] = v3;
        al[nh] = v4;
        ld[nh] = v5;
        rd[nh] = v6;
    }
}

// ---------- CSR build: histogram ----------
__global__ __launch_bounds__(256) void edge_hist(
    const int* __restrict__ ei0, const int* __restrict__ ei1,
    int* __restrict__ hist, int E_, int Nn)
{
    int e = blockIdx.x * 256 + threadIdx.x;
    if (e >= E_) return;
    atomicAdd(&hist[ei0[E_ + e]], 1);
    atomicAdd(&hist[Nn + ei1[E_ + e]], 1);
}

// ---------- CSR build: 3-kernel exclusive scan over Nn (x2 metapaths) ----------
__global__ __launch_bounds__(256) void scan_a(
    const int* __restrict__ hist, int* __restrict__ segoff,
    int* __restrict__ bsum, int Nn)
{
    int m = blockIdx.y;
    int gid = blockIdx.x * 256 + threadIdx.x;
    int lane = threadIdx.x & 63, wid = threadIdx.x >> 6;
    int v = (gid < Nn) ? hist[m * Nn + gid] : 0;
    int incl = v;
#pragma unroll
    for (int off = 1; off < 64; off <<= 1) {
        int u = __shfl_up(incl, off);
        if (lane >= off) incl += u;
    }
    __shared__ int ws[4], wo[4];
    if (lane == 63) ws[wid] = incl;
    __syncthreads();
    if (threadIdx.x == 0) {
        int run = 0;
#pragma unroll
        for (int i = 0; i < 4; i++) { wo[i] = run; run += ws[i]; }
        bsum[m * 512 + blockIdx.x] = run;
    }
    __syncthreads();
    if (gid < Nn) segoff[m * Nn + gid] = incl - v + wo[wid];
}

__global__ __launch_bounds__(512) void scan_b(int* __restrict__ bsum, int nb)
{
    int m = blockIdx.x;
    int* b = bsum + m * 512;
    int tid = threadIdx.x, lane = tid & 63, wid = tid >> 6;
    int v = (tid < nb) ? b[tid] : 0;
    int incl = v;
#pragma unroll
    for (int off = 1; off < 64; off <<= 1) {
        int u = __shfl_up(incl, off);
        if (lane >= off) incl += u;
    }
    __shared__ int ws[8], wo[8];
    if (lane == 63) ws[wid] = incl;
    __syncthreads();
    if (tid == 0) {
        int run = 0;
#pragma unroll
        for (int i = 0; i < 8; i++) { wo[i] = run; run += ws[i]; }
    }
    __syncthreads();
    if (tid < nb) b[tid] = incl - v + wo[wid];
}

__global__ __launch_bounds__(256) void scan_c(
    int* __restrict__ segoff, const int* __restrict__ bsum, int Nn)
{
    int m = blockIdx.y;
    int gid = blockIdx.x * 256 + threadIdx.x;
    if (gid < Nn) segoff[m * Nn + gid] += bsum[m * 512 + blockIdx.x];
}

// ---------- CSR build: scatter src ids into sorted-by-target order ----------
__global__ __launch_bounds__(256) void edge_scatter(
    const int* __restrict__ ei0, const int* __restrict__ ei1,
    const int* __restrict__ segoff, int* __restrict__ cursor,
    int* __restrict__ srcs, int E_, int Nn)
{
    int e = blockIdx.x * 256 + threadIdx.x;
    if (e >= E_) return;
    int t0 = ei0[E_ + e];
    int p0 = segoff[t0] + atomicAdd(&cursor[t0], 1);
    srcs[p0] = ei0[e];
    int t1 = ei1[E_ + e];
    int p1 = segoff[Nn + t1] + atomicAdd(&cursor[Nn + t1], 1);
    srcs[E_ + p1] = ei1[e];
}

// ---------- per-(target,head) softmax stats + relation beta, no atomics ----------
__global__ __launch_bounds__(256) void node_softmax(
    const int* __restrict__ hist, const int* __restrict__ segoff,
    const int* __restrict__ srcs,
    const float* __restrict__ ai, const float* __restrict__ aj,
    const float* __restrict__ al, const float* __restrict__ ld,
    const float* __restrict__ rd,
    float* __restrict__ mx, float* __restrict__ wm, float* __restrict__ beta2,
    int Nn, int E_)
{
    int NH = Nn * H_;
    int nh = blockIdx.x * 256 + threadIdx.x;
    if (nh >= NH) return;
    int t = nh >> 2, h = nh & 3;
    float mxv[2], dnv[2], pv[2];
#pragma unroll
    for (int m = 0; m < 2; m++) {
        const int* sp = srcs + (size_t)m * E_;
        int beg = segoff[m * Nn + t];
        int deg = hist[m * Nn + t];
        float a_i = ai[(size_t)m * NH + nh];
        float mxm = -INFINITY;
        for (int j = 0; j < deg; j++) {
            int s = sp[beg + j];
            mxm = fmaxf(mxm, a_i + aj[(size_t)m * NH + s * H_ + h]);
        }
        float den = 0.f, p = 0.f;
        for (int j = 0; j < deg; j++) {
            int s = sp[beg + j];
            float ev = __expf(a_i + aj[(size_t)m * NH + s * H_ + h] - mxm);
            den += ev;
            p += ev * ld[s * H_ + h];
        }
        if (deg == 0) mxm = 0.f;
        mxv[m] = mxm; dnv[m] = den; pv[m] = p / (den + 1e-16f);
    }
    float a = al[nh];
    float b0 = lrelu(a + pv[0]);
    float b1 = lrelu(a + pv[1]);
    float b2 = lrelu(a + rd[nh]);
    float mm = fmaxf(b0, fmaxf(b1, b2));
    float e0 = __expf(b0 - mm), e1 = __expf(b1 - mm), e2 = __expf(b2 - mm);
    float inv = 1.f / (e0 + e1 + e2);
    mx[nh] = mxv[0]; mx[NH + nh] = mxv[1];
    wm[nh] = e0 * inv / (dnv[0] + 1e-16f);
    wm[NH + nh] = e1 * inv / (dnv[1] + 1e-16f);
    beta2[nh] = e2 * inv;
}

// ---------- fused aggregation: wave per target, register accumulate, one write ----------
__global__ __launch_bounds__(256) void aggregate(
    const int* __restrict__ hist, const int* __restrict__ segoff,
    const int* __restrict__ srcs,
    const float* __restrict__ ai, const float* __restrict__ aj,
    const float* __restrict__ mx, const float* __restrict__ wm,
    const float* __restrict__ beta2, const unsigned short* __restrict__ l,
    float* __restrict__ out, int Nn, int E_)
{
    int lane = threadIdx.x & 63;
    int t = blockIdx.x * 4 + (threadIdx.x >> 6);
    if (t >= Nn) return;
    int h = lane >> 4;
    int NH = Nn * H_;
    int nh = t * H_ + h;

    float4 acc = *(const float4*)&out[(size_t)t * D_ + lane * 4];  // r row
    float b2 = beta2[nh];
    acc.x *= b2; acc.y *= b2; acc.z *= b2; acc.w *= b2;

#pragma unroll
    for (int m = 0; m < 2; m++) {
        const int* sp = srcs + (size_t)m * E_;
        int beg = segoff[m * Nn + t];
        int deg = hist[m * Nn + t];
        float a_i = ai[(size_t)m * NH + nh];
        float mxv = mx[(size_t)m * NH + nh];
        float wmv = wm[(size_t)m * NH + nh];
        for (int j = 0; j < deg; j++) {
            int s = sp[beg + j];
            float w = __expf(a_i + aj[(size_t)m * NH + s * H_ + h] - mxv) * wmv;
            ushort4 lv = *(const ushort4*)&l[(size_t)s * D_ + lane * 4];
            acc.x = fmaf(b2f(lv.x), w, acc.x);
            acc.y = fmaf(b2f(lv.y), w, acc.y);
            acc.z = fmaf(b2f(lv.z), w, acc.z);
            acc.w = fmaf(b2f(lv.w), w, acc.w);
        }
    }
    float4 o;
    o.x = fmaxf(acc.x, 0.f); o.y = fmaxf(acc.y, 0.f);
    o.z = fmaxf(acc.z, 0.f); o.w = fmaxf(acc.w, 0.f);
    *(float4*)&out[(size_t)t * D_ + lane * 4] = o;
}

extern "C" void kernel_launch(void* const* d_in, const int* in_sizes, int n_in,
                              void* d_out, int out_size, void* d_ws, size_t ws_size,
                              hipStream_t stream) {
    const float* x     = (const float*)d_in[0];
    const int*   ei0   = (const int*)d_in[1];
    const int*   ei1   = (const int*)d_in[2];
    const float* W_l   = (const float*)d_in[3];
    const float* b_l   = (const float*)d_in[4];
    const float* W_r   = (const float*)d_in[5];
    const float* b_r   = (const float*)d_in[6];
    const float* attn  = (const float*)d_in[7];
    const float* rel_l = (const float*)d_in[8];
    const float* rel_r = (const float*)d_in[9];
    float* out = (float*)d_out;   // r -> beta2*r + aggregation -> relu (in place)

    const int Nn = in_sizes[0] / D_;        // 100000
    const int E_ = in_sizes[1] / 2;         // 800000
    const size_t ND = (size_t)Nn * D_;
    const int NH = Nn * H_;

    // ---- workspace layout ≈ 79 MB ----
    char* base = (char*)d_ws;
    unsigned short* l = (unsigned short*)base;      size_t off = ND * 2;
    float* ai    = (float*)(base + off); off += (size_t)2 * NH * 4;
    float* aj    = (float*)(base + off); off += (size_t)2 * NH * 4;
    float* mx    = (float*)(base + off); off += (size_t)2 * NH * 4;
    float* wm    = (float*)(base + off); off += (size_t)2 * NH * 4;
    float* al    = (float*)(base + off); off += (size_t)NH * 4;
    float* ld    = (float*)(base + off); off += (size_t)NH * 4;
    float* rd    = (float*)(base + off); off += (size_t)NH * 4;
    float* beta2 = (float*)(base + off); off += (size_t)NH * 4;
    int* hist    = (int*)(base + off);   off += (size_t)2 * Nn * 4;  // [M][Nn]
    int* cursor  = (int*)(base + off);   off += (size_t)2 * Nn * 4;  // [M][Nn]
    int* segoff  = (int*)(base + off);   off += (size_t)2 * Nn * 4;  // [M][Nn]
    int* bsum    = (int*)(base + off);   off += (size_t)1024 * 4;    // [M][512]
    int* srcs    = (int*)(base + off);   off += (size_t)2 * E_ * 4;  // [M][E]

    // zero hist + cursor (contiguous)
    hipMemsetAsync(hist, 0, (size_t)4 * Nn * 4, stream);

    dim3 gg((Nn + BM - 1) / BM, D_ / BN);
    gemm_xwt<true ><<<gg, 256, 0, stream>>>(x, W_l, b_l, l, Nn);    // l -> bf16 ws
    gemm_xwt<false><<<gg, 256, 0, stream>>>(x, W_r, b_r, out, Nn);  // r -> d_out

    node_logits<<<Nn, 256, 0, stream>>>(l, out, attn, rel_l, rel_r,
                                        ai, aj, al, ld, rd, Nn);

    int eb = (E_ + 255) / 256;
    int nb = (Nn + 255) / 256;   // 391
    edge_hist<<<eb, 256, 0, stream>>>(ei0, ei1, hist, E_, Nn);
    scan_a<<<dim3(nb, 2), 256, 0, stream>>>(hist, segoff, bsum, Nn);
    scan_b<<<2, 512, 0, stream>>>(bsum, nb);
    scan_c<<<dim3(nb, 2), 256, 0, stream>>>(segoff, bsum, Nn);
    edge_scatter<<<eb, 256, 0, stream>>>(ei0, ei1, segoff, cursor, srcs, E_, Nn);

    node_softmax<<<(NH + 255) / 256, 256, 0, stream>>>(
        hist, segoff, srcs, ai, aj, al, ld, rd, mx, wm, beta2, Nn, E_);

    aggregate<<<(Nn + 3) / 4, 256, 0, stream>>>(
        hist, segoff, srcs, ai, aj, mx, wm, beta2, l, out, Nn, E_);
}

// Round 4
// 694.917 us; speedup vs baseline: 9.8680x; 1.3381x over previous
//
#include <hip/hip_runtime.h>
#include <hip/hip_bf16.h>
#include <math.h>

#define D_ 256
#define H_ 4
#define C_ 64

typedef __attribute__((ext_vector_type(8))) short short8;
typedef __attribute__((ext_vector_type(4))) float f32x4;

// ---------- helpers ----------
__device__ inline float lrelu(float v) { return v >= 0.f ? v : 0.2f * v; }

__device__ inline float wave_sum(float v) {
#pragma unroll
    for (int off = 32; off > 0; off >>= 1) v += __shfl_xor(v, off);
    return v;
}

// bf16 bit helpers
__device__ inline unsigned short f2b(float f) {
    unsigned u = __float_as_uint(f);
    u = (u + 0x7FFFu + ((u >> 16) & 1u)) >> 16;   // round-to-nearest-even
    return (unsigned short)u;
}
__device__ inline float b2f(unsigned short u) {
    return __uint_as_float(((unsigned)u) << 16);
}

#define GLDS(src, dst) __builtin_amdgcn_global_load_lds(                      \
    (const __attribute__((address_space(1))) void*)(src),                     \
    (__attribute__((address_space(3))) void*)(dst), 16, 0, 0)

// ---------- W -> bf16 ----------
__global__ __launch_bounds__(256) void convert_w(
    const float* __restrict__ Wl, const float* __restrict__ Wr,
    unsigned short* __restrict__ Wb)
{
    int i4 = blockIdx.x * 256 + threadIdx.x;          // 0..32767 float4s
    float4 v = (i4 < 16384) ? ((const float4*)Wl)[i4]
                            : ((const float4*)Wr)[i4 - 16384];
    ushort4 u;
    u.x = f2b(v.x); u.y = f2b(v.y); u.z = f2b(v.z); u.w = f2b(v.w);
    ((ushort4*)Wb)[i4] = u;
}

// ---------- fused MFMA GEMM: l = x@W_l^T + b_l (bf16 out), r = x@W_r^T + b_r ----------
// grid (4, rowTiles): blockIdx.x = {0,1: l cols 0-127,128-255; 2,3: r cols}
__device__ __forceinline__ void stage_a(const float* __restrict__ x, float* dst,
                                        int bm, int k0, int wv, int lane, int Mrows)
{
#pragma unroll
    for (int p = 0; p < 4; p++) {
        int ci = (p * 4 + wv) * 64 + lane;            // chunk 0..1023
        int row = ci >> 3, cc = ci & 7;
        int gr = bm + row; if (gr >= Mrows) gr = Mrows - 1;
        const float* src = x + (size_t)gr * 256 + k0 + ((cc ^ (row & 7)) << 2);
        GLDS(src, (char*)dst + (size_t)(p * 4 + wv) * 1024);
    }
}
__device__ __forceinline__ void stage_b(const unsigned short* __restrict__ W,
                                        unsigned short* dst, int bn, int k0,
                                        int wv, int lane)
{
#pragma unroll
    for (int p = 0; p < 2; p++) {
        int ci = (p * 4 + wv) * 64 + lane;            // chunk 0..511
        int col = ci >> 2, cc = ci & 3;
        const unsigned short* src = W + (size_t)(bn + col) * 256 + k0 +
                                    ((cc ^ (col & 3)) << 3);
        GLDS(src, (char*)dst + (size_t)(p * 4 + wv) * 1024);
    }
}

__global__ __launch_bounds__(256) void gemm_fused(
    const float* __restrict__ x, const unsigned short* __restrict__ Wb,
    const float* __restrict__ b_l, const float* __restrict__ b_r,
    unsigned short* __restrict__ lout, float* __restrict__ rout, int Mrows)
{
    __shared__ float As[2][128 * 32];
    __shared__ unsigned short Bs[2][128 * 32];
    const int tid = threadIdx.x;
    const int lane = tid & 63, wv = tid >> 6;
    const int wr = wv >> 1, wc = wv & 1;
    const int sel = blockIdx.x >> 1;                  // 0 = l, 1 = r
    const int bn = (blockIdx.x & 1) * 128;
    const int bm = blockIdx.y * 128;
    const unsigned short* W = Wb + (size_t)sel * 65536;

    f32x4 acc[4][4];
#pragma unroll
    for (int m = 0; m < 4; m++)
#pragma unroll
        for (int n = 0; n < 4; n++) acc[m][n] = (f32x4)0.f;

    stage_a(x, As[0], bm, 0, wv, lane, Mrows);
    stage_b(W, Bs[0], bn, 0, wv, lane);
    __syncthreads();

    int cur = 0;
#pragma unroll
    for (int t = 0; t < 8; t++) {
        if (t < 7) {
            stage_a(x, As[cur ^ 1], bm, (t + 1) * 32, wv, lane, Mrows);
            stage_b(W, Bs[cur ^ 1], bn, (t + 1) * 32, wv, lane);
        }
        // B fragments
        short8 bfr[4];
#pragma unroll
        for (int n = 0; n < 4; n++) {
            int col = wc * 64 + n * 16 + (lane & 15);
            int sc = (lane >> 4) ^ (col & 3);
            bfr[n] = *(const short8*)&Bs[cur][col * 32 + sc * 8];
        }
        // A fragments (f32 -> bf16 in-register)
        short8 afr[4];
#pragma unroll
        for (int m = 0; m < 4; m++) {
            int row = wr * 64 + m * 16 + (lane & 15);
            int c0 = (lane >> 4) * 2;
            const float* ap = &As[cur][row * 32];
            float4 f0 = *(const float4*)&ap[(c0 ^ (row & 7)) << 2];
            float4 f1 = *(const float4*)&ap[((c0 + 1) ^ (row & 7)) << 2];
            union { short8 v; __hip_bfloat162 b2[4]; } u;
            u.b2[0] = __float22bfloat162_rn(make_float2(f0.x, f0.y));
            u.b2[1] = __float22bfloat162_rn(make_float2(f0.z, f0.w));
            u.b2[2] = __float22bfloat162_rn(make_float2(f1.x, f1.y));
            u.b2[3] = __float22bfloat162_rn(make_float2(f1.z, f1.w));
            afr[m] = u.v;
        }
#pragma unroll
        for (int m = 0; m < 4; m++)
#pragma unroll
            for (int n = 0; n < 4; n++)
                acc[m][n] = __builtin_amdgcn_mfma_f32_16x16x32_bf16(
                    afr[m], bfr[n], acc[m][n], 0, 0, 0);
        __syncthreads();
        cur ^= 1;
    }

    const float* bias = sel ? b_r : b_l;
#pragma unroll
    for (int m = 0; m < 4; m++) {
        int grow0 = bm + wr * 64 + m * 16 + (lane >> 4) * 4;
#pragma unroll
        for (int n = 0; n < 4; n++) {
            int gcol = bn + wc * 64 + n * 16 + (lane & 15);
            float bv = bias[gcol];
#pragma unroll
            for (int q = 0; q < 4; q++) {
                int grow = grow0 + q;
                if (grow < Mrows) {
                    float v = acc[m][n][q] + bv;
                    if (sel == 0) lout[(size_t)grow * 256 + gcol] = f2b(v);
                    else          rout[(size_t)grow * 256 + gcol] = v;
                }
            }
        }
    }
}

// ---------- per-node logit parts ----------
__global__ __launch_bounds__(256) void node_logits(
    const unsigned short* __restrict__ l, const float* __restrict__ r,
    const float* __restrict__ attn, const float* __restrict__ rel_l,
    const float* __restrict__ rel_r,
    float* __restrict__ ai, float* __restrict__ aj, float* __restrict__ al,
    float* __restrict__ ld, float* __restrict__ rd, int Nn)
{
    int n = blockIdx.x;
    int t = threadIdx.x;
    int h = t >> 6, c = t & 63;
    float lv = b2f(l[(size_t)n * D_ + t]);
    float rv = r[(size_t)n * D_ + t];
    float lr_r = lrelu(rv);
    float lr_l = lrelu(lv);
    float wrr = rel_r[h * C_ + c];
    float v0 = lr_r * attn[(0 * H_ + h) * 128 + c];        // ai m=0
    float v1 = lr_r * attn[(1 * H_ + h) * 128 + c];        // ai m=1
    float v2 = lr_l * attn[(0 * H_ + h) * 128 + 64 + c];   // aj m=0
    float v3 = lr_l * attn[(1 * H_ + h) * 128 + 64 + c];   // aj m=1
    float v4 = rv * rel_l[h * C_ + c];
    float v5 = lv * wrr;
    float v6 = rv * wrr;
    v0 = wave_sum(v0); v1 = wave_sum(v1); v2 = wave_sum(v2);
    v3 = wave_sum(v3); v4 = wave_sum(v4); v5 = wave_sum(v5);
    v6 = wave_sum(v6);
    if (c == 0) {
        int NH = Nn * H_;
        int nh = n * H_ + h;
        ai[0 * NH + nh] = v0;
        ai[1 * NH + nh] = v1;
        aj[0 * NH + nh] = v2;
        aj[1 * NH + nh] = v3;
        al[nh] = v4;
        ld[nh] = v5;
        rd[nh] = v6;
    }
}

// ---------- CSR build: histogram ----------
__global__ __launch_bounds__(256) void edge_hist(
    const int* __restrict__ ei0, const int* __restrict__ ei1,
    int* __restrict__ hist, int E_, int Nn)
{
    int e = blockIdx.x * 256 + threadIdx.x;
    if (e >= E_) return;
    atomicAdd(&hist[ei0[E_ + e]], 1);
    atomicAdd(&hist[Nn + ei1[E_ + e]], 1);
}

// ---------- CSR build: 3-kernel exclusive scan ----------
__global__ __launch_bounds__(256) void scan_a(
    const int* __restrict__ hist, int* __restrict__ segoff,
    int* __restrict__ bsum, int Nn)
{
    int m = blockIdx.y;
    int gid = blockIdx.x * 256 + threadIdx.x;
    int lane = threadIdx.x & 63, wid = threadIdx.x >> 6;
    int v = (gid < Nn) ? hist[m * Nn + gid] : 0;
    int incl = v;
#pragma unroll
    for (int off = 1; off < 64; off <<= 1) {
        int u = __shfl_up(incl, off);
        if (lane >= off) incl += u;
    }
    __shared__ int ws[4], wo[4];
    if (lane == 63) ws[wid] = incl;
    __syncthreads();
    if (threadIdx.x == 0) {
        int run = 0;
#pragma unroll
        for (int i = 0; i < 4; i++) { wo[i] = run; run += ws[i]; }
        bsum[m * 512 + blockIdx.x] = run;
    }
    __syncthreads();
    if (gid < Nn) segoff[m * Nn + gid] = incl - v + wo[wid];
}

__global__ __launch_bounds__(512) void scan_b(int* __restrict__ bsum, int nb)
{
    int m = blockIdx.x;
    int* b = bsum + m * 512;
    int tid = threadIdx.x, lane = tid & 63, wid = tid >> 6;
    int v = (tid < nb) ? b[tid] : 0;
    int incl = v;
#pragma unroll
    for (int off = 1; off < 64; off <<= 1) {
        int u = __shfl_up(incl, off);
        if (lane >= off) incl += u;
    }
    __shared__ int ws[8], wo[8];
    if (lane == 63) ws[wid] = incl;
    __syncthreads();
    if (tid == 0) {
        int run = 0;
#pragma unroll
        for (int i = 0; i < 8; i++) { wo[i] = run; run += ws[i]; }
    }
    __syncthreads();
    if (tid < nb) b[tid] = incl - v + wo[wid];
}

__global__ __launch_bounds__(256) void scan_c(
    int* __restrict__ segoff, const int* __restrict__ bsum, int Nn)
{
    int m = blockIdx.y;
    int gid = blockIdx.x * 256 + threadIdx.x;
    if (gid < Nn) segoff[m * Nn + gid] += bsum[m * 512 + blockIdx.x];
}

// ---------- CSR build: scatter ----------
__global__ __launch_bounds__(256) void edge_scatter(
    const int* __restrict__ ei0, const int* __restrict__ ei1,
    const int* __restrict__ segoff, int* __restrict__ cursor,
    int* __restrict__ srcs, int E_, int Nn)
{
    int e = blockIdx.x * 256 + threadIdx.x;
    if (e >= E_) return;
    int t0 = ei0[E_ + e];
    int p0 = segoff[t0] + atomicAdd(&cursor[t0], 1);
    srcs[p0] = ei0[e];
    int t1 = ei1[E_ + e];
    int p1 = segoff[Nn + t1] + atomicAdd(&cursor[Nn + t1], 1);
    srcs[E_ + p1] = ei1[e];
}

// ---------- per-(target,head) softmax stats + relation beta ----------
__global__ __launch_bounds__(256) void node_softmax(
    const int* __restrict__ hist, const int* __restrict__ segoff,
    const int* __restrict__ srcs,
    const float* __restrict__ ai, const float* __restrict__ aj,
    const float* __restrict__ al, const float* __restrict__ ld,
    const float* __restrict__ rd,
    float* __restrict__ mx, float* __restrict__ wm, float* __restrict__ beta2,
    int Nn, int E_)
{
    int NH = Nn * H_;
    int nh = blockIdx.x * 256 + threadIdx.x;
    if (nh >= NH) return;
    int t = nh >> 2, h = nh & 3;
    float mxv[2], dnv[2], pv[2];
#pragma unroll
    for (int m = 0; m < 2; m++) {
        const int* sp = srcs + (size_t)m * E_;
        int beg = segoff[m * Nn + t];
        int deg = hist[m * Nn + t];
        float a_i = ai[(size_t)m * NH + nh];
        float mxm = -INFINITY;
        for (int j = 0; j < deg; j++) {
            int s = sp[beg + j];
            mxm = fmaxf(mxm, a_i + aj[(size_t)m * NH + s * H_ + h]);
        }
        float den = 0.f, p = 0.f;
        for (int j = 0; j < deg; j++) {
            int s = sp[beg + j];
            float ev = __expf(a_i + aj[(size_t)m * NH + s * H_ + h] - mxm);
            den += ev;
            p += ev * ld[s * H_ + h];
        }
        if (deg == 0) mxm = 0.f;
        mxv[m] = mxm; dnv[m] = den; pv[m] = p / (den + 1e-16f);
    }
    float a = al[nh];
    float b0 = lrelu(a + pv[0]);
    float b1 = lrelu(a + pv[1]);
    float b2 = lrelu(a + rd[nh]);
    float mm = fmaxf(b0, fmaxf(b1, b2));
    float e0 = __expf(b0 - mm), e1 = __expf(b1 - mm), e2 = __expf(b2 - mm);
    float inv = 1.f / (e0 + e1 + e2);
    mx[nh] = mxv[0]; mx[NH + nh] = mxv[1];
    wm[nh] = e0 * inv / (dnv[0] + 1e-16f);
    wm[NH + nh] = e1 * inv / (dnv[1] + 1e-16f);
    beta2[nh] = e2 * inv;
}

// ---------- fused aggregation ----------
__global__ __launch_bounds__(256) void aggregate(
    const int* __restrict__ hist, const int* __restrict__ segoff,
    const int* __restrict__ srcs,
    const float* __restrict__ ai, const float* __restrict__ aj,
    const float* __restrict__ mx, const float* __restrict__ wm,
    const float* __restrict__ beta2, const unsigned short* __restrict__ l,
    float* __restrict__ out, int Nn, int E_)
{
    int lane = threadIdx.x & 63;
    int t = blockIdx.x * 4 + (threadIdx.x >> 6);
    if (t >= Nn) return;
    int h = lane >> 4;
    int NH = Nn * H_;
    int nh = t * H_ + h;

    float4 acc = *(const float4*)&out[(size_t)t * D_ + lane * 4];  // r row
    float b2 = beta2[nh];
    acc.x *= b2; acc.y *= b2; acc.z *= b2; acc.w *= b2;

#pragma unroll
    for (int m = 0; m < 2; m++) {
        const int* sp = srcs + (size_t)m * E_;
        int beg = segoff[m * Nn + t];
        int deg = hist[m * Nn + t];
        float a_i = ai[(size_t)m * NH + nh];
        float mxv = mx[(size_t)m * NH + nh];
        float wmv = wm[(size_t)m * NH + nh];
        for (int j = 0; j < deg; j++) {
            int s = sp[beg + j];
            float w = __expf(a_i + aj[(size_t)m * NH + s * H_ + h] - mxv) * wmv;
            ushort4 lv = *(const ushort4*)&l[(size_t)s * D_ + lane * 4];
            acc.x = fmaf(b2f(lv.x), w, acc.x);
            acc.y = fmaf(b2f(lv.y), w, acc.y);
            acc.z = fmaf(b2f(lv.z), w, acc.z);
            acc.w = fmaf(b2f(lv.w), w, acc.w);
        }
    }
    float4 o;
    o.x = fmaxf(acc.x, 0.f); o.y = fmaxf(acc.y, 0.f);
    o.z = fmaxf(acc.z, 0.f); o.w = fmaxf(acc.w, 0.f);
    *(float4*)&out[(size_t)t * D_ + lane * 4] = o;
}

extern "C" void kernel_launch(void* const* d_in, const int* in_sizes, int n_in,
                              void* d_out, int out_size, void* d_ws, size_t ws_size,
                              hipStream_t stream) {
    const float* x     = (const float*)d_in[0];
    const int*   ei0   = (const int*)d_in[1];
    const int*   ei1   = (const int*)d_in[2];
    const float* W_l   = (const float*)d_in[3];
    const float* b_l   = (const float*)d_in[4];
    const float* W_r   = (const float*)d_in[5];
    const float* b_r   = (const float*)d_in[6];
    const float* attn  = (const float*)d_in[7];
    const float* rel_l = (const float*)d_in[8];
    const float* rel_r = (const float*)d_in[9];
    float* out = (float*)d_out;   // r -> beta2*r + aggregation -> relu (in place)

    const int Nn = in_sizes[0] / D_;        // 100000
    const int E_ = in_sizes[1] / 2;         // 800000
    const size_t ND = (size_t)Nn * D_;
    const int NH = Nn * H_;

    // ---- workspace layout ≈ 80 MB ----
    char* base = (char*)d_ws;
    unsigned short* l = (unsigned short*)base;      size_t off = ND * 2;
    float* ai    = (float*)(base + off); off += (size_t)2 * NH * 4;
    float* aj    = (float*)(base + off); off += (size_t)2 * NH * 4;
    float* mx    = (float*)(base + off); off += (size_t)2 * NH * 4;
    float* wm    = (float*)(base + off); off += (size_t)2 * NH * 4;
    float* al    = (float*)(base + off); off += (size_t)NH * 4;
    float* ld    = (float*)(base + off); off += (size_t)NH * 4;
    float* rd    = (float*)(base + off); off += (size_t)NH * 4;
    float* beta2 = (float*)(base + off); off += (size_t)NH * 4;
    int* hist    = (int*)(base + off);   off += (size_t)2 * Nn * 4;  // [M][Nn]
    int* cursor  = (int*)(base + off);   off += (size_t)2 * Nn * 4;
    int* segoff  = (int*)(base + off);   off += (size_t)2 * Nn * 4;
    int* bsum    = (int*)(base + off);   off += (size_t)1024 * 4;
    int* srcs    = (int*)(base + off);   off += (size_t)2 * E_ * 4;  // [M][E]
    unsigned short* Wb = (unsigned short*)(base + off); off += (size_t)2 * 65536 * 2;

    // zero hist + cursor (contiguous)
    hipMemsetAsync(hist, 0, (size_t)4 * Nn * 4, stream);

    convert_w<<<128, 256, 0, stream>>>(W_l, W_r, Wb);

    int rowTiles = (Nn + 127) / 128;   // 782
    gemm_fused<<<dim3(4, rowTiles), 256, 0, stream>>>(x, Wb, b_l, b_r, l, out, Nn);

    node_logits<<<Nn, 256, 0, stream>>>(l, out, attn, rel_l, rel_r,
                                        ai, aj, al, ld, rd, Nn);

    int eb = (E_ + 255) / 256;
    int nb = (Nn + 255) / 256;   // 391
    edge_hist<<<eb, 256, 0, stream>>>(ei0, ei1, hist, E_, Nn);
    scan_a<<<dim3(nb, 2), 256, 0, stream>>>(hist, segoff, bsum, Nn);
    scan_b<<<2, 512, 0, stream>>>(bsum, nb);
    scan_c<<<dim3(nb, 2), 256, 0, stream>>>(segoff, bsum, Nn);
    edge_scatter<<<eb, 256, 0, stream>>>(ei0, ei1, segoff, cursor, srcs, E_, Nn);

    node_softmax<<<(NH + 255) / 256, 256, 0, stream>>>(
        hist, segoff, srcs, ai, aj, al, ld, rd, mx, wm, beta2, Nn, E_);

    aggregate<<<(Nn + 3) / 4, 256, 0, stream>>>(
        hist, segoff, srcs, ai, aj, mx, wm, beta2, l, out, Nn, E_);
}

// Round 5
// 586.634 us; speedup vs baseline: 11.6895x; 1.1846x over previous
//
#include <hip/hip_runtime.h>
#include <hip/hip_bf16.h>
#include <math.h>

#define D_ 256
#define H_ 4
#define C_ 64

typedef __attribute__((ext_vector_type(8))) short short8;
typedef __attribute__((ext_vector_type(4))) float f32x4;

// ---------- helpers ----------
__device__ inline float lrelu(float v) { return v >= 0.f ? v : 0.2f * v; }

__device__ inline float wave_sum(float v) {
#pragma unroll
    for (int off = 32; off > 0; off >>= 1) v += __shfl_xor(v, off);
    return v;
}

// bf16 bit helpers
__device__ inline unsigned short f2b(float f) {
    unsigned u = __float_as_uint(f);
    u = (u + 0x7FFFu + ((u >> 16) & 1u)) >> 16;   // round-to-nearest-even
    return (unsigned short)u;
}
__device__ inline float b2f(unsigned short u) {
    return __uint_as_float(((unsigned)u) << 16);
}

#define GLDS(src, dst) __builtin_amdgcn_global_load_lds(                      \
    (const __attribute__((address_space(1))) void*)(src),                     \
    (__attribute__((address_space(3))) void*)(dst), 16, 0, 0)

// ---------- W -> bf16 ----------
__global__ __launch_bounds__(256) void convert_w(
    const float* __restrict__ Wl, const float* __restrict__ Wr,
    unsigned short* __restrict__ Wb)
{
    int i4 = blockIdx.x * 256 + threadIdx.x;          // 0..32767 float4s
    float4 v = (i4 < 16384) ? ((const float4*)Wl)[i4]
                            : ((const float4*)Wr)[i4 - 16384];
    ushort4 u;
    u.x = f2b(v.x); u.y = f2b(v.y); u.z = f2b(v.z); u.w = f2b(v.w);
    ((ushort4*)Wb)[i4] = u;
}

// ---------- fused MFMA GEMM: l = x@W_l^T + b_l (bf16 out), r = x@W_r^T + b_r ----------
__device__ __forceinline__ void stage_a(const float* __restrict__ x, float* dst,
                                        int bm, int k0, int wv, int lane, int Mrows)
{
#pragma unroll
    for (int p = 0; p < 4; p++) {
        int ci = (p * 4 + wv) * 64 + lane;            // chunk 0..1023
        int row = ci >> 3, cc = ci & 7;
        int gr = bm + row; if (gr >= Mrows) gr = Mrows - 1;
        const float* src = x + (size_t)gr * 256 + k0 + ((cc ^ (row & 7)) << 2);
        GLDS(src, (char*)dst + (size_t)(p * 4 + wv) * 1024);
    }
}
__device__ __forceinline__ void stage_b(const unsigned short* __restrict__ W,
                                        unsigned short* dst, int bn, int k0,
                                        int wv, int lane)
{
#pragma unroll
    for (int p = 0; p < 2; p++) {
        int ci = (p * 4 + wv) * 64 + lane;            // chunk 0..511
        int col = ci >> 2, cc = ci & 3;
        const unsigned short* src = W + (size_t)(bn + col) * 256 + k0 +
                                    ((cc ^ (col & 3)) << 3);
        GLDS(src, (char*)dst + (size_t)(p * 4 + wv) * 1024);
    }
}

__global__ __launch_bounds__(256) void gemm_fused(
    const float* __restrict__ x, const unsigned short* __restrict__ Wb,
    const float* __restrict__ b_l, const float* __restrict__ b_r,
    unsigned short* __restrict__ lout, float* __restrict__ rout, int Mrows)
{
    __shared__ float As[2][128 * 32];
    __shared__ unsigned short Bs[2][128 * 32];
    const int tid = threadIdx.x;
    const int lane = tid & 63, wv = tid >> 6;
    const int wr = wv >> 1, wc = wv & 1;
    const int sel = blockIdx.x >> 1;                  // 0 = l, 1 = r
    const int bn = (blockIdx.x & 1) * 128;
    const int bm = blockIdx.y * 128;
    const unsigned short* W = Wb + (size_t)sel * 65536;

    f32x4 acc[4][4];
#pragma unroll
    for (int m = 0; m < 4; m++)
#pragma unroll
        for (int n = 0; n < 4; n++) acc[m][n] = (f32x4)0.f;

    stage_a(x, As[0], bm, 0, wv, lane, Mrows);
    stage_b(W, Bs[0], bn, 0, wv, lane);
    __syncthreads();

    int cur = 0;
#pragma unroll
    for (int t = 0; t < 8; t++) {
        if (t < 7) {
            stage_a(x, As[cur ^ 1], bm, (t + 1) * 32, wv, lane, Mrows);
            stage_b(W, Bs[cur ^ 1], bn, (t + 1) * 32, wv, lane);
        }
        short8 bfr[4];
#pragma unroll
        for (int n = 0; n < 4; n++) {
            int col = wc * 64 + n * 16 + (lane & 15);
            int sc = (lane >> 4) ^ (col & 3);
            bfr[n] = *(const short8*)&Bs[cur][col * 32 + sc * 8];
        }
        short8 afr[4];
#pragma unroll
        for (int m = 0; m < 4; m++) {
            int row = wr * 64 + m * 16 + (lane & 15);
            int c0 = (lane >> 4) * 2;
            const float* ap = &As[cur][row * 32];
            float4 f0 = *(const float4*)&ap[(c0 ^ (row & 7)) << 2];
            float4 f1 = *(const float4*)&ap[((c0 + 1) ^ (row & 7)) << 2];
            union { short8 v; __hip_bfloat162 b2[4]; } u;
            u.b2[0] = __float22bfloat162_rn(make_float2(f0.x, f0.y));
            u.b2[1] = __float22bfloat162_rn(make_float2(f0.z, f0.w));
            u.b2[2] = __float22bfloat162_rn(make_float2(f1.x, f1.y));
            u.b2[3] = __float22bfloat162_rn(make_float2(f1.z, f1.w));
            afr[m] = u.v;
        }
#pragma unroll
        for (int m = 0; m < 4; m++)
#pragma unroll
            for (int n = 0; n < 4; n++)
                acc[m][n] = __builtin_amdgcn_mfma_f32_16x16x32_bf16(
                    afr[m], bfr[n], acc[m][n], 0, 0, 0);
        __syncthreads();
        cur ^= 1;
    }

    const float* bias = sel ? b_r : b_l;
#pragma unroll
    for (int m = 0; m < 4; m++) {
        int grow0 = bm + wr * 64 + m * 16 + (lane >> 4) * 4;
#pragma unroll
        for (int n = 0; n < 4; n++) {
            int gcol = bn + wc * 64 + n * 16 + (lane & 15);
            float bv = bias[gcol];
#pragma unroll
            for (int q = 0; q < 4; q++) {
                int grow = grow0 + q;
                if (grow < Mrows) {
                    float v = acc[m][n][q] + bv;
                    if (sel == 0) lout[(size_t)grow * 256 + gcol] = f2b(v);
                    else          rout[(size_t)grow * 256 + gcol] = v;
                }
            }
        }
    }
}

// ---------- per-node logit parts ----------
// ej2[m][n][h] = (exp(aj), exp(aj)*ld); al[n][h] = dot(r, rel_l); rd[n][h] = dot(r, rel_r)
// (ai cancels in the segment softmax; raw exp is safe: |aj| << 88)
__global__ __launch_bounds__(256) void node_logits(
    const unsigned short* __restrict__ l, const float* __restrict__ r,
    const float* __restrict__ attn, const float* __restrict__ rel_l,
    const float* __restrict__ rel_r,
    float2* __restrict__ ej2, float* __restrict__ al, float* __restrict__ rd,
    int Nn)
{
    int n = blockIdx.x;
    int t = threadIdx.x;
    int h = t >> 6, c = t & 63;
    float lv = b2f(l[(size_t)n * D_ + t]);
    float rv = r[(size_t)n * D_ + t];
    float lr_l = lrelu(lv);
    float wrr = rel_r[h * C_ + c];
    float v2 = lr_l * attn[(0 * H_ + h) * 128 + 64 + c];   // aj m=0
    float v3 = lr_l * attn[(1 * H_ + h) * 128 + 64 + c];   // aj m=1
    float v4 = rv * rel_l[h * C_ + c];
    float v5 = lv * wrr;                                   // ld
    float v6 = rv * wrr;                                   // rd
    v2 = wave_sum(v2); v3 = wave_sum(v3); v4 = wave_sum(v4);
    v5 = wave_sum(v5); v6 = wave_sum(v6);
    if (c == 0) {
        int NH = Nn * H_;
        int nh = n * H_ + h;
        float e0 = __expf(v2), e1 = __expf(v3);
        ej2[0 * NH + nh] = make_float2(e0, e0 * v5);
        ej2[1 * NH + nh] = make_float2(e1, e1 * v5);
        al[nh] = v4;
        rd[nh] = v6;
    }
}

// ---------- CSR build: histogram ----------
__global__ __launch_bounds__(256) void edge_hist(
    const int* __restrict__ ei0, const int* __restrict__ ei1,
    int* __restrict__ hist, int E_, int Nn)
{
    int e = blockIdx.x * 256 + threadIdx.x;
    if (e >= E_) return;
    atomicAdd(&hist[ei0[E_ + e]], 1);
    atomicAdd(&hist[Nn + ei1[E_ + e]], 1);
}

// ---------- CSR build: 3-kernel exclusive scan ----------
__global__ __launch_bounds__(256) void scan_a(
    const int* __restrict__ hist, int* __restrict__ segoff,
    int* __restrict__ bsum, int Nn)
{
    int m = blockIdx.y;
    int gid = blockIdx.x * 256 + threadIdx.x;
    int lane = threadIdx.x & 63, wid = threadIdx.x >> 6;
    int v = (gid < Nn) ? hist[m * Nn + gid] : 0;
    int incl = v;
#pragma unroll
    for (int off = 1; off < 64; off <<= 1) {
        int u = __shfl_up(incl, off);
        if (lane >= off) incl += u;
    }
    __shared__ int ws[4], wo[4];
    if (lane == 63) ws[wid] = incl;
    __syncthreads();
    if (threadIdx.x == 0) {
        int run = 0;
#pragma unroll
        for (int i = 0; i < 4; i++) { wo[i] = run; run += ws[i]; }
        bsum[m * 512 + blockIdx.x] = run;
    }
    __syncthreads();
    if (gid < Nn) segoff[m * Nn + gid] = incl - v + wo[wid];
}

__global__ __launch_bounds__(512) void scan_b(int* __restrict__ bsum, int nb)
{
    int m = blockIdx.x;
    int* b = bsum + m * 512;
    int tid = threadIdx.x, lane = tid & 63, wid = tid >> 6;
    int v = (tid < nb) ? b[tid] : 0;
    int incl = v;
#pragma unroll
    for (int off = 1; off < 64; off <<= 1) {
        int u = __shfl_up(incl, off);
        if (lane >= off) incl += u;
    }
    __shared__ int ws[8], wo[8];
    if (lane == 63) ws[wid] = incl;
    __syncthreads();
    if (tid == 0) {
        int run = 0;
#pragma unroll
        for (int i = 0; i < 8; i++) { wo[i] = run; run += ws[i]; }
    }
    __syncthreads();
    if (tid < nb) b[tid] = incl - v + wo[wid];
}

__global__ __launch_bounds__(256) void scan_c(
    int* __restrict__ segoff, const int* __restrict__ bsum, int Nn)
{
    int m = blockIdx.y;
    int gid = blockIdx.x * 256 + threadIdx.x;
    if (gid < Nn) segoff[m * Nn + gid] += bsum[m * 512 + blockIdx.x];
}

// ---------- CSR build: scatter ----------
__global__ __launch_bounds__(256) void edge_scatter(
    const int* __restrict__ ei0, const int* __restrict__ ei1,
    const int* __restrict__ segoff, int* __restrict__ cursor,
    int* __restrict__ srcs, int E_, int Nn)
{
    int e = blockIdx.x * 256 + threadIdx.x;
    if (e >= E_) return;
    int t0 = ei0[E_ + e];
    int p0 = segoff[t0] + atomicAdd(&cursor[t0], 1);
    srcs[p0] = ei0[e];
    int t1 = ei1[E_ + e];
    int p1 = segoff[Nn + t1] + atomicAdd(&cursor[Nn + t1], 1);
    srcs[E_ + p1] = ei1[e];
}

// ---------- per-(target,head): den/p accumulation + relation beta ----------
__global__ __launch_bounds__(256) void node_softmax(
    const int* __restrict__ hist, const int* __restrict__ segoff,
    const int* __restrict__ srcs, const float2* __restrict__ ej2,
    const float* __restrict__ al, const float* __restrict__ rd,
    float* __restrict__ wm, float* __restrict__ beta2, int Nn, int E_)
{
    int NH = Nn * H_;
    int nh = blockIdx.x * 256 + threadIdx.x;
    if (nh >= NH) return;
    int t = nh >> 2, h = nh & 3;
    float dnv[2], pv[2];
#pragma unroll
    for (int m = 0; m < 2; m++) {
        const int* sp = srcs + (size_t)m * E_;
        int beg = segoff[m * Nn + t];
        int deg = hist[m * Nn + t];
        float den = 0.f, pn = 0.f;
#pragma unroll 4
        for (int j = 0; j < deg; j++) {
            int s = sp[beg + j];
            float2 q = ej2[(size_t)m * NH + s * H_ + h];
            den += q.x;
            pn += q.y;
        }
        dnv[m] = den;
        pv[m] = pn / (den + 1e-16f);
    }
    float a = al[nh];
    float b0 = lrelu(a + pv[0]);
    float b1 = lrelu(a + pv[1]);
    float b2 = lrelu(a + rd[nh]);
    float mm = fmaxf(b0, fmaxf(b1, b2));
    float e0 = __expf(b0 - mm), e1 = __expf(b1 - mm), e2 = __expf(b2 - mm);
    float inv = 1.f / (e0 + e1 + e2);
    wm[nh] = e0 * inv / (dnv[0] + 1e-16f);
    wm[NH + nh] = e1 * inv / (dnv[1] + 1e-16f);
    beta2[nh] = e2 * inv;
}

// ---------- fused aggregation: wave per target ----------
__global__ __launch_bounds__(256) void aggregate(
    const int* __restrict__ hist, const int* __restrict__ segoff,
    const int* __restrict__ srcs, const float2* __restrict__ ej2,
    const float* __restrict__ wm, const float* __restrict__ beta2,
    const unsigned short* __restrict__ l, float* __restrict__ out,
    int Nn, int E_)
{
    int lane = threadIdx.x & 63;
    int t = blockIdx.x * 4 + (threadIdx.x >> 6);
    if (t >= Nn) return;
    int h = lane >> 4;
    int NH = Nn * H_;
    int nh = t * H_ + h;

    float4 acc = *(const float4*)&out[(size_t)t * D_ + lane * 4];  // r row
    float b2 = beta2[nh];
    acc.x *= b2; acc.y *= b2; acc.z *= b2; acc.w *= b2;

#pragma unroll
    for (int m = 0; m < 2; m++) {
        const int* sp = srcs + (size_t)m * E_;
        int beg = segoff[m * Nn + t];
        int deg = hist[m * Nn + t];
        float wmv = wm[(size_t)m * NH + nh];
#pragma unroll 4
        for (int j = 0; j < deg; j++) {
            int s = sp[beg + j];
            float w = ej2[(size_t)m * NH + s * H_ + h].x * wmv;
            ushort4 lv = *(const ushort4*)&l[(size_t)s * D_ + lane * 4];
            acc.x = fmaf(b2f(lv.x), w, acc.x);
            acc.y = fmaf(b2f(lv.y), w, acc.y);
            acc.z = fmaf(b2f(lv.z), w, acc.z);
            acc.w = fmaf(b2f(lv.w), w, acc.w);
        }
    }
    float4 o;
    o.x = fmaxf(acc.x, 0.f); o.y = fmaxf(acc.y, 0.f);
    o.z = fmaxf(acc.z, 0.f); o.w = fmaxf(acc.w, 0.f);
    *(float4*)&out[(size_t)t * D_ + lane * 4] = o;
}

extern "C" void kernel_launch(void* const* d_in, const int* in_sizes, int n_in,
                              void* d_out, int out_size, void* d_ws, size_t ws_size,
                              hipStream_t stream) {
    const float* x     = (const float*)d_in[0];
    const int*   ei0   = (const int*)d_in[1];
    const int*   ei1   = (const int*)d_in[2];
    const float* W_l   = (const float*)d_in[3];
    const float* b_l   = (const float*)d_in[4];
    const float* W_r   = (const float*)d_in[5];
    const float* b_r   = (const float*)d_in[6];
    const float* attn  = (const float*)d_in[7];
    const float* rel_l = (const float*)d_in[8];
    const float* rel_r = (const float*)d_in[9];
    float* out = (float*)d_out;   // r -> beta2*r + aggregation -> relu (in place)

    const int Nn = in_sizes[0] / D_;        // 100000
    const int E_ = in_sizes[1] / 2;         // 800000
    const size_t ND = (size_t)Nn * D_;
    const int NH = Nn * H_;

    // ---- workspace layout ≈ 76 MB ----
    char* base = (char*)d_ws;
    unsigned short* l = (unsigned short*)base;      size_t off = ND * 2;
    float2* ej2  = (float2*)(base + off); off += (size_t)2 * NH * 8;  // [M][N][H]
    float* wm    = (float*)(base + off);  off += (size_t)2 * NH * 4;
    float* al    = (float*)(base + off);  off += (size_t)NH * 4;
    float* rd    = (float*)(base + off);  off += (size_t)NH * 4;
    float* beta2 = (float*)(base + off);  off += (size_t)NH * 4;
    int* hist    = (int*)(base + off);    off += (size_t)2 * Nn * 4;  // [M][Nn]
    int* cursor  = (int*)(base + off);    off += (size_t)2 * Nn * 4;
    int* segoff  = (int*)(base + off);    off += (size_t)2 * Nn * 4;
    int* bsum    = (int*)(base + off);    off += (size_t)1024 * 4;
    int* srcs    = (int*)(base + off);    off += (size_t)2 * E_ * 4;  // [M][E]
    unsigned short* Wb = (unsigned short*)(base + off); off += (size_t)2 * 65536 * 2;

    // zero hist + cursor (contiguous)
    hipMemsetAsync(hist, 0, (size_t)4 * Nn * 4, stream);

    convert_w<<<128, 256, 0, stream>>>(W_l, W_r, Wb);

    int rowTiles = (Nn + 127) / 128;   // 782
    gemm_fused<<<dim3(4, rowTiles), 256, 0, stream>>>(x, Wb, b_l, b_r, l, out, Nn);

    node_logits<<<Nn, 256, 0, stream>>>(l, out, attn, rel_l, rel_r,
                                        ej2, al, rd, Nn);

    int eb = (E_ + 255) / 256;
    int nb = (Nn + 255) / 256;   // 391
    edge_hist<<<eb, 256, 0, stream>>>(ei0, ei1, hist, E_, Nn);
    scan_a<<<dim3(nb, 2), 256, 0, stream>>>(hist, segoff, bsum, Nn);
    scan_b<<<2, 512, 0, stream>>>(bsum, nb);
    scan_c<<<dim3(nb, 2), 256, 0, stream>>>(segoff, bsum, Nn);
    edge_scatter<<<eb, 256, 0, stream>>>(ei0, ei1, segoff, cursor, srcs, E_, Nn);

    node_softmax<<<(NH + 255) / 256, 256, 0, stream>>>(
        hist, segoff, srcs, ej2, al, rd, wm, beta2, Nn, E_);

    aggregate<<<(Nn + 3) / 4, 256, 0, stream>>>(
        hist, segoff, srcs, ej2, wm, beta2, l, out, Nn, E_);
}

// Round 6
// 482.521 us; speedup vs baseline: 14.2117x; 1.2158x over previous
//
#include <hip/hip_runtime.h>
#include <hip/hip_bf16.h>
#include <math.h>

#define D_ 256
#define H_ 4
#define C_ 64

typedef __attribute__((ext_vector_type(8))) short short8;
typedef __attribute__((ext_vector_type(4))) float f32x4;

// ---------- helpers ----------
__device__ inline float lrelu(float v) { return v >= 0.f ? v : 0.2f * v; }

// bf16 bit helpers
__device__ inline unsigned short f2b(float f) {
    unsigned u = __float_as_uint(f);
    u = (u + 0x7FFFu + ((u >> 16) & 1u)) >> 16;   // round-to-nearest-even
    return (unsigned short)u;
}
__device__ inline float b2f(unsigned short u) {
    return __uint_as_float(((unsigned)u) << 16);
}

#define GLDS(src, dst) __builtin_amdgcn_global_load_lds(                      \
    (const __attribute__((address_space(1))) void*)(src),                     \
    (__attribute__((address_space(3))) void*)(dst), 16, 0, 0)

// ---------- W -> bf16 ----------
__global__ __launch_bounds__(256) void convert_w(
    const float* __restrict__ Wl, const float* __restrict__ Wr,
    unsigned short* __restrict__ Wb)
{
    int i4 = blockIdx.x * 256 + threadIdx.x;          // 0..32767 float4s
    float4 v = (i4 < 16384) ? ((const float4*)Wl)[i4]
                            : ((const float4*)Wr)[i4 - 16384];
    ushort4 u;
    u.x = f2b(v.x); u.y = f2b(v.y); u.z = f2b(v.z); u.w = f2b(v.w);
    ((ushort4*)Wb)[i4] = u;
}

// ---------- fused MFMA GEMM: l = x@W_l^T + b_l (bf16 out), r = x@W_r^T + b_r ----------
__device__ __forceinline__ void stage_a(const float* __restrict__ x, float* dst,
                                        int bm, int k0, int wv, int lane, int Mrows)
{
#pragma unroll
    for (int p = 0; p < 4; p++) {
        int ci = (p * 4 + wv) * 64 + lane;            // chunk 0..1023
        int row = ci >> 3, cc = ci & 7;
        int gr = bm + row; if (gr >= Mrows) gr = Mrows - 1;
        const float* src = x + (size_t)gr * 256 + k0 + ((cc ^ (row & 7)) << 2);
        GLDS(src, (char*)dst + (size_t)(p * 4 + wv) * 1024);
    }
}
__device__ __forceinline__ void stage_b(const unsigned short* __restrict__ W,
                                        unsigned short* dst, int bn, int k0,
                                        int wv, int lane)
{
#pragma unroll
    for (int p = 0; p < 2; p++) {
        int ci = (p * 4 + wv) * 64 + lane;            // chunk 0..511
        int col = ci >> 2, cc = ci & 3;
        const unsigned short* src = W + (size_t)(bn + col) * 256 + k0 +
                                    ((cc ^ (col & 3)) << 3);
        GLDS(src, (char*)dst + (size_t)(p * 4 + wv) * 1024);
    }
}

__global__ __launch_bounds__(256) void gemm_fused(
    const float* __restrict__ x, const unsigned short* __restrict__ Wb,
    const float* __restrict__ b_l, const float* __restrict__ b_r,
    unsigned short* __restrict__ lout, float* __restrict__ rout, int Mrows)
{
    __shared__ float As[2][128 * 32];
    __shared__ unsigned short Bs[2][128 * 32];
    const int tid = threadIdx.x;
    const int lane = tid & 63, wv = tid >> 6;
    const int wr = wv >> 1, wc = wv & 1;
    const int sel = blockIdx.x >> 1;                  // 0 = l, 1 = r
    const int bn = (blockIdx.x & 1) * 128;
    const int bm = blockIdx.y * 128;
    const unsigned short* W = Wb + (size_t)sel * 65536;

    f32x4 acc[4][4];
#pragma unroll
    for (int m = 0; m < 4; m++)
#pragma unroll
        for (int n = 0; n < 4; n++) acc[m][n] = (f32x4)0.f;

    stage_a(x, As[0], bm, 0, wv, lane, Mrows);
    stage_b(W, Bs[0], bn, 0, wv, lane);
    __syncthreads();

    int cur = 0;
#pragma unroll
    for (int t = 0; t < 8; t++) {
        if (t < 7) {
            stage_a(x, As[cur ^ 1], bm, (t + 1) * 32, wv, lane, Mrows);
            stage_b(W, Bs[cur ^ 1], bn, (t + 1) * 32, wv, lane);
        }
        short8 bfr[4];
#pragma unroll
        for (int n = 0; n < 4; n++) {
            int col = wc * 64 + n * 16 + (lane & 15);
            int sc = (lane >> 4) ^ (col & 3);
            bfr[n] = *(const short8*)&Bs[cur][col * 32 + sc * 8];
        }
        short8 afr[4];
#pragma unroll
        for (int m = 0; m < 4; m++) {
            int row = wr * 64 + m * 16 + (lane & 15);
            int c0 = (lane >> 4) * 2;
            const float* ap = &As[cur][row * 32];
            float4 f0 = *(const float4*)&ap[(c0 ^ (row & 7)) << 2];
            float4 f1 = *(const float4*)&ap[((c0 + 1) ^ (row & 7)) << 2];
            union { short8 v; __hip_bfloat162 b2[4]; } u;
            u.b2[0] = __float22bfloat162_rn(make_float2(f0.x, f0.y));
            u.b2[1] = __float22bfloat162_rn(make_float2(f0.z, f0.w));
            u.b2[2] = __float22bfloat162_rn(make_float2(f1.x, f1.y));
            u.b2[3] = __float22bfloat162_rn(make_float2(f1.z, f1.w));
            afr[m] = u.v;
        }
#pragma unroll
        for (int m = 0; m < 4; m++)
#pragma unroll
            for (int n = 0; n < 4; n++)
                acc[m][n] = __builtin_amdgcn_mfma_f32_16x16x32_bf16(
                    afr[m], bfr[n], acc[m][n], 0, 0, 0);
        __syncthreads();
        cur ^= 1;
    }

    const float* bias = sel ? b_r : b_l;
#pragma unroll
    for (int m = 0; m < 4; m++) {
        int grow0 = bm + wr * 64 + m * 16 + (lane >> 4) * 4;
#pragma unroll
        for (int n = 0; n < 4; n++) {
            int gcol = bn + wc * 64 + n * 16 + (lane & 15);
            float bv = bias[gcol];
#pragma unroll
            for (int q = 0; q < 4; q++) {
                int grow = grow0 + q;
                if (grow < Mrows) {
                    float v = acc[m][n][q] + bv;
                    if (sel == 0) lout[(size_t)grow * 256 + gcol] = f2b(v);
                    else          rout[(size_t)grow * 256 + gcol] = v;
                }
            }
        }
    }
}

// ---------- per-node logit parts: wave per node, vectorized ----------
// ej2[m][n][h] = (exp(aj), exp(aj)*ld); al[n][h] = dot(r, rel_l); rd[n][h] = dot(r, rel_r)
__global__ __launch_bounds__(256) void node_logits(
    const unsigned short* __restrict__ l, const float* __restrict__ r,
    const float* __restrict__ attn, const float* __restrict__ rel_l,
    const float* __restrict__ rel_r,
    float2* __restrict__ ej2, float* __restrict__ al, float* __restrict__ rd,
    int Nn)
{
    int lane = threadIdx.x & 63;
    int n = blockIdx.x * 4 + (threadIdx.x >> 6);
    if (n >= Nn) return;
    int h = lane >> 4, q = lane & 15;

    ushort4 lv4 = *(const ushort4*)&l[(size_t)n * D_ + lane * 4];
    float4 rv4 = *(const float4*)&r[(size_t)n * D_ + lane * 4];
    float4 a0 = *(const float4*)&attn[(0 * H_ + h) * 128 + 64 + q * 4];
    float4 a1 = *(const float4*)&attn[(1 * H_ + h) * 128 + 64 + q * 4];
    float4 wl = *(const float4*)&rel_l[h * C_ + q * 4];
    float4 wr = *(const float4*)&rel_r[h * C_ + q * 4];

    float lf[4] = { b2f(lv4.x), b2f(lv4.y), b2f(lv4.z), b2f(lv4.w) };
    float rf[4] = { rv4.x, rv4.y, rv4.z, rv4.w };
    float af0[4] = { a0.x, a0.y, a0.z, a0.w };
    float af1[4] = { a1.x, a1.y, a1.z, a1.w };
    float wlf[4] = { wl.x, wl.y, wl.z, wl.w };
    float wrf[4] = { wr.x, wr.y, wr.z, wr.w };

    float v2 = 0.f, v3 = 0.f, v4 = 0.f, v5 = 0.f, v6 = 0.f;
#pragma unroll
    for (int k = 0; k < 4; k++) {
        float ll = lrelu(lf[k]);
        v2 = fmaf(ll, af0[k], v2);
        v3 = fmaf(ll, af1[k], v3);
        v4 = fmaf(rf[k], wlf[k], v4);
        v5 = fmaf(lf[k], wrf[k], v5);
        v6 = fmaf(rf[k], wrf[k], v6);
    }
#pragma unroll
    for (int off = 1; off < 16; off <<= 1) {
        v2 += __shfl_xor(v2, off);
        v3 += __shfl_xor(v3, off);
        v4 += __shfl_xor(v4, off);
        v5 += __shfl_xor(v5, off);
        v6 += __shfl_xor(v6, off);
    }
    if (q == 0) {
        int NH = Nn * H_;
        int nh = n * H_ + h;
        float e0 = __expf(v2), e1 = __expf(v3);
        ej2[nh]      = make_float2(e0, e0 * v5);
        ej2[NH + nh] = make_float2(e1, e1 * v5);
        al[nh] = v4;
        rd[nh] = v6;
    }
}

// ---------- CSR build: histogram ----------
__global__ __launch_bounds__(256) void edge_hist(
    const int* __restrict__ ei0, const int* __restrict__ ei1,
    int* __restrict__ hist, int E_, int Nn)
{
    int e = blockIdx.x * 256 + threadIdx.x;
    if (e >= E_) return;
    atomicAdd(&hist[ei0[E_ + e]], 1);
    atomicAdd(&hist[Nn + ei1[E_ + e]], 1);
}

// ---------- CSR build: 3-kernel exclusive scan ----------
__global__ __launch_bounds__(256) void scan_a(
    const int* __restrict__ hist, int* __restrict__ segoff,
    int* __restrict__ bsum, int Nn)
{
    int m = blockIdx.y;
    int gid = blockIdx.x * 256 + threadIdx.x;
    int lane = threadIdx.x & 63, wid = threadIdx.x >> 6;
    int v = (gid < Nn) ? hist[m * Nn + gid] : 0;
    int incl = v;
#pragma unroll
    for (int off = 1; off < 64; off <<= 1) {
        int u = __shfl_up(incl, off);
        if (lane >= off) incl += u;
    }
    __shared__ int ws[4], wo[4];
    if (lane == 63) ws[wid] = incl;
    __syncthreads();
    if (threadIdx.x == 0) {
        int run = 0;
#pragma unroll
        for (int i = 0; i < 4; i++) { wo[i] = run; run += ws[i]; }
        bsum[m * 512 + blockIdx.x] = run;
    }
    __syncthreads();
    if (gid < Nn) segoff[m * Nn + gid] = incl - v + wo[wid];
}

__global__ __launch_bounds__(512) void scan_b(int* __restrict__ bsum, int nb)
{
    int m = blockIdx.x;
    int* b = bsum + m * 512;
    int tid = threadIdx.x, lane = tid & 63, wid = tid >> 6;
    int v = (tid < nb) ? b[tid] : 0;
    int incl = v;
#pragma unroll
    for (int off = 1; off < 64; off <<= 1) {
        int u = __shfl_up(incl, off);
        if (lane >= off) incl += u;
    }
    __shared__ int ws[8], wo[8];
    if (lane == 63) ws[wid] = incl;
    __syncthreads();
    if (tid == 0) {
        int run = 0;
#pragma unroll
        for (int i = 0; i < 8; i++) { wo[i] = run; run += ws[i]; }
    }
    __syncthreads();
    if (tid < nb) b[tid] = incl - v + wo[wid];
}

__global__ __launch_bounds__(256) void scan_c(
    int* __restrict__ segoff, const int* __restrict__ bsum, int Nn)
{
    int m = blockIdx.y;
    int gid = blockIdx.x * 256 + threadIdx.x;
    if (gid < Nn) segoff[m * Nn + gid] += bsum[m * 512 + blockIdx.x];
}

// ---------- CSR build: scatter ----------
__global__ __launch_bounds__(256) void edge_scatter(
    const int* __restrict__ ei0, const int* __restrict__ ei1,
    const int* __restrict__ segoff, int* __restrict__ cursor,
    int* __restrict__ srcs, int E_, int Nn)
{
    int e = blockIdx.x * 256 + threadIdx.x;
    if (e >= E_) return;
    int t0 = ei0[E_ + e];
    int p0 = segoff[t0] + atomicAdd(&cursor[t0], 1);
    srcs[p0] = ei0[e];
    int t1 = ei1[E_ + e];
    int p1 = segoff[Nn + t1] + atomicAdd(&cursor[Nn + t1], 1);
    srcs[E_ + p1] = ei1[e];
}

// ---------- fused softmax-stats + beta + aggregation: wave per target ----------
__global__ __launch_bounds__(256) void aggregate(
    const int* __restrict__ hist, const int* __restrict__ segoff,
    const int* __restrict__ srcs, const float2* __restrict__ ej2,
    const float* __restrict__ al, const float* __restrict__ rd,
    const float* __restrict__ r, const unsigned short* __restrict__ l,
    float* __restrict__ out, int Nn, int E_)
{
    int lane = threadIdx.x & 63;
    int t = blockIdx.x * 4 + (threadIdx.x >> 6);
    if (t >= Nn) return;
    int h = lane >> 4, q = lane & 15;
    int NH = Nn * H_;
    int nh = t * H_ + h;

    // ---- phase 1: den/p per metapath; 16 lanes of each h-group split edges ----
    int beg0 = segoff[t],      deg0 = hist[t];
    int beg1 = segoff[Nn + t], deg1 = hist[Nn + t];
    float den0 = 0.f, pn0 = 0.f, den1 = 0.f, pn1 = 0.f;
    for (int j = q; j < deg0; j += 16) {
        float2 v = ej2[(size_t)srcs[beg0 + j] * H_ + h];
        den0 += v.x; pn0 += v.y;
    }
    for (int j = q; j < deg1; j += 16) {
        float2 v = ej2[(size_t)NH + (size_t)srcs[E_ + beg1 + j] * H_ + h];
        den1 += v.x; pn1 += v.y;
    }
#pragma unroll
    for (int off = 1; off < 16; off <<= 1) {
        den0 += __shfl_xor(den0, off); pn0 += __shfl_xor(pn0, off);
        den1 += __shfl_xor(den1, off); pn1 += __shfl_xor(pn1, off);
    }

    float a = al[nh];
    float b0 = lrelu(a + pn0 / (den0 + 1e-16f));
    float b1 = lrelu(a + pn1 / (den1 + 1e-16f));
    float b2 = lrelu(a + rd[nh]);
    float mm = fmaxf(b0, fmaxf(b1, b2));
    float e0 = __expf(b0 - mm), e1 = __expf(b1 - mm), e2 = __expf(b2 - mm);
    float inv = 1.f / (e0 + e1 + e2);
    float wm0 = e0 * inv / (den0 + 1e-16f);
    float wm1 = e1 * inv / (den1 + 1e-16f);
    float b2v = e2 * inv;

    // ---- phase 2: weighted row accumulation ----
    float4 acc = *(const float4*)&r[(size_t)t * D_ + lane * 4];
    acc.x *= b2v; acc.y *= b2v; acc.z *= b2v; acc.w *= b2v;

#pragma unroll
    for (int m = 0; m < 2; m++) {
        const int* sp = srcs + (size_t)m * E_;
        int beg = m ? beg1 : beg0;
        int deg = m ? deg1 : deg0;
        float wmv = m ? wm1 : wm0;
        const float2* ep = ej2 + (size_t)m * NH;
#pragma unroll 4
        for (int j = 0; j < deg; j++) {
            int s = sp[beg + j];
            float w = ep[(size_t)s * H_ + h].x * wmv;
            ushort4 lv = *(const ushort4*)&l[(size_t)s * D_ + lane * 4];
            acc.x = fmaf(b2f(lv.x), w, acc.x);
            acc.y = fmaf(b2f(lv.y), w, acc.y);
            acc.z = fmaf(b2f(lv.z), w, acc.z);
            acc.w = fmaf(b2f(lv.w), w, acc.w);
        }
    }
    float4 o;
    o.x = fmaxf(acc.x, 0.f); o.y = fmaxf(acc.y, 0.f);
    o.z = fmaxf(acc.z, 0.f); o.w = fmaxf(acc.w, 0.f);
    *(float4*)&out[(size_t)t * D_ + lane * 4] = o;
}

extern "C" void kernel_launch(void* const* d_in, const int* in_sizes, int n_in,
                              void* d_out, int out_size, void* d_ws, size_t ws_size,
                              hipStream_t stream) {
    const float* x     = (const float*)d_in[0];
    const int*   ei0   = (const int*)d_in[1];
    const int*   ei1   = (const int*)d_in[2];
    const float* W_l   = (const float*)d_in[3];
    const float* b_l   = (const float*)d_in[4];
    const float* W_r   = (const float*)d_in[5];
    const float* b_r   = (const float*)d_in[6];
    const float* attn  = (const float*)d_in[7];
    const float* rel_l = (const float*)d_in[8];
    const float* rel_r = (const float*)d_in[9];
    float* out = (float*)d_out;   // r (from gemm), then final output in place

    const int Nn = in_sizes[0] / D_;        // 100000
    const int E_ = in_sizes[1] / 2;         // 800000
    const size_t ND = (size_t)Nn * D_;
    const int NH = Nn * H_;

    // ---- workspace layout ≈ 70 MB ----
    char* base = (char*)d_ws;
    unsigned short* l = (unsigned short*)base;      size_t off = ND * 2;
    float2* ej2  = (float2*)(base + off); off += (size_t)2 * NH * 8;  // [M][N][H]
    float* al    = (float*)(base + off);  off += (size_t)NH * 4;
    float* rd    = (float*)(base + off);  off += (size_t)NH * 4;
    int* hist    = (int*)(base + off);    off += (size_t)2 * Nn * 4;  // [M][Nn]
    int* cursor  = (int*)(base + off);    off += (size_t)2 * Nn * 4;
    int* segoff  = (int*)(base + off);    off += (size_t)2 * Nn * 4;
    int* bsum    = (int*)(base + off);    off += (size_t)1024 * 4;
    int* srcs    = (int*)(base + off);    off += (size_t)2 * E_ * 4;  // [M][E]
    unsigned short* Wb = (unsigned short*)(base + off); off += (size_t)2 * 65536 * 2;

    // zero hist + cursor (contiguous)
    hipMemsetAsync(hist, 0, (size_t)4 * Nn * 4, stream);

    convert_w<<<128, 256, 0, stream>>>(W_l, W_r, Wb);

    int rowTiles = (Nn + 127) / 128;   // 782
    gemm_fused<<<dim3(4, rowTiles), 256, 0, stream>>>(x, Wb, b_l, b_r, l, out, Nn);

    node_logits<<<(Nn + 3) / 4, 256, 0, stream>>>(l, out, attn, rel_l, rel_r,
                                                  ej2, al, rd, Nn);

    int eb = (E_ + 255) / 256;
    int nb = (Nn + 255) / 256;   // 391
    edge_hist<<<eb, 256, 0, stream>>>(ei0, ei1, hist, E_, Nn);
    scan_a<<<dim3(nb, 2), 256, 0, stream>>>(hist, segoff, bsum, Nn);
    scan_b<<<2, 512, 0, stream>>>(bsum, nb);
    scan_c<<<dim3(nb, 2), 256, 0, stream>>>(segoff, bsum, Nn);
    edge_scatter<<<eb, 256, 0, stream>>>(ei0, ei1, segoff, cursor, srcs, E_, Nn);

    aggregate<<<(Nn + 3) / 4, 256, 0, stream>>>(
        hist, segoff, srcs, ej2, al, rd, out, l, out, Nn, E_);
}

// Round 7
// 459.683 us; speedup vs baseline: 14.9177x; 1.0497x over previous
//
#include <hip/hip_runtime.h>
#include <hip/hip_bf16.h>
#include <math.h>

#define D_ 256
#define H_ 4
#define C_ 64

typedef __attribute__((ext_vector_type(8))) short short8;
typedef __attribute__((ext_vector_type(4))) float f32x4;

// ---------- helpers ----------
__device__ inline float lrelu(float v) { return v >= 0.f ? v : 0.2f * v; }

// bf16 bit helpers
__device__ inline unsigned short f2b(float f) {
    unsigned u = __float_as_uint(f);
    u = (u + 0x7FFFu + ((u >> 16) & 1u)) >> 16;   // round-to-nearest-even
    return (unsigned short)u;
}
__device__ inline float b2f(unsigned short u) {
    return __uint_as_float(((unsigned)u) << 16);
}

#define GLDS(src, dst) __builtin_amdgcn_global_load_lds(                      \
    (const __attribute__((address_space(1))) void*)(src),                     \
    (__attribute__((address_space(3))) void*)(dst), 16, 0, 0)

// ---------- W -> bf16 ----------
__global__ __launch_bounds__(256) void convert_w(
    const float* __restrict__ Wl, const float* __restrict__ Wr,
    unsigned short* __restrict__ Wb)
{
    int i4 = blockIdx.x * 256 + threadIdx.x;          // 0..32767 float4s
    float4 v = (i4 < 16384) ? ((const float4*)Wl)[i4]
                            : ((const float4*)Wr)[i4 - 16384];
    ushort4 u;
    u.x = f2b(v.x); u.y = f2b(v.y); u.z = f2b(v.z); u.w = f2b(v.w);
    ((ushort4*)Wb)[i4] = u;
}

// ---------- fused MFMA GEMM: l = x@W_l^T + b_l (bf16), r = x@W_r^T + b_r ----------
__device__ __forceinline__ void stage_a(const float* __restrict__ x, float* dst,
                                        int bm, int k0, int wv, int lane, int Mrows)
{
#pragma unroll
    for (int p = 0; p < 4; p++) {
        int ci = (p * 4 + wv) * 64 + lane;            // chunk 0..1023
        int row = ci >> 3, cc = ci & 7;
        int gr = bm + row; if (gr >= Mrows) gr = Mrows - 1;
        const float* src = x + (size_t)gr * 256 + k0 + ((cc ^ (row & 7)) << 2);
        GLDS(src, (char*)dst + (size_t)(p * 4 + wv) * 1024);
    }
}
__device__ __forceinline__ void stage_b(const unsigned short* __restrict__ W,
                                        unsigned short* dst, int bn, int k0,
                                        int wv, int lane)
{
#pragma unroll
    for (int p = 0; p < 2; p++) {
        int ci = (p * 4 + wv) * 64 + lane;            // chunk 0..511
        int col = ci >> 2, cc = ci & 3;
        const unsigned short* src = W + (size_t)(bn + col) * 256 + k0 +
                                    ((cc ^ (col & 3)) << 3);
        GLDS(src, (char*)dst + (size_t)(p * 4 + wv) * 1024);
    }
}

template <bool RB16>
__global__ __launch_bounds__(256) void gemm_fused(
    const float* __restrict__ x, const unsigned short* __restrict__ Wb,
    const float* __restrict__ b_l, const float* __restrict__ b_r,
    unsigned short* __restrict__ lout, void* __restrict__ rout, int Mrows)
{
    __shared__ float As[2][128 * 32];
    __shared__ unsigned short Bs[2][128 * 32];
    const int tid = threadIdx.x;
    const int lane = tid & 63, wv = tid >> 6;
    const int wr = wv >> 1, wc = wv & 1;
    const int sel = blockIdx.x >> 1;                  // 0 = l, 1 = r
    const int bn = (blockIdx.x & 1) * 128;
    const int bm = blockIdx.y * 128;
    const unsigned short* W = Wb + (size_t)sel * 65536;

    f32x4 acc[4][4];
#pragma unroll
    for (int m = 0; m < 4; m++)
#pragma unroll
        for (int n = 0; n < 4; n++) acc[m][n] = (f32x4)0.f;

    stage_a(x, As[0], bm, 0, wv, lane, Mrows);
    stage_b(W, Bs[0], bn, 0, wv, lane);
    __syncthreads();

    int cur = 0;
#pragma unroll
    for (int t = 0; t < 8; t++) {
        if (t < 7) {
            stage_a(x, As[cur ^ 1], bm, (t + 1) * 32, wv, lane, Mrows);
            stage_b(W, Bs[cur ^ 1], bn, (t + 1) * 32, wv, lane);
        }
        short8 bfr[4];
#pragma unroll
        for (int n = 0; n < 4; n++) {
            int col = wc * 64 + n * 16 + (lane & 15);
            int sc = (lane >> 4) ^ (col & 3);
            bfr[n] = *(const short8*)&Bs[cur][col * 32 + sc * 8];
        }
        short8 afr[4];
#pragma unroll
        for (int m = 0; m < 4; m++) {
            int row = wr * 64 + m * 16 + (lane & 15);
            int c0 = (lane >> 4) * 2;
            const float* ap = &As[cur][row * 32];
            float4 f0 = *(const float4*)&ap[(c0 ^ (row & 7)) << 2];
            float4 f1 = *(const float4*)&ap[((c0 + 1) ^ (row & 7)) << 2];
            union { short8 v; __hip_bfloat162 b2[4]; } u;
            u.b2[0] = __float22bfloat162_rn(make_float2(f0.x, f0.y));
            u.b2[1] = __float22bfloat162_rn(make_float2(f0.z, f0.w));
            u.b2[2] = __float22bfloat162_rn(make_float2(f1.x, f1.y));
            u.b2[3] = __float22bfloat162_rn(make_float2(f1.z, f1.w));
            afr[m] = u.v;
        }
#pragma unroll
        for (int m = 0; m < 4; m++)
#pragma unroll
            for (int n = 0; n < 4; n++)
                acc[m][n] = __builtin_amdgcn_mfma_f32_16x16x32_bf16(
                    afr[m], bfr[n], acc[m][n], 0, 0, 0);
        __syncthreads();
        cur ^= 1;
    }

    const float* bias = sel ? b_r : b_l;
#pragma unroll
    for (int m = 0; m < 4; m++) {
        int grow0 = bm + wr * 64 + m * 16 + (lane >> 4) * 4;
#pragma unroll
        for (int n = 0; n < 4; n++) {
            int gcol = bn + wc * 64 + n * 16 + (lane & 15);
            float bv = bias[gcol];
#pragma unroll
            for (int q = 0; q < 4; q++) {
                int grow = grow0 + q;
                if (grow < Mrows) {
                    float v = acc[m][n][q] + bv;
                    if (sel == 0) {
                        lout[(size_t)grow * 256 + gcol] = f2b(v);
                    } else {
                        if (RB16) ((unsigned short*)rout)[(size_t)grow * 256 + gcol] = f2b(v);
                        else      ((float*)rout)[(size_t)grow * 256 + gcol] = v;
                    }
                }
            }
        }
    }
}

// ---------- per-node logit parts: wave per node, vectorized ----------
// ej2[m][n][h] = (exp(aj), exp(aj)*ld); al[n][h] = dot(r, rel_l); rd[n][h] = dot(r, rel_r)
template <bool RB16>
__global__ __launch_bounds__(256) void node_logits(
    const unsigned short* __restrict__ l, const void* __restrict__ rv,
    const float* __restrict__ attn, const float* __restrict__ rel_l,
    const float* __restrict__ rel_r,
    float2* __restrict__ ej2, float* __restrict__ al, float* __restrict__ rd,
    int Nn)
{
    int lane = threadIdx.x & 63;
    int n = blockIdx.x * 4 + (threadIdx.x >> 6);
    if (n >= Nn) return;
    int h = lane >> 4, q = lane & 15;

    ushort4 lv4 = *(const ushort4*)&l[(size_t)n * D_ + lane * 4];
    float rf[4];
    if (RB16) {
        ushort4 ru = ((const ushort4*)rv)[(size_t)n * 64 + lane];
        rf[0] = b2f(ru.x); rf[1] = b2f(ru.y); rf[2] = b2f(ru.z); rf[3] = b2f(ru.w);
    } else {
        float4 rv4 = ((const float4*)rv)[(size_t)n * 64 + lane];
        rf[0] = rv4.x; rf[1] = rv4.y; rf[2] = rv4.z; rf[3] = rv4.w;
    }
    float4 a0 = *(const float4*)&attn[(0 * H_ + h) * 128 + 64 + q * 4];
    float4 a1 = *(const float4*)&attn[(1 * H_ + h) * 128 + 64 + q * 4];
    float4 wl = *(const float4*)&rel_l[h * C_ + q * 4];
    float4 wr = *(const float4*)&rel_r[h * C_ + q * 4];

    float lf[4] = { b2f(lv4.x), b2f(lv4.y), b2f(lv4.z), b2f(lv4.w) };
    float af0[4] = { a0.x, a0.y, a0.z, a0.w };
    float af1[4] = { a1.x, a1.y, a1.z, a1.w };
    float wlf[4] = { wl.x, wl.y, wl.z, wl.w };
    float wrf[4] = { wr.x, wr.y, wr.z, wr.w };

    float v2 = 0.f, v3 = 0.f, v4 = 0.f, v5 = 0.f, v6 = 0.f;
#pragma unroll
    for (int k = 0; k < 4; k++) {
        float ll = lrelu(lf[k]);
        v2 = fmaf(ll, af0[k], v2);
        v3 = fmaf(ll, af1[k], v3);
        v4 = fmaf(rf[k], wlf[k], v4);
        v5 = fmaf(lf[k], wrf[k], v5);
        v6 = fmaf(rf[k], wrf[k], v6);
    }
#pragma unroll
    for (int off = 1; off < 16; off <<= 1) {
        v2 += __shfl_xor(v2, off);
        v3 += __shfl_xor(v3, off);
        v4 += __shfl_xor(v4, off);
        v5 += __shfl_xor(v5, off);
        v6 += __shfl_xor(v6, off);
    }
    if (q == 0) {
        int NH = Nn * H_;
        int nh = n * H_ + h;
        float e0 = __expf(v2), e1 = __expf(v3);
        ej2[nh]      = make_float2(e0, e0 * v5);
        ej2[NH + nh] = make_float2(e1, e1 * v5);
        al[nh] = v4;
        rd[nh] = v6;
    }
}

// ---------- CSR build: histogram ----------
__global__ __launch_bounds__(256) void edge_hist(
    const int* __restrict__ ei0, const int* __restrict__ ei1,
    int* __restrict__ hist, int E_, int Nn)
{
    int e = blockIdx.x * 256 + threadIdx.x;
    if (e >= E_) return;
    atomicAdd(&hist[ei0[E_ + e]], 1);
    atomicAdd(&hist[Nn + ei1[E_ + e]], 1);
}

// ---------- CSR build: 3-kernel exclusive scan ----------
__global__ __launch_bounds__(256) void scan_a(
    const int* __restrict__ hist, int* __restrict__ segoff,
    int* __restrict__ bsum, int Nn)
{
    int m = blockIdx.y;
    int gid = blockIdx.x * 256 + threadIdx.x;
    int lane = threadIdx.x & 63, wid = threadIdx.x >> 6;
    int v = (gid < Nn) ? hist[m * Nn + gid] : 0;
    int incl = v;
#pragma unroll
    for (int off = 1; off < 64; off <<= 1) {
        int u = __shfl_up(incl, off);
        if (lane >= off) incl += u;
    }
    __shared__ int ws[4], wo[4];
    if (lane == 63) ws[wid] = incl;
    __syncthreads();
    if (threadIdx.x == 0) {
        int run = 0;
#pragma unroll
        for (int i = 0; i < 4; i++) { wo[i] = run; run += ws[i]; }
        bsum[m * 512 + blockIdx.x] = run;
    }
    __syncthreads();
    if (gid < Nn) segoff[m * Nn + gid] = incl - v + wo[wid];
}

__global__ __launch_bounds__(512) void scan_b(int* __restrict__ bsum, int nb)
{
    int m = blockIdx.x;
    int* b = bsum + m * 512;
    int tid = threadIdx.x, lane = tid & 63, wid = tid >> 6;
    int v = (tid < nb) ? b[tid] : 0;
    int incl = v;
#pragma unroll
    for (int off = 1; off < 64; off <<= 1) {
        int u = __shfl_up(incl, off);
        if (lane >= off) incl += u;
    }
    __shared__ int ws[8], wo[8];
    if (lane == 63) ws[wid] = incl;
    __syncthreads();
    if (tid == 0) {
        int run = 0;
#pragma unroll
        for (int i = 0; i < 8; i++) { wo[i] = run; run += ws[i]; }
    }
    __syncthreads();
    if (tid < nb) b[tid] = incl - v + wo[wid];
}

__global__ __launch_bounds__(256) void scan_c(
    int* __restrict__ segoff, const int* __restrict__ bsum, int Nn)
{
    int m = blockIdx.y;
    int gid = blockIdx.x * 256 + threadIdx.x;
    if (gid < Nn) segoff[m * Nn + gid] += bsum[m * 512 + blockIdx.x];
}

// ---------- CSR build: scatter ----------
__global__ __launch_bounds__(256) void edge_scatter(
    const int* __restrict__ ei0, const int* __restrict__ ei1,
    const int* __restrict__ segoff, int* __restrict__ cursor,
    int* __restrict__ srcs, int E_, int Nn)
{
    int e = blockIdx.x * 256 + threadIdx.x;
    if (e >= E_) return;
    int t0 = ei0[E_ + e];
    int p0 = segoff[t0] + atomicAdd(&cursor[t0], 1);
    srcs[p0] = ei0[e];
    int t1 = ei1[E_ + e];
    int p1 = segoff[Nn + t1] + atomicAdd(&cursor[Nn + t1], 1);
    srcs[E_ + p1] = ei1[e];
}

// ---------- single-pass aggregation: wave per target ----------
// acc_m = sum exp*l[src]; den/pn broadcast per h-group; beta + combine at end.
template <bool RB16>
__global__ __launch_bounds__(256) void aggregate(
    const int* __restrict__ hist, const int* __restrict__ segoff,
    const int* __restrict__ srcs, const float2* __restrict__ ej2,
    const float* __restrict__ al, const float* __restrict__ rd,
    const void* __restrict__ rv, const unsigned short* __restrict__ l,
    float* __restrict__ out, int Nn, int E_)
{
    int lane = threadIdx.x & 63;
    int t = blockIdx.x * 4 + (threadIdx.x >> 6);
    if (t >= Nn) return;
    int h = lane >> 4;
    int NH = Nn * H_;
    int nh = t * H_ + h;

    int beg0 = segoff[t],      deg0 = hist[t];
    int beg1 = segoff[Nn + t], deg1 = hist[Nn + t];

    float4 acc0 = make_float4(0.f, 0.f, 0.f, 0.f);
    float4 acc1 = make_float4(0.f, 0.f, 0.f, 0.f);
    float den0 = 0.f, pn0 = 0.f, den1 = 0.f, pn1 = 0.f;

#pragma unroll 4
    for (int j = 0; j < deg0; j++) {
        int s = srcs[beg0 + j];
        float2 v = ej2[(size_t)s * H_ + h];
        den0 += v.x; pn0 += v.y;
        ushort4 lv = *(const ushort4*)&l[(size_t)s * D_ + lane * 4];
        acc0.x = fmaf(b2f(lv.x), v.x, acc0.x);
        acc0.y = fmaf(b2f(lv.y), v.x, acc0.y);
        acc0.z = fmaf(b2f(lv.z), v.x, acc0.z);
        acc0.w = fmaf(b2f(lv.w), v.x, acc0.w);
    }
    const float2* ep1 = ej2 + NH;
#pragma unroll 4
    for (int j = 0; j < deg1; j++) {
        int s = srcs[E_ + beg1 + j];
        float2 v = ep1[(size_t)s * H_ + h];
        den1 += v.x; pn1 += v.y;
        ushort4 lv = *(const ushort4*)&l[(size_t)s * D_ + lane * 4];
        acc1.x = fmaf(b2f(lv.x), v.x, acc1.x);
        acc1.y = fmaf(b2f(lv.y), v.x, acc1.y);
        acc1.z = fmaf(b2f(lv.z), v.x, acc1.z);
        acc1.w = fmaf(b2f(lv.w), v.x, acc1.w);
    }

    float a = al[nh];
    float b0 = lrelu(a + pn0 / (den0 + 1e-16f));
    float b1 = lrelu(a + pn1 / (den1 + 1e-16f));
    float b2 = lrelu(a + rd[nh]);
    float mm = fmaxf(b0, fmaxf(b1, b2));
    float e0 = __expf(b0 - mm), e1 = __expf(b1 - mm), e2 = __expf(b2 - mm);
    float inv = 1.f / (e0 + e1 + e2);
    float wm0 = e0 * inv / (den0 + 1e-16f);
    float wm1 = e1 * inv / (den1 + 1e-16f);
    float b2v = e2 * inv;

    float4 rrow;
    if (RB16) {
        ushort4 ru = ((const ushort4*)rv)[(size_t)t * 64 + lane];
        rrow = make_float4(b2f(ru.x), b2f(ru.y), b2f(ru.z), b2f(ru.w));
    } else {
        rrow = ((const float4*)rv)[(size_t)t * 64 + lane];
    }

    float4 o;
    o.x = fmaxf(fmaf(wm0, acc0.x, fmaf(wm1, acc1.x, b2v * rrow.x)), 0.f);
    o.y = fmaxf(fmaf(wm0, acc0.y, fmaf(wm1, acc1.y, b2v * rrow.y)), 0.f);
    o.z = fmaxf(fmaf(wm0, acc0.z, fmaf(wm1, acc1.z, b2v * rrow.z)), 0.f);
    o.w = fmaxf(fmaf(wm0, acc0.w, fmaf(wm1, acc1.w, b2v * rrow.w)), 0.f);
    *(float4*)&out[(size_t)t * D_ + lane * 4] = o;
}

extern "C" void kernel_launch(void* const* d_in, const int* in_sizes, int n_in,
                              void* d_out, int out_size, void* d_ws, size_t ws_size,
                              hipStream_t stream) {
    const float* x     = (const float*)d_in[0];
    const int*   ei0   = (const int*)d_in[1];
    const int*   ei1   = (const int*)d_in[2];
    const float* W_l   = (const float*)d_in[3];
    const float* b_l   = (const float*)d_in[4];
    const float* W_r   = (const float*)d_in[5];
    const float* b_r   = (const float*)d_in[6];
    const float* attn  = (const float*)d_in[7];
    const float* rel_l = (const float*)d_in[8];
    const float* rel_r = (const float*)d_in[9];
    float* out = (float*)d_out;

    const int Nn = in_sizes[0] / D_;        // 100000
    const int E_ = in_sizes[1] / 2;         // 800000
    const size_t ND = (size_t)Nn * D_;
    const int NH = Nn * H_;

    // ---- workspace layout (~70 MB base; +51 MB if bf16-r fits) ----
    char* base = (char*)d_ws;
    unsigned short* l = (unsigned short*)base;      size_t off = ND * 2;
    float2* ej2  = (float2*)(base + off); off += (size_t)2 * NH * 8;  // [M][N][H]
    float* al    = (float*)(base + off);  off += (size_t)NH * 4;
    float* rd    = (float*)(base + off);  off += (size_t)NH * 4;
    int* hist    = (int*)(base + off);    off += (size_t)2 * Nn * 4;  // [M][Nn]
    int* cursor  = (int*)(base + off);    off += (size_t)2 * Nn * 4;
    int* segoff  = (int*)(base + off);    off += (size_t)2 * Nn * 4;
    int* bsum    = (int*)(base + off);    off += (size_t)1024 * 4;
    int* srcs    = (int*)(base + off);    off += (size_t)2 * E_ * 4;  // [M][E]
    unsigned short* Wb = (unsigned short*)(base + off); off += (size_t)2 * 65536 * 2;
    unsigned short* rb = (unsigned short*)(base + off);
    const bool rb16 = (ws_size >= off + ND * 2);    // bf16 r storage fits?
    void* r_any = rb16 ? (void*)rb : (void*)out;

    // zero hist + cursor (contiguous)
    hipMemsetAsync(hist, 0, (size_t)4 * Nn * 4, stream);

    convert_w<<<128, 256, 0, stream>>>(W_l, W_r, Wb);

    int rowTiles = (Nn + 127) / 128;   // 782
    if (rb16)
        gemm_fused<true ><<<dim3(4, rowTiles), 256, 0, stream>>>(
            x, Wb, b_l, b_r, l, r_any, Nn);
    else
        gemm_fused<false><<<dim3(4, rowTiles), 256, 0, stream>>>(
            x, Wb, b_l, b_r, l, r_any, Nn);

    if (rb16)
        node_logits<true ><<<(Nn + 3) / 4, 256, 0, stream>>>(
            l, r_any, attn, rel_l, rel_r, ej2, al, rd, Nn);
    else
        node_logits<false><<<(Nn + 3) / 4, 256, 0, stream>>>(
            l, r_any, attn, rel_l, rel_r, ej2, al, rd, Nn);

    int eb = (E_ + 255) / 256;
    int nb = (Nn + 255) / 256;   // 391
    edge_hist<<<eb, 256, 0, stream>>>(ei0, ei1, hist, E_, Nn);
    scan_a<<<dim3(nb, 2), 256, 0, stream>>>(hist, segoff, bsum, Nn);
    scan_b<<<2, 512, 0, stream>>>(bsum, nb);
    scan_c<<<dim3(nb, 2), 256, 0, stream>>>(segoff, bsum, Nn);
    edge_scatter<<<eb, 256, 0, stream>>>(ei0, ei1, segoff, cursor, srcs, E_, Nn);

    if (rb16)
        aggregate<true ><<<(Nn + 3) / 4, 256, 0, stream>>>(
            hist, segoff, srcs, ej2, al, rd, r_any, l, out, Nn, E_);
    else
        aggregate<false><<<(Nn + 3) / 4, 256, 0, stream>>>(
            hist, segoff, srcs, ej2, al, rd, r_any, l, out, Nn, E_);
}

// Round 8
// 458.813 us; speedup vs baseline: 14.9460x; 1.0019x over previous
//
#include <hip/hip_runtime.h>
#include <hip/hip_bf16.h>
#include <math.h>

#define D_ 256
#define H_ 4
#define C_ 64

typedef __attribute__((ext_vector_type(8))) short short8;
typedef __attribute__((ext_vector_type(4))) float f32x4;

// ---------- helpers ----------
__device__ inline float lrelu(float v) { return v >= 0.f ? v : 0.2f * v; }

// bf16 bit helpers
__device__ inline unsigned short f2b(float f) {
    unsigned u = __float_as_uint(f);
    u = (u + 0x7FFFu + ((u >> 16) & 1u)) >> 16;   // round-to-nearest-even
    return (unsigned short)u;
}
__device__ inline float b2f(unsigned short u) {
    return __uint_as_float(((unsigned)u) << 16);
}

#define GLDS(src, dst) __builtin_amdgcn_global_load_lds(                      \
    (const __attribute__((address_space(1))) void*)(src),                     \
    (__attribute__((address_space(3))) void*)(dst), 16, 0, 0)

// ---------- W (and optionally x) -> bf16 ----------
__global__ __launch_bounds__(256) void convert_wx(
    const float* __restrict__ Wl, const float* __restrict__ Wr,
    const float* __restrict__ x,
    unsigned short* __restrict__ Wb, unsigned short* __restrict__ xb,
    int total4)   // 32768 W float4s + optional Nn*64 x float4s
{
    int gid = blockIdx.x * 256 + threadIdx.x;
    if (gid >= total4) return;
    float4 v;
    ushort4 u;
    if (gid < 16384) {
        v = ((const float4*)Wl)[gid];
        u.x = f2b(v.x); u.y = f2b(v.y); u.z = f2b(v.z); u.w = f2b(v.w);
        ((ushort4*)Wb)[gid] = u;
    } else if (gid < 32768) {
        v = ((const float4*)Wr)[gid - 16384];
        u.x = f2b(v.x); u.y = f2b(v.y); u.z = f2b(v.z); u.w = f2b(v.w);
        ((ushort4*)Wb)[gid] = u;
    } else {
        int i = gid - 32768;
        v = ((const float4*)x)[i];
        u.x = f2b(v.x); u.y = f2b(v.y); u.z = f2b(v.z); u.w = f2b(v.w);
        ((ushort4*)xb)[i] = u;
    }
}

// ---------- staging ----------
__device__ __forceinline__ void stage_a(const float* __restrict__ x, float* dst,
                                        int bm, int k0, int wv, int lane, int Mrows)
{
#pragma unroll
    for (int p = 0; p < 4; p++) {
        int ci = (p * 4 + wv) * 64 + lane;            // chunk 0..1023
        int row = ci >> 3, cc = ci & 7;
        int gr = bm + row; if (gr >= Mrows) gr = Mrows - 1;
        const float* src = x + (size_t)gr * 256 + k0 + ((cc ^ (row & 7)) << 2);
        GLDS(src, (char*)dst + (size_t)(p * 4 + wv) * 1024);
    }
}
__device__ __forceinline__ void stage_a16(const unsigned short* __restrict__ xb,
                                          unsigned short* dst, int bm, int k0,
                                          int wv, int lane, int Mrows)
{
#pragma unroll
    for (int p = 0; p < 2; p++) {
        int ci = (p * 4 + wv) * 64 + lane;            // chunk 0..511
        int row = ci >> 2, cc = ci & 3;
        int gr = bm + row; if (gr >= Mrows) gr = Mrows - 1;
        const unsigned short* src = xb + (size_t)gr * 256 + k0 +
                                    ((cc ^ (row & 3)) << 3);
        GLDS(src, (char*)dst + (size_t)(p * 4 + wv) * 1024);
    }
}
__device__ __forceinline__ void stage_b(const unsigned short* __restrict__ W,
                                        unsigned short* dst, int bn, int k0,
                                        int wv, int lane)
{
#pragma unroll
    for (int p = 0; p < 2; p++) {
        int ci = (p * 4 + wv) * 64 + lane;            // chunk 0..511
        int col = ci >> 2, cc = ci & 3;
        const unsigned short* src = W + (size_t)(bn + col) * 256 + k0 +
                                    ((cc ^ (col & 3)) << 3);
        GLDS(src, (char*)dst + (size_t)(p * 4 + wv) * 1024);
    }
}

// ---------- epilogue (shared) ----------
template <bool RB16>
__device__ __forceinline__ void gemm_epilogue(
    f32x4 (&acc)[4][4], const float* bias, int sel, int bm, int bn,
    int wr, int wc, int lane, unsigned short* lout, void* rout, int Mrows)
{
#pragma unroll
    for (int m = 0; m < 4; m++) {
        int grow0 = bm + wr * 64 + m * 16 + (lane >> 4) * 4;
#pragma unroll
        for (int n = 0; n < 4; n++) {
            int gcol = bn + wc * 64 + n * 16 + (lane & 15);
            float bv = bias[gcol];
#pragma unroll
            for (int q = 0; q < 4; q++) {
                int grow = grow0 + q;
                if (grow < Mrows) {
                    float v = acc[m][n][q] + bv;
                    if (sel == 0) {
                        lout[(size_t)grow * 256 + gcol] = f2b(v);
                    } else {
                        if (RB16) ((unsigned short*)rout)[(size_t)grow * 256 + gcol] = f2b(v);
                        else      ((float*)rout)[(size_t)grow * 256 + gcol] = v;
                    }
                }
            }
        }
    }
}

// ---------- MFMA GEMM, f32-A fallback path ----------
template <bool RB16>
__global__ __launch_bounds__(256) void gemm_fused_f32(
    const float* __restrict__ x, const unsigned short* __restrict__ Wb,
    const float* __restrict__ b_l, const float* __restrict__ b_r,
    unsigned short* __restrict__ lout, void* __restrict__ rout, int Mrows)
{
    __shared__ float As[2][128 * 32];
    __shared__ unsigned short Bs[2][128 * 32];
    const int tid = threadIdx.x;
    const int lane = tid & 63, wv = tid >> 6;
    const int wr = wv >> 1, wc = wv & 1;
    const int sel = blockIdx.x >> 1;
    const int bn = (blockIdx.x & 1) * 128;
    const int bm = blockIdx.y * 128;
    const unsigned short* W = Wb + (size_t)sel * 65536;

    f32x4 acc[4][4];
#pragma unroll
    for (int m = 0; m < 4; m++)
#pragma unroll
        for (int n = 0; n < 4; n++) acc[m][n] = (f32x4)0.f;

    stage_a(x, As[0], bm, 0, wv, lane, Mrows);
    stage_b(W, Bs[0], bn, 0, wv, lane);
    __syncthreads();

    int cur = 0;
#pragma unroll
    for (int t = 0; t < 8; t++) {
        if (t < 7) {
            stage_a(x, As[cur ^ 1], bm, (t + 1) * 32, wv, lane, Mrows);
            stage_b(W, Bs[cur ^ 1], bn, (t + 1) * 32, wv, lane);
        }
        short8 bfr[4];
#pragma unroll
        for (int n = 0; n < 4; n++) {
            int col = wc * 64 + n * 16 + (lane & 15);
            int sc = (lane >> 4) ^ (col & 3);
            bfr[n] = *(const short8*)&Bs[cur][col * 32 + sc * 8];
        }
        short8 afr[4];
#pragma unroll
        for (int m = 0; m < 4; m++) {
            int row = wr * 64 + m * 16 + (lane & 15);
            int c0 = (lane >> 4) * 2;
            const float* ap = &As[cur][row * 32];
            float4 f0 = *(const float4*)&ap[(c0 ^ (row & 7)) << 2];
            float4 f1 = *(const float4*)&ap[((c0 + 1) ^ (row & 7)) << 2];
            union { short8 v; __hip_bfloat162 b2[4]; } u;
            u.b2[0] = __float22bfloat162_rn(make_float2(f0.x, f0.y));
            u.b2[1] = __float22bfloat162_rn(make_float2(f0.z, f0.w));
            u.b2[2] = __float22bfloat162_rn(make_float2(f1.x, f1.y));
            u.b2[3] = __float22bfloat162_rn(make_float2(f1.z, f1.w));
            afr[m] = u.v;
        }
#pragma unroll
        for (int m = 0; m < 4; m++)
#pragma unroll
            for (int n = 0; n < 4; n++)
                acc[m][n] = __builtin_amdgcn_mfma_f32_16x16x32_bf16(
                    afr[m], bfr[n], acc[m][n], 0, 0, 0);
        __syncthreads();
        cur ^= 1;
    }
    gemm_epilogue<RB16>(acc, sel ? b_r : b_l, sel, bm, bn, wr, wc, lane,
                        lout, rout, Mrows);
}

// ---------- MFMA GEMM, bf16-A path (xb precomputed) ----------
__global__ __launch_bounds__(256) void gemm_fused_b16(
    const unsigned short* __restrict__ xb, const unsigned short* __restrict__ Wb,
    const float* __restrict__ b_l, const float* __restrict__ b_r,
    unsigned short* __restrict__ lout, void* __restrict__ rout, int Mrows)
{
    __shared__ unsigned short As[2][128 * 32];
    __shared__ unsigned short Bs[2][128 * 32];
    const int tid = threadIdx.x;
    const int lane = tid & 63, wv = tid >> 6;
    const int wr = wv >> 1, wc = wv & 1;
    const int sel = blockIdx.x >> 1;
    const int bn = (blockIdx.x & 1) * 128;
    const int bm = blockIdx.y * 128;
    const unsigned short* W = Wb + (size_t)sel * 65536;

    f32x4 acc[4][4];
#pragma unroll
    for (int m = 0; m < 4; m++)
#pragma unroll
        for (int n = 0; n < 4; n++) acc[m][n] = (f32x4)0.f;

    stage_a16(xb, As[0], bm, 0, wv, lane, Mrows);
    stage_b(W, Bs[0], bn, 0, wv, lane);
    __syncthreads();

    int cur = 0;
#pragma unroll
    for (int t = 0; t < 8; t++) {
        if (t < 7) {
            stage_a16(xb, As[cur ^ 1], bm, (t + 1) * 32, wv, lane, Mrows);
            stage_b(W, Bs[cur ^ 1], bn, (t + 1) * 32, wv, lane);
        }
        short8 bfr[4], afr[4];
#pragma unroll
        for (int n = 0; n < 4; n++) {
            int col = wc * 64 + n * 16 + (lane & 15);
            int sc = (lane >> 4) ^ (col & 3);
            bfr[n] = *(const short8*)&Bs[cur][col * 32 + sc * 8];
        }
#pragma unroll
        for (int m = 0; m < 4; m++) {
            int row = wr * 64 + m * 16 + (lane & 15);
            int sa = (lane >> 4) ^ (row & 3);
            afr[m] = *(const short8*)&As[cur][row * 32 + sa * 8];
        }
#pragma unroll
        for (int m = 0; m < 4; m++)
#pragma unroll
            for (int n = 0; n < 4; n++)
                acc[m][n] = __builtin_amdgcn_mfma_f32_16x16x32_bf16(
                    afr[m], bfr[n], acc[m][n], 0, 0, 0);
        __syncthreads();
        cur ^= 1;
    }
    gemm_epilogue<true>(acc, sel ? b_r : b_l, sel, bm, bn, wr, wc, lane,
                        lout, rout, Mrows);
}

// ---------- per-node logit parts: wave per node, vectorized ----------
template <bool RB16>
__global__ __launch_bounds__(256) void node_logits(
    const unsigned short* __restrict__ l, const void* __restrict__ rv,
    const float* __restrict__ attn, const float* __restrict__ rel_l,
    const float* __restrict__ rel_r,
    float2* __restrict__ ej2, float* __restrict__ al, float* __restrict__ rd,
    int Nn)
{
    int lane = threadIdx.x & 63;
    int n = blockIdx.x * 4 + (threadIdx.x >> 6);
    if (n >= Nn) return;
    int h = lane >> 4, q = lane & 15;

    ushort4 lv4 = *(const ushort4*)&l[(size_t)n * D_ + lane * 4];
    float rf[4];
    if (RB16) {
        ushort4 ru = ((const ushort4*)rv)[(size_t)n * 64 + lane];
        rf[0] = b2f(ru.x); rf[1] = b2f(ru.y); rf[2] = b2f(ru.z); rf[3] = b2f(ru.w);
    } else {
        float4 rv4 = ((const float4*)rv)[(size_t)n * 64 + lane];
        rf[0] = rv4.x; rf[1] = rv4.y; rf[2] = rv4.z; rf[3] = rv4.w;
    }
    float4 a0 = *(const float4*)&attn[(0 * H_ + h) * 128 + 64 + q * 4];
    float4 a1 = *(const float4*)&attn[(1 * H_ + h) * 128 + 64 + q * 4];
    float4 wl = *(const float4*)&rel_l[h * C_ + q * 4];
    float4 wr = *(const float4*)&rel_r[h * C_ + q * 4];

    float lf[4] = { b2f(lv4.x), b2f(lv4.y), b2f(lv4.z), b2f(lv4.w) };
    float af0[4] = { a0.x, a0.y, a0.z, a0.w };
    float af1[4] = { a1.x, a1.y, a1.z, a1.w };
    float wlf[4] = { wl.x, wl.y, wl.z, wl.w };
    float wrf[4] = { wr.x, wr.y, wr.z, wr.w };

    float v2 = 0.f, v3 = 0.f, v4 = 0.f, v5 = 0.f, v6 = 0.f;
#pragma unroll
    for (int k = 0; k < 4; k++) {
        float ll = lrelu(lf[k]);
        v2 = fmaf(ll, af0[k], v2);
        v3 = fmaf(ll, af1[k], v3);
        v4 = fmaf(rf[k], wlf[k], v4);
        v5 = fmaf(lf[k], wrf[k], v5);
        v6 = fmaf(rf[k], wrf[k], v6);
    }
#pragma unroll
    for (int off = 1; off < 16; off <<= 1) {
        v2 += __shfl_xor(v2, off);
        v3 += __shfl_xor(v3, off);
        v4 += __shfl_xor(v4, off);
        v5 += __shfl_xor(v5, off);
        v6 += __shfl_xor(v6, off);
    }
    if (q == 0) {
        int NH = Nn * H_;
        int nh = n * H_ + h;
        float e0 = __expf(v2), e1 = __expf(v3);
        ej2[nh]      = make_float2(e0, e0 * v5);
        ej2[NH + nh] = make_float2(e1, e1 * v5);
        al[nh] = v4;
        rd[nh] = v6;
    }
}

// ---------- CSR build: histogram ----------
__global__ __launch_bounds__(256) void edge_hist(
    const int* __restrict__ ei0, const int* __restrict__ ei1,
    int* __restrict__ hist, int E_, int Nn)
{
    int e = blockIdx.x * 256 + threadIdx.x;
    if (e >= E_) return;
    atomicAdd(&hist[ei0[E_ + e]], 1);
    atomicAdd(&hist[Nn + ei1[E_ + e]], 1);
}

// ---------- CSR build: 3-kernel exclusive scan ----------
__global__ __launch_bounds__(256) void scan_a(
    const int* __restrict__ hist, int* __restrict__ segoff,
    int* __restrict__ bsum, int Nn)
{
    int m = blockIdx.y;
    int gid = blockIdx.x * 256 + threadIdx.x;
    int lane = threadIdx.x & 63, wid = threadIdx.x >> 6;
    int v = (gid < Nn) ? hist[m * Nn + gid] : 0;
    int incl = v;
#pragma unroll
    for (int off = 1; off < 64; off <<= 1) {
        int u = __shfl_up(incl, off);
        if (lane >= off) incl += u;
    }
    __shared__ int ws[4], wo[4];
    if (lane == 63) ws[wid] = incl;
    __syncthreads();
    if (threadIdx.x == 0) {
        int run = 0;
#pragma unroll
        for (int i = 0; i < 4; i++) { wo[i] = run; run += ws[i]; }
        bsum[m * 512 + blockIdx.x] = run;
    }
    __syncthreads();
    if (gid < Nn) segoff[m * Nn + gid] = incl - v + wo[wid];
}

__global__ __launch_bounds__(512) void scan_b(int* __restrict__ bsum, int nb)
{
    int m = blockIdx.x;
    int* b = bsum + m * 512;
    int tid = threadIdx.x, lane = tid & 63, wid = tid >> 6;
    int v = (tid < nb) ? b[tid] : 0;
    int incl = v;
#pragma unroll
    for (int off = 1; off < 64; off <<= 1) {
        int u = __shfl_up(incl, off);
        if (lane >= off) incl += u;
    }
    __shared__ int ws[8], wo[8];
    if (lane == 63) ws[wid] = incl;
    __syncthreads();
    if (tid == 0) {
        int run = 0;
#pragma unroll
        for (int i = 0; i < 8; i++) { wo[i] = run; run += ws[i]; }
    }
    __syncthreads();
    if (tid < nb) b[tid] = incl - v + wo[wid];
}

__global__ __launch_bounds__(256) void scan_c(
    int* __restrict__ segoff, const int* __restrict__ bsum, int Nn)
{
    int m = blockIdx.y;
    int gid = blockIdx.x * 256 + threadIdx.x;
    if (gid < Nn) segoff[m * Nn + gid] += bsum[m * 512 + blockIdx.x];
}

// ---------- CSR build: scatter ----------
__global__ __launch_bounds__(256) void edge_scatter(
    const int* __restrict__ ei0, const int* __restrict__ ei1,
    const int* __restrict__ segoff, int* __restrict__ cursor,
    int* __restrict__ srcs, int E_, int Nn)
{
    int e = blockIdx.x * 256 + threadIdx.x;
    if (e >= E_) return;
    int t0 = ei0[E_ + e];
    int p0 = segoff[t0] + atomicAdd(&cursor[t0], 1);
    srcs[p0] = ei0[e];
    int t1 = ei1[E_ + e];
    int p1 = segoff[Nn + t1] + atomicAdd(&cursor[Nn + t1], 1);
    srcs[E_ + p1] = ei1[e];
}

// ---------- single-pass aggregation: wave per target ----------
template <bool RB16>
__global__ __launch_bounds__(256) void aggregate(
    const int* __restrict__ hist, const int* __restrict__ segoff,
    const int* __restrict__ srcs, const float2* __restrict__ ej2,
    const float* __restrict__ al, const float* __restrict__ rd,
    const void* __restrict__ rv, const unsigned short* __restrict__ l,
    float* __restrict__ out, int Nn, int E_)
{
    int lane = threadIdx.x & 63;
    int t = blockIdx.x * 4 + (threadIdx.x >> 6);
    if (t >= Nn) return;
    int h = lane >> 4;
    int NH = Nn * H_;
    int nh = t * H_ + h;

    // issue these early: consumed only after the edge loops
    float4 rrow;
    if (RB16) {
        ushort4 ru = ((const ushort4*)rv)[(size_t)t * 64 + lane];
        rrow = make_float4(b2f(ru.x), b2f(ru.y), b2f(ru.z), b2f(ru.w));
    } else {
        rrow = ((const float4*)rv)[(size_t)t * 64 + lane];
    }
    float a = al[nh];
    float rdv = rd[nh];

    int beg0 = segoff[t],      deg0 = hist[t];
    int beg1 = segoff[Nn + t], deg1 = hist[Nn + t];

    float4 acc0 = make_float4(0.f, 0.f, 0.f, 0.f);
    float4 acc1 = make_float4(0.f, 0.f, 0.f, 0.f);
    float den0 = 0.f, pn0 = 0.f, den1 = 0.f, pn1 = 0.f;

#pragma unroll 4
    for (int j = 0; j < deg0; j++) {
        int s = srcs[beg0 + j];
        float2 v = ej2[(size_t)s * H_ + h];
        den0 += v.x; pn0 += v.y;
        ushort4 lv = *(const ushort4*)&l[(size_t)s * D_ + lane * 4];
        acc0.x = fmaf(b2f(lv.x), v.x, acc0.x);
        acc0.y = fmaf(b2f(lv.y), v.x, acc0.y);
        acc0.z = fmaf(b2f(lv.z), v.x, acc0.z);
        acc0.w = fmaf(b2f(lv.w), v.x, acc0.w);
    }
    const float2* ep1 = ej2 + NH;
#pragma unroll 4
    for (int j = 0; j < deg1; j++) {
        int s = srcs[E_ + beg1 + j];
        float2 v = ep1[(size_t)s * H_ + h];
        den1 += v.x; pn1 += v.y;
        ushort4 lv = *(const ushort4*)&l[(size_t)s * D_ + lane * 4];
        acc1.x = fmaf(b2f(lv.x), v.x, acc1.x);
        acc1.y = fmaf(b2f(lv.y), v.x, acc1.y);
        acc1.z = fmaf(b2f(lv.z), v.x, acc1.z);
        acc1.w = fmaf(b2f(lv.w), v.x, acc1.w);
    }

    float b0 = lrelu(a + pn0 / (den0 + 1e-16f));
    float b1 = lrelu(a + pn1 / (den1 + 1e-16f));
    float b2 = lrelu(a + rdv);
    float mm = fmaxf(b0, fmaxf(b1, b2));
    float e0 = __expf(b0 - mm), e1 = __expf(b1 - mm), e2 = __expf(b2 - mm);
    float inv = 1.f / (e0 + e1 + e2);
    float wm0 = e0 * inv / (den0 + 1e-16f);
    float wm1 = e1 * inv / (den1 + 1e-16f);
    float b2v = e2 * inv;

    float4 o;
    o.x = fmaxf(fmaf(wm0, acc0.x, fmaf(wm1, acc1.x, b2v * rrow.x)), 0.f);
    o.y = fmaxf(fmaf(wm0, acc0.y, fmaf(wm1, acc1.y, b2v * rrow.y)), 0.f);
    o.z = fmaxf(fmaf(wm0, acc0.z, fmaf(wm1, acc1.z, b2v * rrow.z)), 0.f);
    o.w = fmaxf(fmaf(wm0, acc0.w, fmaf(wm1, acc1.w, b2v * rrow.w)), 0.f);
    *(float4*)&out[(size_t)t * D_ + lane * 4] = o;
}

extern "C" void kernel_launch(void* const* d_in, const int* in_sizes, int n_in,
                              void* d_out, int out_size, void* d_ws, size_t ws_size,
                              hipStream_t stream) {
    const float* x     = (const float*)d_in[0];
    const int*   ei0   = (const int*)d_in[1];
    const int*   ei1   = (const int*)d_in[2];
    const float* W_l   = (const float*)d_in[3];
    const float* b_l   = (const float*)d_in[4];
    const float* W_r   = (const float*)d_in[5];
    const float* b_r   = (const float*)d_in[6];
    const float* attn  = (const float*)d_in[7];
    const float* rel_l = (const float*)d_in[8];
    const float* rel_r = (const float*)d_in[9];
    float* out = (float*)d_out;

    const int Nn = in_sizes[0] / D_;        // 100000
    const int E_ = in_sizes[1] / 2;         // 800000
    const size_t ND = (size_t)Nn * D_;
    const int NH = Nn * H_;

    // ---- workspace layout (~70 MB base; +51 rb; +51 xb) ----
    char* base = (char*)d_ws;
    unsigned short* l = (unsigned short*)base;      size_t off = ND * 2;
    float2* ej2  = (float2*)(base + off); off += (size_t)2 * NH * 8;  // [M][N][H]
    float* al    = (float*)(base + off);  off += (size_t)NH * 4;
    float* rd    = (float*)(base + off);  off += (size_t)NH * 4;
    int* hist    = (int*)(base + off);    off += (size_t)2 * Nn * 4;  // [M][Nn]
    int* cursor  = (int*)(base + off);    off += (size_t)2 * Nn * 4;
    int* segoff  = (int*)(base + off);    off += (size_t)2 * Nn * 4;
    int* bsum    = (int*)(base + off);    off += (size_t)1024 * 4;
    int* srcs    = (int*)(base + off);    off += (size_t)2 * E_ * 4;  // [M][E]
    unsigned short* Wb = (unsigned short*)(base + off); off += (size_t)2 * 65536 * 2;
    unsigned short* rb = (unsigned short*)(base + off);
    const bool rb16 = (ws_size >= off + ND * 2);
    if (rb16) off += ND * 2;
    unsigned short* xb = (unsigned short*)(base + off);
    const bool xb16 = rb16 && (ws_size >= off + ND * 2);
    void* r_any = rb16 ? (void*)rb : (void*)out;

    // zero hist + cursor (contiguous)
    hipMemsetAsync(hist, 0, (size_t)4 * Nn * 4, stream);

    int total4 = 32768 + (xb16 ? Nn * 64 : 0);
    convert_wx<<<(total4 + 255) / 256, 256, 0, stream>>>(W_l, W_r, x, Wb, xb, total4);

    int rowTiles = (Nn + 127) / 128;   // 782
    if (xb16)
        gemm_fused_b16<<<dim3(4, rowTiles), 256, 0, stream>>>(
            xb, Wb, b_l, b_r, l, r_any, Nn);
    else if (rb16)
        gemm_fused_f32<true ><<<dim3(4, rowTiles), 256, 0, stream>>>(
            x, Wb, b_l, b_r, l, r_any, Nn);
    else
        gemm_fused_f32<false><<<dim3(4, rowTiles), 256, 0, stream>>>(
            x, Wb, b_l, b_r, l, r_any, Nn);

    if (rb16)
        node_logits<true ><<<(Nn + 3) / 4, 256, 0, stream>>>(
            l, r_any, attn, rel_l, rel_r, ej2, al, rd, Nn);
    else
        node_logits<false><<<(Nn + 3) / 4, 256, 0, stream>>>(
            l, r_any, attn, rel_l, rel_r, ej2, al, rd, Nn);

    int eb = (E_ + 255) / 256;
    int nb = (Nn + 255) / 256;   // 391
    edge_hist<<<eb, 256, 0, stream>>>(ei0, ei1, hist, E_, Nn);
    scan_a<<<dim3(nb, 2), 256, 0, stream>>>(hist, segoff, bsum, Nn);
    scan_b<<<2, 512, 0, stream>>>(bsum, nb);
    scan_c<<<dim3(nb, 2), 256, 0, stream>>>(segoff, bsum, Nn);
    edge_scatter<<<eb, 256, 0, stream>>>(ei0, ei1, segoff, cursor, srcs, E_, Nn);

    if (rb16)
        aggregate<true ><<<(Nn + 3) / 4, 256, 0, stream>>>(
            hist, segoff, srcs, ej2, al, rd, r_any, l, out, Nn, E_);
    else
        aggregate<false><<<(Nn + 3) / 4, 256, 0, stream>>>(
            hist, segoff, srcs, ej2, al, rd, r_any, l, out, Nn, E_);
}

// Round 9
// 446.673 us; speedup vs baseline: 15.3523x; 1.0272x over previous
//
#include <hip/hip_runtime.h>
#include <hip/hip_bf16.h>
#include <math.h>

#define D_ 256
#define H_ 4
#define C_ 64

typedef __attribute__((ext_vector_type(8))) short short8;
typedef __attribute__((ext_vector_type(4))) float f32x4;

// ---------- helpers ----------
__device__ inline float lrelu(float v) { return v >= 0.f ? v : 0.2f * v; }

// bf16 bit helpers
__device__ inline unsigned short f2b(float f) {
    unsigned u = __float_as_uint(f);
    u = (u + 0x7FFFu + ((u >> 16) & 1u)) >> 16;   // round-to-nearest-even
    return (unsigned short)u;
}
__device__ inline float b2f(unsigned short u) {
    return __uint_as_float(((unsigned)u) << 16);
}

#define GLDS(src, dst) __builtin_amdgcn_global_load_lds(                      \
    (const __attribute__((address_space(1))) void*)(src),                     \
    (__attribute__((address_space(3))) void*)(dst), 16, 0, 0)

// ---------- W -> bf16 ----------
__global__ __launch_bounds__(256) void convert_w(
    const float* __restrict__ Wl, const float* __restrict__ Wr,
    unsigned short* __restrict__ Wb)
{
    int i4 = blockIdx.x * 256 + threadIdx.x;          // 0..32767 float4s
    float4 v = (i4 < 16384) ? ((const float4*)Wl)[i4]
                            : ((const float4*)Wr)[i4 - 16384];
    ushort4 u;
    u.x = f2b(v.x); u.y = f2b(v.y); u.z = f2b(v.z); u.w = f2b(v.w);
    ((ushort4*)Wb)[i4] = u;
}

// ---------- staging ----------
__device__ __forceinline__ void stage_a(const float* __restrict__ x, float* dst,
                                        int bm, int k0, int wv, int lane, int Mrows)
{
#pragma unroll
    for (int p = 0; p < 4; p++) {
        int ci = (p * 4 + wv) * 64 + lane;            // chunk 0..1023
        int row = ci >> 3, cc = ci & 7;
        int gr = bm + row; if (gr >= Mrows) gr = Mrows - 1;
        const float* src = x + (size_t)gr * 256 + k0 + ((cc ^ (row & 7)) << 2);
        GLDS(src, (char*)dst + (size_t)(p * 4 + wv) * 1024);
    }
}
__device__ __forceinline__ void stage_b(const unsigned short* __restrict__ W,
                                        unsigned short* dst, int bn, int k0,
                                        int wv, int lane)
{
#pragma unroll
    for (int p = 0; p < 2; p++) {
        int ci = (p * 4 + wv) * 64 + lane;            // chunk 0..511
        int col = ci >> 2, cc = ci & 3;
        const unsigned short* src = W + (size_t)(bn + col) * 256 + k0 +
                                    ((cc ^ (col & 3)) << 3);
        GLDS(src, (char*)dst + (size_t)(p * 4 + wv) * 1024);
    }
}

// ---------- MFMA GEMM: l = x@W_l^T + b_l (bf16), r = x@W_r^T + b_r ----------
// XCD-chunked swizzle: siblings (same row-tile, 4 col-selections) stay on one XCD.
template <bool RB16>
__global__ __launch_bounds__(256) void gemm_fused(
    const float* __restrict__ x, const unsigned short* __restrict__ Wb,
    const float* __restrict__ b_l, const float* __restrict__ b_r,
    unsigned short* __restrict__ lout, void* __restrict__ rout,
    int Mrows, int nblk)
{
    int hw = blockIdx.x;
    int orig = hw;
    if ((nblk & 7) == 0) {                 // bijective chunked swizzle
        int cpx = nblk >> 3;
        orig = (hw & 7) * cpx + (hw >> 3);
    }
    const int sel = (orig & 3) >> 1;       // 0 = l, 1 = r
    const int bn = (orig & 1) * 128;
    const int bm = (orig >> 2) * 128;

    __shared__ float As[2][128 * 32];
    __shared__ unsigned short Bs[2][128 * 32];
    const int tid = threadIdx.x;
    const int lane = tid & 63, wv = tid >> 6;
    const int wr = wv >> 1, wc = wv & 1;
    const unsigned short* W = Wb + (size_t)sel * 65536;

    f32x4 acc[4][4];
#pragma unroll
    for (int m = 0; m < 4; m++)
#pragma unroll
        for (int n = 0; n < 4; n++) acc[m][n] = (f32x4)0.f;

    stage_a(x, As[0], bm, 0, wv, lane, Mrows);
    stage_b(W, Bs[0], bn, 0, wv, lane);
    __syncthreads();

    int cur = 0;
#pragma unroll
    for (int t = 0; t < 8; t++) {
        if (t < 7) {
            stage_a(x, As[cur ^ 1], bm, (t + 1) * 32, wv, lane, Mrows);
            stage_b(W, Bs[cur ^ 1], bn, (t + 1) * 32, wv, lane);
        }
        short8 bfr[4];
#pragma unroll
        for (int n = 0; n < 4; n++) {
            int col = wc * 64 + n * 16 + (lane & 15);
            int sc = (lane >> 4) ^ (col & 3);
            bfr[n] = *(const short8*)&Bs[cur][col * 32 + sc * 8];
        }
        short8 afr[4];
#pragma unroll
        for (int m = 0; m < 4; m++) {
            int row = wr * 64 + m * 16 + (lane & 15);
            int c0 = (lane >> 4) * 2;
            const float* ap = &As[cur][row * 32];
            float4 f0 = *(const float4*)&ap[(c0 ^ (row & 7)) << 2];
            float4 f1 = *(const float4*)&ap[((c0 + 1) ^ (row & 7)) << 2];
            union { short8 v; __hip_bfloat162 b2[4]; } u;
            u.b2[0] = __float22bfloat162_rn(make_float2(f0.x, f0.y));
            u.b2[1] = __float22bfloat162_rn(make_float2(f0.z, f0.w));
            u.b2[2] = __float22bfloat162_rn(make_float2(f1.x, f1.y));
            u.b2[3] = __float22bfloat162_rn(make_float2(f1.z, f1.w));
            afr[m] = u.v;
        }
#pragma unroll
        for (int m = 0; m < 4; m++)
#pragma unroll
            for (int n = 0; n < 4; n++)
                acc[m][n] = __builtin_amdgcn_mfma_f32_16x16x32_bf16(
                    afr[m], bfr[n], acc[m][n], 0, 0, 0);
        __syncthreads();
        cur ^= 1;
    }

    const float* bias = sel ? b_r : b_l;
#pragma unroll
    for (int m = 0; m < 4; m++) {
        int grow0 = bm + wr * 64 + m * 16 + (lane >> 4) * 4;
#pragma unroll
        for (int n = 0; n < 4; n++) {
            int gcol = bn + wc * 64 + n * 16 + (lane & 15);
            float bv = bias[gcol];
#pragma unroll
            for (int q = 0; q < 4; q++) {
                int grow = grow0 + q;
                if (grow < Mrows) {
                    float v = acc[m][n][q] + bv;
                    if (sel == 0) {
                        lout[(size_t)grow * 256 + gcol] = f2b(v);
                    } else {
                        if (RB16) ((unsigned short*)rout)[(size_t)grow * 256 + gcol] = f2b(v);
                        else      ((float*)rout)[(size_t)grow * 256 + gcol] = v;
                    }
                }
            }
        }
    }
}

// ---------- per-node logit parts: wave per node, vectorized ----------
template <bool RB16>
__global__ __launch_bounds__(256) void node_logits(
    const unsigned short* __restrict__ l, const void* __restrict__ rv,
    const float* __restrict__ attn, const float* __restrict__ rel_l,
    const float* __restrict__ rel_r,
    float2* __restrict__ ej2, float* __restrict__ al, float* __restrict__ rd,
    int Nn)
{
    int lane = threadIdx.x & 63;
    int n = blockIdx.x * 4 + (threadIdx.x >> 6);
    if (n >= Nn) return;
    int h = lane >> 4, q = lane & 15;

    ushort4 lv4 = *(const ushort4*)&l[(size_t)n * D_ + lane * 4];
    float rf[4];
    if (RB16) {
        ushort4 ru = ((const ushort4*)rv)[(size_t)n * 64 + lane];
        rf[0] = b2f(ru.x); rf[1] = b2f(ru.y); rf[2] = b2f(ru.z); rf[3] = b2f(ru.w);
    } else {
        float4 rv4 = ((const float4*)rv)[(size_t)n * 64 + lane];
        rf[0] = rv4.x; rf[1] = rv4.y; rf[2] = rv4.z; rf[3] = rv4.w;
    }
    float4 a0 = *(const float4*)&attn[(0 * H_ + h) * 128 + 64 + q * 4];
    float4 a1 = *(const float4*)&attn[(1 * H_ + h) * 128 + 64 + q * 4];
    float4 wl = *(const float4*)&rel_l[h * C_ + q * 4];
    float4 wr = *(const float4*)&rel_r[h * C_ + q * 4];

    float lf[4] = { b2f(lv4.x), b2f(lv4.y), b2f(lv4.z), b2f(lv4.w) };
    float af0[4] = { a0.x, a0.y, a0.z, a0.w };
    float af1[4] = { a1.x, a1.y, a1.z, a1.w };
    float wlf[4] = { wl.x, wl.y, wl.z, wl.w };
    float wrf[4] = { wr.x, wr.y, wr.z, wr.w };

    float v2 = 0.f, v3 = 0.f, v4 = 0.f, v5 = 0.f, v6 = 0.f;
#pragma unroll
    for (int k = 0; k < 4; k++) {
        float ll = lrelu(lf[k]);
        v2 = fmaf(ll, af0[k], v2);
        v3 = fmaf(ll, af1[k], v3);
        v4 = fmaf(rf[k], wlf[k], v4);
        v5 = fmaf(lf[k], wrf[k], v5);
        v6 = fmaf(rf[k], wrf[k], v6);
    }
#pragma unroll
    for (int off = 1; off < 16; off <<= 1) {
        v2 += __shfl_xor(v2, off);
        v3 += __shfl_xor(v3, off);
        v4 += __shfl_xor(v4, off);
        v5 += __shfl_xor(v5, off);
        v6 += __shfl_xor(v6, off);
    }
    if (q == 0) {
        int NH = Nn * H_;
        int nh = n * H_ + h;
        float e0 = __expf(v2), e1 = __expf(v3);
        ej2[nh]      = make_float2(e0, e0 * v5);
        ej2[NH + nh] = make_float2(e1, e1 * v5);
        al[nh] = v4;
        rd[nh] = v6;
    }
}

// ---------- CSR build: histogram ----------
__global__ __launch_bounds__(256) void edge_hist(
    const int* __restrict__ ei0, const int* __restrict__ ei1,
    int* __restrict__ hist, int E_, int Nn)
{
    int e = blockIdx.x * 256 + threadIdx.x;
    if (e >= E_) return;
    atomicAdd(&hist[ei0[E_ + e]], 1);
    atomicAdd(&hist[Nn + ei1[E_ + e]], 1);
}

// ---------- CSR build: 2-kernel exclusive scan (block sums folded downstream) ----------
__global__ __launch_bounds__(256) void scan_a(
    const int* __restrict__ hist, int* __restrict__ segoff,
    int* __restrict__ bsum, int Nn)
{
    int m = blockIdx.y;
    int gid = blockIdx.x * 256 + threadIdx.x;
    int lane = threadIdx.x & 63, wid = threadIdx.x >> 6;
    int v = (gid < Nn) ? hist[m * Nn + gid] : 0;
    int incl = v;
#pragma unroll
    for (int off = 1; off < 64; off <<= 1) {
        int u = __shfl_up(incl, off);
        if (lane >= off) incl += u;
    }
    __shared__ int ws[4], wo[4];
    if (lane == 63) ws[wid] = incl;
    __syncthreads();
    if (threadIdx.x == 0) {
        int run = 0;
#pragma unroll
        for (int i = 0; i < 4; i++) { wo[i] = run; run += ws[i]; }
        bsum[m * 512 + blockIdx.x] = run;
    }
    __syncthreads();
    if (gid < Nn) segoff[m * Nn + gid] = incl - v + wo[wid];
}

__global__ __launch_bounds__(512) void scan_b(int* __restrict__ bsum, int nb)
{
    int m = blockIdx.x;
    int* b = bsum + m * 512;
    int tid = threadIdx.x, lane = tid & 63, wid = tid >> 6;
    int v = (tid < nb) ? b[tid] : 0;
    int incl = v;
#pragma unroll
    for (int off = 1; off < 64; off <<= 1) {
        int u = __shfl_up(incl, off);
        if (lane >= off) incl += u;
    }
    __shared__ int ws[8], wo[8];
    if (lane == 63) ws[wid] = incl;
    __syncthreads();
    if (tid == 0) {
        int run = 0;
#pragma unroll
        for (int i = 0; i < 8; i++) { wo[i] = run; run += ws[i]; }
    }
    __syncthreads();
    if (tid < nb) b[tid] = incl - v + wo[wid];
}

// ---------- CSR build: scatter (adds bsum inline; scan_c eliminated) ----------
__global__ __launch_bounds__(256) void edge_scatter(
    const int* __restrict__ ei0, const int* __restrict__ ei1,
    const int* __restrict__ segoff, const int* __restrict__ bsum,
    int* __restrict__ cursor, int* __restrict__ srcs, int E_, int Nn)
{
    int e = blockIdx.x * 256 + threadIdx.x;
    if (e >= E_) return;
    int t0 = ei0[E_ + e];
    int p0 = segoff[t0] + bsum[t0 >> 8] + atomicAdd(&cursor[t0], 1);
    srcs[p0] = ei0[e];
    int t1 = ei1[E_ + e];
    int p1 = segoff[Nn + t1] + bsum[512 + (t1 >> 8)] + atomicAdd(&cursor[Nn + t1], 1);
    srcs[E_ + p1] = ei1[e];
}

// ---------- single-pass aggregation: wave per target ----------
template <bool RB16>
__global__ __launch_bounds__(256) void aggregate(
    const int* __restrict__ hist, const int* __restrict__ segoff,
    const int* __restrict__ bsum,
    const int* __restrict__ srcs, const float2* __restrict__ ej2,
    const float* __restrict__ al, const float* __restrict__ rd,
    const void* __restrict__ rv, const unsigned short* __restrict__ l,
    float* __restrict__ out, int Nn, int E_)
{
    int lane = threadIdx.x & 63;
    int t = blockIdx.x * 4 + (threadIdx.x >> 6);
    if (t >= Nn) return;
    int h = lane >> 4;
    int NH = Nn * H_;
    int nh = t * H_ + h;

    // issue these early: consumed only after the edge loops
    float4 rrow;
    if (RB16) {
        ushort4 ru = ((const ushort4*)rv)[(size_t)t * 64 + lane];
        rrow = make_float4(b2f(ru.x), b2f(ru.y), b2f(ru.z), b2f(ru.w));
    } else {
        rrow = ((const float4*)rv)[(size_t)t * 64 + lane];
    }
    float a = al[nh];
    float rdv = rd[nh];

    int beg0 = segoff[t]      + bsum[t >> 8],         deg0 = hist[t];
    int beg1 = segoff[Nn + t] + bsum[512 + (t >> 8)], deg1 = hist[Nn + t];

    float4 acc0 = make_float4(0.f, 0.f, 0.f, 0.f);
    float4 acc1 = make_float4(0.f, 0.f, 0.f, 0.f);
    float den0 = 0.f, pn0 = 0.f, den1 = 0.f, pn1 = 0.f;

#pragma unroll 4
    for (int j = 0; j < deg0; j++) {
        int s = srcs[beg0 + j];
        float2 v = ej2[(size_t)s * H_ + h];
        den0 += v.x; pn0 += v.y;
        ushort4 lv = *(const ushort4*)&l[(size_t)s * D_ + lane * 4];
        acc0.x = fmaf(b2f(lv.x), v.x, acc0.x);
        acc0.y = fmaf(b2f(lv.y), v.x, acc0.y);
        acc0.z = fmaf(b2f(lv.z), v.x, acc0.z);
        acc0.w = fmaf(b2f(lv.w), v.x, acc0.w);
    }
    const float2* ep1 = ej2 + NH;
#pragma unroll 4
    for (int j = 0; j < deg1; j++) {
        int s = srcs[E_ + beg1 + j];
        float2 v = ep1[(size_t)s * H_ + h];
        den1 += v.x; pn1 += v.y;
        ushort4 lv = *(const ushort4*)&l[(size_t)s * D_ + lane * 4];
        acc1.x = fmaf(b2f(lv.x), v.x, acc1.x);
        acc1.y = fmaf(b2f(lv.y), v.x, acc1.y);
        acc1.z = fmaf(b2f(lv.z), v.x, acc1.z);
        acc1.w = fmaf(b2f(lv.w), v.x, acc1.w);
    }

    float b0 = lrelu(a + pn0 / (den0 + 1e-16f));
    float b1 = lrelu(a + pn1 / (den1 + 1e-16f));
    float b2 = lrelu(a + rdv);
    float mm = fmaxf(b0, fmaxf(b1, b2));
    float e0 = __expf(b0 - mm), e1 = __expf(b1 - mm), e2 = __expf(b2 - mm);
    float inv = 1.f / (e0 + e1 + e2);
    float wm0 = e0 * inv / (den0 + 1e-16f);
    float wm1 = e1 * inv / (den1 + 1e-16f);
    float b2v = e2 * inv;

    float4 o;
    o.x = fmaxf(fmaf(wm0, acc0.x, fmaf(wm1, acc1.x, b2v * rrow.x)), 0.f);
    o.y = fmaxf(fmaf(wm0, acc0.y, fmaf(wm1, acc1.y, b2v * rrow.y)), 0.f);
    o.z = fmaxf(fmaf(wm0, acc0.z, fmaf(wm1, acc1.z, b2v * rrow.z)), 0.f);
    o.w = fmaxf(fmaf(wm0, acc0.w, fmaf(wm1, acc1.w, b2v * rrow.w)), 0.f);
    *(float4*)&out[(size_t)t * D_ + lane * 4] = o;
}

extern "C" void kernel_launch(void* const* d_in, const int* in_sizes, int n_in,
                              void* d_out, int out_size, void* d_ws, size_t ws_size,
                              hipStream_t stream) {
    const float* x     = (const float*)d_in[0];
    const int*   ei0   = (const int*)d_in[1];
    const int*   ei1   = (const int*)d_in[2];
    const float* W_l   = (const float*)d_in[3];
    const float* b_l   = (const float*)d_in[4];
    const float* W_r   = (const float*)d_in[5];
    const float* b_r   = (const float*)d_in[6];
    const float* attn  = (const float*)d_in[7];
    const float* rel_l = (const float*)d_in[8];
    const float* rel_r = (const float*)d_in[9];
    float* out = (float*)d_out;

    const int Nn = in_sizes[0] / D_;        // 100000
    const int E_ = in_sizes[1] / 2;         // 800000
    const size_t ND = (size_t)Nn * D_;
    const int NH = Nn * H_;

    // ---- workspace layout (~70 MB base; +51 MB rb if it fits — proven) ----
    char* base = (char*)d_ws;
    unsigned short* l = (unsigned short*)base;      size_t off = ND * 2;
    float2* ej2  = (float2*)(base + off); off += (size_t)2 * NH * 8;  // [M][N][H]
    float* al    = (float*)(base + off);  off += (size_t)NH * 4;
    float* rd    = (float*)(base + off);  off += (size_t)NH * 4;
    int* hist    = (int*)(base + off);    off += (size_t)2 * Nn * 4;  // [M][Nn]
    int* cursor  = (int*)(base + off);    off += (size_t)2 * Nn * 4;
    int* segoff  = (int*)(base + off);    off += (size_t)2 * Nn * 4;
    int* bsum    = (int*)(base + off);    off += (size_t)1024 * 4;
    int* srcs    = (int*)(base + off);    off += (size_t)2 * E_ * 4;  // [M][E]
    unsigned short* Wb = (unsigned short*)(base + off); off += (size_t)2 * 65536 * 2;
    unsigned short* rb = (unsigned short*)(base + off);
    const bool rb16 = (ws_size >= off + ND * 2);
    void* r_any = rb16 ? (void*)rb : (void*)out;

    // zero hist + cursor (contiguous)
    hipMemsetAsync(hist, 0, (size_t)4 * Nn * 4, stream);

    convert_w<<<128, 256, 0, stream>>>(W_l, W_r, Wb);

    int rowTiles = (Nn + 127) / 128;   // 782
    int nblk = 4 * rowTiles;           // 3128 (divisible by 8)
    if (rb16)
        gemm_fused<true ><<<nblk, 256, 0, stream>>>(x, Wb, b_l, b_r, l, r_any, Nn, nblk);
    else
        gemm_fused<false><<<nblk, 256, 0, stream>>>(x, Wb, b_l, b_r, l, r_any, Nn, nblk);

    if (rb16)
        node_logits<true ><<<(Nn + 3) / 4, 256, 0, stream>>>(
            l, r_any, attn, rel_l, rel_r, ej2, al, rd, Nn);
    else
        node_logits<false><<<(Nn + 3) / 4, 256, 0, stream>>>(
            l, r_any, attn, rel_l, rel_r, ej2, al, rd, Nn);

    int eb = (E_ + 255) / 256;
    int nb = (Nn + 255) / 256;   // 391
    edge_hist<<<eb, 256, 0, stream>>>(ei0, ei1, hist, E_, Nn);
    scan_a<<<dim3(nb, 2), 256, 0, stream>>>(hist, segoff, bsum, Nn);
    scan_b<<<2, 512, 0, stream>>>(bsum, nb);
    edge_scatter<<<eb, 256, 0, stream>>>(ei0, ei1, segoff, bsum, cursor, srcs, E_, Nn);

    if (rb16)
        aggregate<true ><<<(Nn + 3) / 4, 256, 0, stream>>>(
            hist, segoff, bsum, srcs, ej2, al, rd, r_any, l, out, Nn, E_);
    else
        aggregate<false><<<(Nn + 3) / 4, 256, 0, stream>>>(
            hist, segoff, bsum, srcs, ej2, al, rd, r_any, l, out, Nn, E_);
}

// Round 10
// 441.225 us; speedup vs baseline: 15.5418x; 1.0123x over previous
//
#include <hip/hip_runtime.h>
#include <hip/hip_bf16.h>
#include <math.h>

#define D_ 256
#define H_ 4
#define C_ 64

typedef __attribute__((ext_vector_type(8))) short short8;
typedef __attribute__((ext_vector_type(4))) float f32x4;

// ---------- helpers ----------
__device__ inline float lrelu(float v) { return v >= 0.f ? v : 0.2f * v; }

// bf16 bit helpers
__device__ inline unsigned short f2b(float f) {
    unsigned u = __float_as_uint(f);
    u = (u + 0x7FFFu + ((u >> 16) & 1u)) >> 16;   // round-to-nearest-even
    return (unsigned short)u;
}
__device__ inline float b2f(unsigned short u) {
    return __uint_as_float(((unsigned)u) << 16);
}

#define GLDS(src, dst) __builtin_amdgcn_global_load_lds(                      \
    (const __attribute__((address_space(1))) void*)(src),                     \
    (__attribute__((address_space(3))) void*)(dst), 16, 0, 0)

// ---------- W -> bf16 ----------
__global__ __launch_bounds__(256) void convert_w(
    const float* __restrict__ Wl, const float* __restrict__ Wr,
    unsigned short* __restrict__ Wb)
{
    int i4 = blockIdx.x * 256 + threadIdx.x;          // 0..32767 float4s
    float4 v = (i4 < 16384) ? ((const float4*)Wl)[i4]
                            : ((const float4*)Wr)[i4 - 16384];
    ushort4 u;
    u.x = f2b(v.x); u.y = f2b(v.y); u.z = f2b(v.z); u.w = f2b(v.w);
    ((ushort4*)Wb)[i4] = u;
}

// ---------- staging ----------
__device__ __forceinline__ void stage_a(const float* __restrict__ x, float* dst,
                                        int bm, int k0, int wv, int lane, int Mrows)
{
#pragma unroll
    for (int p = 0; p < 4; p++) {
        int ci = (p * 4 + wv) * 64 + lane;            // chunk 0..1023
        int row = ci >> 3, cc = ci & 7;
        int gr = bm + row; if (gr >= Mrows) gr = Mrows - 1;
        const float* src = x + (size_t)gr * 256 + k0 + ((cc ^ (row & 7)) << 2);
        GLDS(src, (char*)dst + (size_t)(p * 4 + wv) * 1024);
    }
}
__device__ __forceinline__ void stage_b(const unsigned short* __restrict__ W,
                                        unsigned short* dst, int bn, int k0,
                                        int wv, int lane)
{
#pragma unroll
    for (int p = 0; p < 2; p++) {
        int ci = (p * 4 + wv) * 64 + lane;            // chunk 0..511
        int col = ci >> 2, cc = ci & 3;
        const unsigned short* src = W + (size_t)(bn + col) * 256 + k0 +
                                    ((cc ^ (col & 3)) << 3);
        GLDS(src, (char*)dst + (size_t)(p * 4 + wv) * 1024);
    }
}

// ---------- MFMA GEMM with fused per-node logits in the epilogue ----------
// Each wave's output = 64 rows x one head's 64 cols -> logit dots reduce
// entirely within the wave (16-lane col groups). sel=0 waves emit ej2;
// sel=1 waves emit al, rd.
template <bool RB16>
__global__ __launch_bounds__(256) void gemm_fused(
    const float* __restrict__ x, const unsigned short* __restrict__ Wb,
    const float* __restrict__ b_l, const float* __restrict__ b_r,
    const float* __restrict__ attn, const float* __restrict__ rel_l,
    const float* __restrict__ rel_r,
    unsigned short* __restrict__ lout, void* __restrict__ rout,
    float2* __restrict__ ej2, float* __restrict__ al, float* __restrict__ rd,
    int Mrows, int nblk)
{
    int hw = blockIdx.x;
    int orig = hw;
    if ((nblk & 7) == 0) {                 // bijective chunked swizzle
        int cpx = nblk >> 3;
        orig = (hw & 7) * cpx + (hw >> 3);
    }
    const int sel = (orig & 3) >> 1;       // 0 = l, 1 = r
    const int bn = (orig & 1) * 128;
    const int bm = (orig >> 2) * 128;

    __shared__ float As[2][128 * 32];
    __shared__ unsigned short Bs[2][128 * 32];
    const int tid = threadIdx.x;
    const int lane = tid & 63, wv = tid >> 6;
    const int wr = wv >> 1, wc = wv & 1;
    const unsigned short* W = Wb + (size_t)sel * 65536;

    f32x4 acc[4][4];
#pragma unroll
    for (int m = 0; m < 4; m++)
#pragma unroll
        for (int n = 0; n < 4; n++) acc[m][n] = (f32x4)0.f;

    stage_a(x, As[0], bm, 0, wv, lane, Mrows);
    stage_b(W, Bs[0], bn, 0, wv, lane);
    __syncthreads();

    int cur = 0;
#pragma unroll
    for (int t = 0; t < 8; t++) {
        if (t < 7) {
            stage_a(x, As[cur ^ 1], bm, (t + 1) * 32, wv, lane, Mrows);
            stage_b(W, Bs[cur ^ 1], bn, (t + 1) * 32, wv, lane);
        }
        short8 bfr[4];
#pragma unroll
        for (int n = 0; n < 4; n++) {
            int col = wc * 64 + n * 16 + (lane & 15);
            int sc = (lane >> 4) ^ (col & 3);
            bfr[n] = *(const short8*)&Bs[cur][col * 32 + sc * 8];
        }
        short8 afr[4];
#pragma unroll
        for (int m = 0; m < 4; m++) {
            int row = wr * 64 + m * 16 + (lane & 15);
            int c0 = (lane >> 4) * 2;
            const float* ap = &As[cur][row * 32];
            float4 f0 = *(const float4*)&ap[(c0 ^ (row & 7)) << 2];
            float4 f1 = *(const float4*)&ap[((c0 + 1) ^ (row & 7)) << 2];
            union { short8 v; __hip_bfloat162 b2[4]; } u;
            u.b2[0] = __float22bfloat162_rn(make_float2(f0.x, f0.y));
            u.b2[1] = __float22bfloat162_rn(make_float2(f0.z, f0.w));
            u.b2[2] = __float22bfloat162_rn(make_float2(f1.x, f1.y));
            u.b2[3] = __float22bfloat162_rn(make_float2(f1.z, f1.w));
            afr[m] = u.v;
        }
#pragma unroll
        for (int m = 0; m < 4; m++)
#pragma unroll
            for (int n = 0; n < 4; n++)
                acc[m][n] = __builtin_amdgcn_mfma_f32_16x16x32_bf16(
                    afr[m], bfr[n], acc[m][n], 0, 0, 0);
        __syncthreads();
        cur ^= 1;
    }

    // ---- fused epilogue ----
    const float* bias = sel ? b_r : b_l;
    const int NH = Mrows * H_;
    const int h = (bn >> 6) + wc;          // this wave's head
    float bv[4], w0[4], w1[4], w2[4];
    int gcol[4];
#pragma unroll
    for (int n = 0; n < 4; n++) {
        int c = n * 16 + (lane & 15);
        gcol[n] = bn + wc * 64 + c - (wc * 64 + c) + wc * 64 + c; // = bn+wc*64+c
        gcol[n] = bn + wc * 64 + c;
        bv[n] = bias[gcol[n]];
        if (sel == 0) {
            w0[n] = attn[(0 * H_ + h) * 128 + 64 + c];
            w1[n] = attn[(1 * H_ + h) * 128 + 64 + c];
            w2[n] = rel_r[h * C_ + c];
        } else {
            w0[n] = rel_l[h * C_ + c];
            w1[n] = rel_r[h * C_ + c];
        }
    }
#pragma unroll
    for (int m = 0; m < 4; m++) {
#pragma unroll
        for (int q = 0; q < 4; q++) {
            int grow = bm + wr * 64 + m * 16 + (lane >> 4) * 4 + q;
            bool ok = grow < Mrows;
            float p0 = 0.f, p1 = 0.f, p2 = 0.f;
#pragma unroll
            for (int n = 0; n < 4; n++) {
                float v = acc[m][n][q] + bv[n];
                if (ok) {
                    if (sel == 0) {
                        lout[(size_t)grow * 256 + gcol[n]] = f2b(v);
                    } else {
                        if (RB16) ((unsigned short*)rout)[(size_t)grow * 256 + gcol[n]] = f2b(v);
                        else      ((float*)rout)[(size_t)grow * 256 + gcol[n]] = v;
                    }
                }
                if (sel == 0) {
                    float lr = lrelu(v);
                    p0 = fmaf(lr, w0[n], p0);
                    p1 = fmaf(lr, w1[n], p1);
                    p2 = fmaf(v, w2[n], p2);
                } else {
                    p0 = fmaf(v, w0[n], p0);
                    p1 = fmaf(v, w1[n], p1);
                }
            }
#pragma unroll
            for (int off = 1; off < 16; off <<= 1) {
                p0 += __shfl_xor(p0, off);
                p1 += __shfl_xor(p1, off);
                if (sel == 0) p2 += __shfl_xor(p2, off);
            }
            if (ok && (lane & 15) == 0) {
                int nh = grow * H_ + h;
                if (sel == 0) {
                    float e0 = __expf(p0), e1 = __expf(p1);
                    ej2[nh]      = make_float2(e0, e0 * p2);
                    ej2[NH + nh] = make_float2(e1, e1 * p2);
                } else {
                    al[nh] = p0;
                    rd[nh] = p1;
                }
            }
        }
    }
}

// ---------- CSR build: histogram ----------
__global__ __launch_bounds__(256) void edge_hist(
    const int* __restrict__ ei0, const int* __restrict__ ei1,
    int* __restrict__ hist, int E_, int Nn)
{
    int e = blockIdx.x * 256 + threadIdx.x;
    if (e >= E_) return;
    atomicAdd(&hist[ei0[E_ + e]], 1);
    atomicAdd(&hist[Nn + ei1[E_ + e]], 1);
}

// ---------- CSR build: 2-kernel exclusive scan (block sums folded downstream) ----------
__global__ __launch_bounds__(256) void scan_a(
    const int* __restrict__ hist, int* __restrict__ segoff,
    int* __restrict__ bsum, int Nn)
{
    int m = blockIdx.y;
    int gid = blockIdx.x * 256 + threadIdx.x;
    int lane = threadIdx.x & 63, wid = threadIdx.x >> 6;
    int v = (gid < Nn) ? hist[m * Nn + gid] : 0;
    int incl = v;
#pragma unroll
    for (int off = 1; off < 64; off <<= 1) {
        int u = __shfl_up(incl, off);
        if (lane >= off) incl += u;
    }
    __shared__ int ws[4], wo[4];
    if (lane == 63) ws[wid] = incl;
    __syncthreads();
    if (threadIdx.x == 0) {
        int run = 0;
#pragma unroll
        for (int i = 0; i < 4; i++) { wo[i] = run; run += ws[i]; }
        bsum[m * 512 + blockIdx.x] = run;
    }
    __syncthreads();
    if (gid < Nn) segoff[m * Nn + gid] = incl - v + wo[wid];
}

__global__ __launch_bounds__(512) void scan_b(int* __restrict__ bsum, int nb)
{
    int m = blockIdx.x;
    int* b = bsum + m * 512;
    int tid = threadIdx.x, lane = tid & 63, wid = tid >> 6;
    int v = (tid < nb) ? b[tid] : 0;
    int incl = v;
#pragma unroll
    for (int off = 1; off < 64; off <<= 1) {
        int u = __shfl_up(incl, off);
        if (lane >= off) incl += u;
    }
    __shared__ int ws[8], wo[8];
    if (lane == 63) ws[wid] = incl;
    __syncthreads();
    if (tid == 0) {
        int run = 0;
#pragma unroll
        for (int i = 0; i < 8; i++) { wo[i] = run; run += ws[i]; }
    }
    __syncthreads();
    if (tid < nb) b[tid] = incl - v + wo[wid];
}

// ---------- CSR build: scatter (adds bsum inline) ----------
__global__ __launch_bounds__(256) void edge_scatter(
    const int* __restrict__ ei0, const int* __restrict__ ei1,
    const int* __restrict__ segoff, const int* __restrict__ bsum,
    int* __restrict__ cursor, int* __restrict__ srcs, int E_, int Nn)
{
    int e = blockIdx.x * 256 + threadIdx.x;
    if (e >= E_) return;
    int t0 = ei0[E_ + e];
    int p0 = segoff[t0] + bsum[t0 >> 8] + atomicAdd(&cursor[t0], 1);
    srcs[p0] = ei0[e];
    int t1 = ei1[E_ + e];
    int p1 = segoff[Nn + t1] + bsum[512 + (t1 >> 8)] + atomicAdd(&cursor[Nn + t1], 1);
    srcs[E_ + p1] = ei1[e];
}

// ---------- aggregation: one wave per (target, metapath); LDS combine ----------
template <bool RB16>
__global__ __launch_bounds__(256) void aggregate(
    const int* __restrict__ hist, const int* __restrict__ segoff,
    const int* __restrict__ bsum,
    const int* __restrict__ srcs, const float2* __restrict__ ej2,
    const float* __restrict__ al, const float* __restrict__ rd,
    const void* __restrict__ rv, const unsigned short* __restrict__ l,
    float* __restrict__ out, int Nn, int E_)
{
    __shared__ float4 accS[2][64];
    __shared__ float2 dpS[2][64];
    int lane = threadIdx.x & 63;
    int wid = threadIdx.x >> 6;
    int pair = wid >> 1, mp = wid & 1;
    int t = blockIdx.x * 2 + pair;
    bool active = t < Nn;
    int h = lane >> 4;
    int NH = Nn * H_;
    int nh = t * H_ + h;

    // mp==0 wave pre-issues the combine inputs (hidden under its edge loop)
    float4 rrow = make_float4(0.f, 0.f, 0.f, 0.f);
    float a = 0.f, rdv = 0.f;
    if (active && mp == 0) {
        if (RB16) {
            ushort4 ru = ((const ushort4*)rv)[(size_t)t * 64 + lane];
            rrow = make_float4(b2f(ru.x), b2f(ru.y), b2f(ru.z), b2f(ru.w));
        } else {
            rrow = ((const float4*)rv)[(size_t)t * 64 + lane];
        }
        a = al[nh];
        rdv = rd[nh];
    }

    float4 acc = make_float4(0.f, 0.f, 0.f, 0.f);
    float den = 0.f, pn = 0.f;
    if (active) {
        int beg = segoff[mp * Nn + t] + bsum[mp * 512 + (t >> 8)];
        int deg = hist[mp * Nn + t];
        const int* sp = srcs + (size_t)mp * E_;
        const float2* ep = ej2 + (size_t)mp * NH;
#pragma unroll 4
        for (int j = 0; j < deg; j++) {
            int s = sp[beg + j];
            float2 v = ep[(size_t)s * H_ + h];
            den += v.x; pn += v.y;
            ushort4 lv = *(const ushort4*)&l[(size_t)s * D_ + lane * 4];
            acc.x = fmaf(b2f(lv.x), v.x, acc.x);
            acc.y = fmaf(b2f(lv.y), v.x, acc.y);
            acc.z = fmaf(b2f(lv.z), v.x, acc.z);
            acc.w = fmaf(b2f(lv.w), v.x, acc.w);
        }
    }
    if (mp == 1) {
        accS[pair][lane] = acc;
        dpS[pair][lane] = make_float2(den, pn);
    }
    __syncthreads();
    if (mp == 1 || !active) return;

    float4 acc1 = accS[pair][lane];
    float2 dp1 = dpS[pair][lane];

    float b0 = lrelu(a + pn / (den + 1e-16f));
    float b1 = lrelu(a + dp1.y / (dp1.x + 1e-16f));
    float b2 = lrelu(a + rdv);
    float mm = fmaxf(b0, fmaxf(b1, b2));
    float e0 = __expf(b0 - mm), e1 = __expf(b1 - mm), e2 = __expf(b2 - mm);
    float inv = 1.f / (e0 + e1 + e2);
    float wm0 = e0 * inv / (den + 1e-16f);
    float wm1 = e1 * inv / (dp1.x + 1e-16f);
    float b2v = e2 * inv;

    float4 o;
    o.x = fmaxf(fmaf(wm0, acc.x, fmaf(wm1, acc1.x, b2v * rrow.x)), 0.f);
    o.y = fmaxf(fmaf(wm0, acc.y, fmaf(wm1, acc1.y, b2v * rrow.y)), 0.f);
    o.z = fmaxf(fmaf(wm0, acc.z, fmaf(wm1, acc1.z, b2v * rrow.z)), 0.f);
    o.w = fmaxf(fmaf(wm0, acc.w, fmaf(wm1, acc1.w, b2v * rrow.w)), 0.f);
    *(float4*)&out[(size_t)t * D_ + lane * 4] = o;
}

extern "C" void kernel_launch(void* const* d_in, const int* in_sizes, int n_in,
                              void* d_out, int out_size, void* d_ws, size_t ws_size,
                              hipStream_t stream) {
    const float* x     = (const float*)d_in[0];
    const int*   ei0   = (const int*)d_in[1];
    const int*   ei1   = (const int*)d_in[2];
    const float* W_l   = (const float*)d_in[3];
    const float* b_l   = (const float*)d_in[4];
    const float* W_r   = (const float*)d_in[5];
    const float* b_r   = (const float*)d_in[6];
    const float* attn  = (const float*)d_in[7];
    const float* rel_l = (const float*)d_in[8];
    const float* rel_r = (const float*)d_in[9];
    float* out = (float*)d_out;

    const int Nn = in_sizes[0] / D_;        // 100000
    const int E_ = in_sizes[1] / 2;         // 800000
    const size_t ND = (size_t)Nn * D_;
    const int NH = Nn * H_;

    // ---- workspace layout (~70 MB base; +51 MB rb if it fits — proven) ----
    char* base = (char*)d_ws;
    unsigned short* l = (unsigned short*)base;      size_t off = ND * 2;
    float2* ej2  = (float2*)(base + off); off += (size_t)2 * NH * 8;  // [M][N][H]
    float* al    = (float*)(base + off);  off += (size_t)NH * 4;
    float* rd    = (float*)(base + off);  off += (size_t)NH * 4;
    int* hist    = (int*)(base + off);    off += (size_t)2 * Nn * 4;  // [M][Nn]
    int* cursor  = (int*)(base + off);    off += (size_t)2 * Nn * 4;
    int* segoff  = (int*)(base + off);    off += (size_t)2 * Nn * 4;
    int* bsum    = (int*)(base + off);    off += (size_t)1024 * 4;
    int* srcs    = (int*)(base + off);    off += (size_t)2 * E_ * 4;  // [M][E]
    unsigned short* Wb = (unsigned short*)(base + off); off += (size_t)2 * 65536 * 2;
    unsigned short* rb = (unsigned short*)(base + off);
    const bool rb16 = (ws_size >= off + ND * 2);
    void* r_any = rb16 ? (void*)rb : (void*)out;

    // zero hist + cursor (contiguous)
    hipMemsetAsync(hist, 0, (size_t)4 * Nn * 4, stream);

    convert_w<<<128, 256, 0, stream>>>(W_l, W_r, Wb);

    int rowTiles = (Nn + 127) / 128;   // 782
    int nblk = 4 * rowTiles;           // 3128 (divisible by 8)
    if (rb16)
        gemm_fused<true ><<<nblk, 256, 0, stream>>>(
            x, Wb, b_l, b_r, attn, rel_l, rel_r, l, r_any, ej2, al, rd, Nn, nblk);
    else
        gemm_fused<false><<<nblk, 256, 0, stream>>>(
            x, Wb, b_l, b_r, attn, rel_l, rel_r, l, r_any, ej2, al, rd, Nn, nblk);

    int eb = (E_ + 255) / 256;
    int nb = (Nn + 255) / 256;   // 391
    edge_hist<<<eb, 256, 0, stream>>>(ei0, ei1, hist, E_, Nn);
    scan_a<<<dim3(nb, 2), 256, 0, stream>>>(hist, segoff, bsum, Nn);
    scan_b<<<2, 512, 0, stream>>>(bsum, nb);
    edge_scatter<<<eb, 256, 0, stream>>>(ei0, ei1, segoff, bsum, cursor, srcs, E_, Nn);

    if (rb16)
        aggregate<true ><<<(Nn + 1) / 2, 256, 0, stream>>>(
            hist, segoff, bsum, srcs, ej2, al, rd, r_any, l, out, Nn, E_);
    else
        aggregate<false><<<(Nn + 1) / 2, 256, 0, stream>>>(
            hist, segoff, bsum, srcs, ej2, al, rd, r_any, l, out, Nn, E_);
}

// Round 11
// 438.183 us; speedup vs baseline: 15.6497x; 1.0069x over previous
//
#include <hip/hip_runtime.h>
#include <hip/hip_bf16.h>
#include <math.h>

#define D_ 256
#define H_ 4
#define C_ 64

typedef __attribute__((ext_vector_type(8))) short short8;
typedef __attribute__((ext_vector_type(4))) float f32x4;

// ---------- helpers ----------
__device__ inline float lrelu(float v) { return v >= 0.f ? v : 0.2f * v; }

// bf16 bit helpers
__device__ inline unsigned short f2b(float f) {
    unsigned u = __float_as_uint(f);
    u = (u + 0x7FFFu + ((u >> 16) & 1u)) >> 16;   // round-to-nearest-even
    return (unsigned short)u;
}
__device__ inline float b2f(unsigned short u) {
    return __uint_as_float(((unsigned)u) << 16);
}

#define GLDS(src, dst) __builtin_amdgcn_global_load_lds(                      \
    (const __attribute__((address_space(1))) void*)(src),                     \
    (__attribute__((address_space(3))) void*)(dst), 16, 0, 0)

// ---------- W -> bf16 ----------
__global__ __launch_bounds__(256) void convert_w(
    const float* __restrict__ Wl, const float* __restrict__ Wr,
    unsigned short* __restrict__ Wb)
{
    int i4 = blockIdx.x * 256 + threadIdx.x;          // 0..32767 float4s
    float4 v = (i4 < 16384) ? ((const float4*)Wl)[i4]
                            : ((const float4*)Wr)[i4 - 16384];
    ushort4 u;
    u.x = f2b(v.x); u.y = f2b(v.y); u.z = f2b(v.z); u.w = f2b(v.w);
    ((ushort4*)Wb)[i4] = u;
}

// ---------- staging ----------
__device__ __forceinline__ void stage_a(const float* __restrict__ x, float* dst,
                                        int bm, int k0, int wv, int lane, int Mrows)
{
#pragma unroll
    for (int p = 0; p < 4; p++) {
        int ci = (p * 4 + wv) * 64 + lane;            // chunk 0..1023
        int row = ci >> 3, cc = ci & 7;
        int gr = bm + row; if (gr >= Mrows) gr = Mrows - 1;
        const float* src = x + (size_t)gr * 256 + k0 + ((cc ^ (row & 7)) << 2);
        GLDS(src, (char*)dst + (size_t)(p * 4 + wv) * 1024);
    }
}
__device__ __forceinline__ void stage_b(const unsigned short* __restrict__ W,
                                        unsigned short* dst, int bn, int k0,
                                        int wv, int lane)
{
#pragma unroll
    for (int p = 0; p < 2; p++) {
        int ci = (p * 4 + wv) * 64 + lane;            // chunk 0..511
        int col = ci >> 2, cc = ci & 3;
        const unsigned short* src = W + (size_t)(bn + col) * 256 + k0 +
                                    ((cc ^ (col & 3)) << 3);
        GLDS(src, (char*)dst + (size_t)(p * 4 + wv) * 1024);
    }
}

// ---------- MFMA GEMM with fused per-node logits in the epilogue ----------
// Each wave's output = 64 rows x one head's 64 cols -> logit dots reduce
// entirely within the wave (16-lane col groups). sel=0 waves emit ej2;
// sel=1 waves emit al, rd.
template <bool RB16>
__global__ __launch_bounds__(256) void gemm_fused(
    const float* __restrict__ x, const unsigned short* __restrict__ Wb,
    const float* __restrict__ b_l, const float* __restrict__ b_r,
    const float* __restrict__ attn, const float* __restrict__ rel_l,
    const float* __restrict__ rel_r,
    unsigned short* __restrict__ lout, void* __restrict__ rout,
    float2* __restrict__ ej2, float* __restrict__ al, float* __restrict__ rd,
    int Mrows, int nblk)
{
    int hw = blockIdx.x;
    int orig = hw;
    if ((nblk & 7) == 0) {                 // bijective chunked swizzle
        int cpx = nblk >> 3;
        orig = (hw & 7) * cpx + (hw >> 3);
    }
    const int sel = (orig & 3) >> 1;       // 0 = l, 1 = r
    const int bn = (orig & 1) * 128;
    const int bm = (orig >> 2) * 128;

    __shared__ float As[2][128 * 32];
    __shared__ unsigned short Bs[2][128 * 32];
    const int tid = threadIdx.x;
    const int lane = tid & 63, wv = tid >> 6;
    const int wr = wv >> 1, wc = wv & 1;
    const unsigned short* W = Wb + (size_t)sel * 65536;

    f32x4 acc[4][4];
#pragma unroll
    for (int m = 0; m < 4; m++)
#pragma unroll
        for (int n = 0; n < 4; n++) acc[m][n] = (f32x4)0.f;

    stage_a(x, As[0], bm, 0, wv, lane, Mrows);
    stage_b(W, Bs[0], bn, 0, wv, lane);
    __syncthreads();

    int cur = 0;
#pragma unroll
    for (int t = 0; t < 8; t++) {
        if (t < 7) {
            stage_a(x, As[cur ^ 1], bm, (t + 1) * 32, wv, lane, Mrows);
            stage_b(W, Bs[cur ^ 1], bn, (t + 1) * 32, wv, lane);
        }
        short8 bfr[4];
#pragma unroll
        for (int n = 0; n < 4; n++) {
            int col = wc * 64 + n * 16 + (lane & 15);
            int sc = (lane >> 4) ^ (col & 3);
            bfr[n] = *(const short8*)&Bs[cur][col * 32 + sc * 8];
        }
        short8 afr[4];
#pragma unroll
        for (int m = 0; m < 4; m++) {
            int row = wr * 64 + m * 16 + (lane & 15);
            int c0 = (lane >> 4) * 2;
            const float* ap = &As[cur][row * 32];
            float4 f0 = *(const float4*)&ap[(c0 ^ (row & 7)) << 2];
            float4 f1 = *(const float4*)&ap[((c0 + 1) ^ (row & 7)) << 2];
            union { short8 v; __hip_bfloat162 b2[4]; } u;
            u.b2[0] = __float22bfloat162_rn(make_float2(f0.x, f0.y));
            u.b2[1] = __float22bfloat162_rn(make_float2(f0.z, f0.w));
            u.b2[2] = __float22bfloat162_rn(make_float2(f1.x, f1.y));
            u.b2[3] = __float22bfloat162_rn(make_float2(f1.z, f1.w));
            afr[m] = u.v;
        }
#pragma unroll
        for (int m = 0; m < 4; m++)
#pragma unroll
            for (int n = 0; n < 4; n++)
                acc[m][n] = __builtin_amdgcn_mfma_f32_16x16x32_bf16(
                    afr[m], bfr[n], acc[m][n], 0, 0, 0);
        __syncthreads();
        cur ^= 1;
    }

    // ---- fused epilogue ----
    const float* bias = sel ? b_r : b_l;
    const int NH = Mrows * H_;
    const int h = (bn >> 6) + wc;          // this wave's head
    float bv[4], w0[4], w1[4], w2[4];
    int gcol[4];
#pragma unroll
    for (int n = 0; n < 4; n++) {
        int c = n * 16 + (lane & 15);
        gcol[n] = bn + wc * 64 + c;
        bv[n] = bias[gcol[n]];
        if (sel == 0) {
            w0[n] = attn[(0 * H_ + h) * 128 + 64 + c];
            w1[n] = attn[(1 * H_ + h) * 128 + 64 + c];
            w2[n] = rel_r[h * C_ + c];
        } else {
            w0[n] = rel_l[h * C_ + c];
            w1[n] = rel_r[h * C_ + c];
        }
    }
#pragma unroll
    for (int m = 0; m < 4; m++) {
#pragma unroll
        for (int q = 0; q < 4; q++) {
            int grow = bm + wr * 64 + m * 16 + (lane >> 4) * 4 + q;
            bool ok = grow < Mrows;
            float p0 = 0.f, p1 = 0.f, p2 = 0.f;
#pragma unroll
            for (int n = 0; n < 4; n++) {
                float v = acc[m][n][q] + bv[n];
                if (ok) {
                    if (sel == 0) {
                        lout[(size_t)grow * 256 + gcol[n]] = f2b(v);
                    } else {
                        if (RB16) ((unsigned short*)rout)[(size_t)grow * 256 + gcol[n]] = f2b(v);
                        else      ((float*)rout)[(size_t)grow * 256 + gcol[n]] = v;
                    }
                }
                if (sel == 0) {
                    float lr = lrelu(v);
                    p0 = fmaf(lr, w0[n], p0);
                    p1 = fmaf(lr, w1[n], p1);
                    p2 = fmaf(v, w2[n], p2);
                } else {
                    p0 = fmaf(v, w0[n], p0);
                    p1 = fmaf(v, w1[n], p1);
                }
            }
#pragma unroll
            for (int off = 1; off < 16; off <<= 1) {
                p0 += __shfl_xor(p0, off);
                p1 += __shfl_xor(p1, off);
                if (sel == 0) p2 += __shfl_xor(p2, off);
            }
            if (ok && (lane & 15) == 0) {
                int nh = grow * H_ + h;
                if (sel == 0) {
                    float e0 = __expf(p0), e1 = __expf(p1);
                    ej2[nh]      = make_float2(e0, e0 * p2);
                    ej2[NH + nh] = make_float2(e1, e1 * p2);
                } else {
                    al[nh] = p0;
                    rd[nh] = p1;
                }
            }
        }
    }
}

// ---------- CSR build: histogram ----------
__global__ __launch_bounds__(256) void edge_hist(
    const int* __restrict__ ei0, const int* __restrict__ ei1,
    int* __restrict__ hist, int E_, int Nn)
{
    int e = blockIdx.x * 256 + threadIdx.x;
    if (e >= E_) return;
    atomicAdd(&hist[ei0[E_ + e]], 1);
    atomicAdd(&hist[Nn + ei1[E_ + e]], 1);
}

// ---------- CSR build: 2-kernel exclusive scan (block sums folded downstream) ----------
__global__ __launch_bounds__(256) void scan_a(
    const int* __restrict__ hist, int* __restrict__ segoff,
    int* __restrict__ bsum, int Nn)
{
    int m = blockIdx.y;
    int gid = blockIdx.x * 256 + threadIdx.x;
    int lane = threadIdx.x & 63, wid = threadIdx.x >> 6;
    int v = (gid < Nn) ? hist[m * Nn + gid] : 0;
    int incl = v;
#pragma unroll
    for (int off = 1; off < 64; off <<= 1) {
        int u = __shfl_up(incl, off);
        if (lane >= off) incl += u;
    }
    __shared__ int ws[4], wo[4];
    if (lane == 63) ws[wid] = incl;
    __syncthreads();
    if (threadIdx.x == 0) {
        int run = 0;
#pragma unroll
        for (int i = 0; i < 4; i++) { wo[i] = run; run += ws[i]; }
        bsum[m * 512 + blockIdx.x] = run;
    }
    __syncthreads();
    if (gid < Nn) segoff[m * Nn + gid] = incl - v + wo[wid];
}

__global__ __launch_bounds__(512) void scan_b(int* __restrict__ bsum, int nb)
{
    int m = blockIdx.x;
    int* b = bsum + m * 512;
    int tid = threadIdx.x, lane = tid & 63, wid = tid >> 6;
    int v = (tid < nb) ? b[tid] : 0;
    int incl = v;
#pragma unroll
    for (int off = 1; off < 64; off <<= 1) {
        int u = __shfl_up(incl, off);
        if (lane >= off) incl += u;
    }
    __shared__ int ws[8], wo[8];
    if (lane == 63) ws[wid] = incl;
    __syncthreads();
    if (tid == 0) {
        int run = 0;
#pragma unroll
        for (int i = 0; i < 8; i++) { wo[i] = run; run += ws[i]; }
    }
    __syncthreads();
    if (tid < nb) b[tid] = incl - v + wo[wid];
}

// ---------- CSR build: scatter (adds bsum inline) ----------
__global__ __launch_bounds__(256) void edge_scatter(
    const int* __restrict__ ei0, const int* __restrict__ ei1,
    const int* __restrict__ segoff, const int* __restrict__ bsum,
    int* __restrict__ cursor, int* __restrict__ srcs, int E_, int Nn)
{
    int e = blockIdx.x * 256 + threadIdx.x;
    if (e >= E_) return;
    int t0 = ei0[E_ + e];
    int p0 = segoff[t0] + bsum[t0 >> 8] + atomicAdd(&cursor[t0], 1);
    srcs[p0] = ei0[e];
    int t1 = ei1[E_ + e];
    int p1 = segoff[Nn + t1] + bsum[512 + (t1 >> 8)] + atomicAdd(&cursor[Nn + t1], 1);
    srcs[E_ + p1] = ei1[e];
}

// ---------- single-pass aggregation: wave per target, dual accumulators ----------
template <bool RB16>
__global__ __launch_bounds__(256) void aggregate(
    const int* __restrict__ hist, const int* __restrict__ segoff,
    const int* __restrict__ bsum,
    const int* __restrict__ srcs, const float2* __restrict__ ej2,
    const float* __restrict__ al, const float* __restrict__ rd,
    const void* __restrict__ rv, const unsigned short* __restrict__ l,
    float* __restrict__ out, int Nn, int E_)
{
    int lane = threadIdx.x & 63;
    int t = blockIdx.x * 4 + (threadIdx.x >> 6);
    if (t >= Nn) return;
    int h = lane >> 4;
    int NH = Nn * H_;
    int nh = t * H_ + h;

    // issue these early: consumed only after the edge loops
    float4 rrow;
    if (RB16) {
        ushort4 ru = ((const ushort4*)rv)[(size_t)t * 64 + lane];
        rrow = make_float4(b2f(ru.x), b2f(ru.y), b2f(ru.z), b2f(ru.w));
    } else {
        rrow = ((const float4*)rv)[(size_t)t * 64 + lane];
    }
    float a = al[nh];
    float rdv = rd[nh];

    float4 accm[2];
    float denm[2], pnm[2];
#pragma unroll
    for (int m = 0; m < 2; m++) {
        const int* sp = srcs + (size_t)m * E_;
        const float2* ep = ej2 + (size_t)m * NH;
        int beg = segoff[m * Nn + t] + bsum[m * 512 + (t >> 8)];
        int deg = hist[m * Nn + t];

        float4 aA = make_float4(0.f, 0.f, 0.f, 0.f);
        float4 aB = make_float4(0.f, 0.f, 0.f, 0.f);
        float dA = 0.f, dB = 0.f, pA = 0.f, pB = 0.f;
        int j = 0;
#pragma unroll 2
        for (; j + 1 < deg; j += 2) {
            int s0 = sp[beg + j];
            int s1 = sp[beg + j + 1];
            float2 v0 = ep[(size_t)s0 * H_ + h];
            float2 v1 = ep[(size_t)s1 * H_ + h];
            ushort4 l0 = *(const ushort4*)&l[(size_t)s0 * D_ + lane * 4];
            ushort4 l1 = *(const ushort4*)&l[(size_t)s1 * D_ + lane * 4];
            dA += v0.x; pA += v0.y;
            dB += v1.x; pB += v1.y;
            aA.x = fmaf(b2f(l0.x), v0.x, aA.x);
            aA.y = fmaf(b2f(l0.y), v0.x, aA.y);
            aA.z = fmaf(b2f(l0.z), v0.x, aA.z);
            aA.w = fmaf(b2f(l0.w), v0.x, aA.w);
            aB.x = fmaf(b2f(l1.x), v1.x, aB.x);
            aB.y = fmaf(b2f(l1.y), v1.x, aB.y);
            aB.z = fmaf(b2f(l1.z), v1.x, aB.z);
            aB.w = fmaf(b2f(l1.w), v1.x, aB.w);
        }
        if (j < deg) {
            int s0 = sp[beg + j];
            float2 v0 = ep[(size_t)s0 * H_ + h];
            ushort4 l0 = *(const ushort4*)&l[(size_t)s0 * D_ + lane * 4];
            dA += v0.x; pA += v0.y;
            aA.x = fmaf(b2f(l0.x), v0.x, aA.x);
            aA.y = fmaf(b2f(l0.y), v0.x, aA.y);
            aA.z = fmaf(b2f(l0.z), v0.x, aA.z);
            aA.w = fmaf(b2f(l0.w), v0.x, aA.w);
        }
        accm[m] = make_float4(aA.x + aB.x, aA.y + aB.y, aA.z + aB.z, aA.w + aB.w);
        denm[m] = dA + dB;
        pnm[m] = pA + pB;
    }

    float b0 = lrelu(a + pnm[0] / (denm[0] + 1e-16f));
    float b1 = lrelu(a + pnm[1] / (denm[1] + 1e-16f));
    float b2 = lrelu(a + rdv);
    float mm = fmaxf(b0, fmaxf(b1, b2));
    float e0 = __expf(b0 - mm), e1 = __expf(b1 - mm), e2 = __expf(b2 - mm);
    float inv = 1.f / (e0 + e1 + e2);
    float wm0 = e0 * inv / (denm[0] + 1e-16f);
    float wm1 = e1 * inv / (denm[1] + 1e-16f);
    float b2v = e2 * inv;

    float4 o;
    o.x = fmaxf(fmaf(wm0, accm[0].x, fmaf(wm1, accm[1].x, b2v * rrow.x)), 0.f);
    o.y = fmaxf(fmaf(wm0, accm[0].y, fmaf(wm1, accm[1].y, b2v * rrow.y)), 0.f);
    o.z = fmaxf(fmaf(wm0, accm[0].z, fmaf(wm1, accm[1].z, b2v * rrow.z)), 0.f);
    o.w = fmaxf(fmaf(wm0, accm[0].w, fmaf(wm1, accm[1].w, b2v * rrow.w)), 0.f);
    *(float4*)&out[(size_t)t * D_ + lane * 4] = o;
}

extern "C" void kernel_launch(void* const* d_in, const int* in_sizes, int n_in,
                              void* d_out, int out_size, void* d_ws, size_t ws_size,
                              hipStream_t stream) {
    const float* x     = (const float*)d_in[0];
    const int*   ei0   = (const int*)d_in[1];
    const int*   ei1   = (const int*)d_in[2];
    const float* W_l   = (const float*)d_in[3];
    const float* b_l   = (const float*)d_in[4];
    const float* W_r   = (const float*)d_in[5];
    const float* b_r   = (const float*)d_in[6];
    const float* attn  = (const float*)d_in[7];
    const float* rel_l = (const float*)d_in[8];
    const float* rel_r = (const float*)d_in[9];
    float* out = (float*)d_out;

    const int Nn = in_sizes[0] / D_;        // 100000
    const int E_ = in_sizes[1] / 2;         // 800000
    const size_t ND = (size_t)Nn * D_;
    const int NH = Nn * H_;

    // ---- workspace layout (~70 MB base; +51 MB rb if it fits — proven) ----
    char* base = (char*)d_ws;
    unsigned short* l = (unsigned short*)base;      size_t off = ND * 2;
    float2* ej2  = (float2*)(base + off); off += (size_t)2 * NH * 8;  // [M][N][H]
    float* al    = (float*)(base + off);  off += (size_t)NH * 4;
    float* rd    = (float*)(base + off);  off += (size_t)NH * 4;
    int* hist    = (int*)(base + off);    off += (size_t)2 * Nn * 4;  // [M][Nn]
    int* cursor  = (int*)(base + off);    off += (size_t)2 * Nn * 4;
    int* segoff  = (int*)(base + off);    off += (size_t)2 * Nn * 4;
    int* bsum    = (int*)(base + off);    off += (size_t)1024 * 4;
    int* srcs    = (int*)(base + off);    off += (size_t)2 * E_ * 4;  // [M][E]
    unsigned short* Wb = (unsigned short*)(base + off); off += (size_t)2 * 65536 * 2;
    unsigned short* rb = (unsigned short*)(base + off);
    const bool rb16 = (ws_size >= off + ND * 2);
    void* r_any = rb16 ? (void*)rb : (void*)out;

    // zero hist + cursor (contiguous)
    hipMemsetAsync(hist, 0, (size_t)4 * Nn * 4, stream);

    convert_w<<<128, 256, 0, stream>>>(W_l, W_r, Wb);

    int rowTiles = (Nn + 127) / 128;   // 782
    int nblk = 4 * rowTiles;           // 3128 (divisible by 8)
    if (rb16)
        gemm_fused<true ><<<nblk, 256, 0, stream>>>(
            x, Wb, b_l, b_r, attn, rel_l, rel_r, l, r_any, ej2, al, rd, Nn, nblk);
    else
        gemm_fused<false><<<nblk, 256, 0, stream>>>(
            x, Wb, b_l, b_r, attn, rel_l, rel_r, l, r_any, ej2, al, rd, Nn, nblk);

    int eb = (E_ + 255) / 256;
    int nb = (Nn + 255) / 256;   // 391
    edge_hist<<<eb, 256, 0, stream>>>(ei0, ei1, hist, E_, Nn);
    scan_a<<<dim3(nb, 2), 256, 0, stream>>>(hist, segoff, bsum, Nn);
    scan_b<<<2, 512, 0, stream>>>(bsum, nb);
    edge_scatter<<<eb, 256, 0, stream>>>(ei0, ei1, segoff, bsum, cursor, srcs, E_, Nn);

    if (rb16)
        aggregate<true ><<<(Nn + 3) / 4, 256, 0, stream>>>(
            hist, segoff, bsum, srcs, ej2, al, rd, r_any, l, out, Nn, E_);
    else
        aggregate<false><<<(Nn + 3) / 4, 256, 0, stream>>>(
            hist, segoff, bsum, srcs, ej2, al, rd, r_any, l, out, Nn, E_);
}

// Round 12
// 427.635 us; speedup vs baseline: 16.0357x; 1.0247x over previous
//
#include <hip/hip_runtime.h>
#include <hip/hip_bf16.h>
#include <math.h>

#define D_ 256
#define H_ 4
#define C_ 64

typedef __attribute__((ext_vector_type(8))) short short8;
typedef __attribute__((ext_vector_type(4))) float f32x4;

// ---------- helpers ----------
__device__ inline float lrelu(float v) { return v >= 0.f ? v : 0.2f * v; }

// bf16 bit helpers
__device__ inline unsigned short f2b(float f) {
    unsigned u = __float_as_uint(f);
    u = (u + 0x7FFFu + ((u >> 16) & 1u)) >> 16;   // round-to-nearest-even
    return (unsigned short)u;
}
__device__ inline float b2f(unsigned short u) {
    return __uint_as_float(((unsigned)u) << 16);
}

#define GLDS(src, dst) __builtin_amdgcn_global_load_lds(                      \
    (const __attribute__((address_space(1))) void*)(src),                     \
    (__attribute__((address_space(3))) void*)(dst), 16, 0, 0)

// ---------- W -> bf16 ----------
__global__ __launch_bounds__(256) void convert_w(
    const float* __restrict__ Wl, const float* __restrict__ Wr,
    unsigned short* __restrict__ Wb)
{
    int i4 = blockIdx.x * 256 + threadIdx.x;          // 0..32767 float4s
    float4 v = (i4 < 16384) ? ((const float4*)Wl)[i4]
                            : ((const float4*)Wr)[i4 - 16384];
    ushort4 u;
    u.x = f2b(v.x); u.y = f2b(v.y); u.z = f2b(v.z); u.w = f2b(v.w);
    ((ushort4*)Wb)[i4] = u;
}

// ---------- staging ----------
// A: reg-staged f32 -> bf16 (rn), same rounding point as before (bit-identical)
__device__ __forceinline__ void load_a_regs(const float* __restrict__ x,
                                            int bm, int k0, int tid, int Mrows,
                                            float4 f[4])
{
    int row = tid >> 1;
    int gr = bm + row; if (gr >= Mrows) gr = Mrows - 1;
    const float* src = x + (size_t)gr * 256 + k0 + (tid & 1) * 16;
    f[0] = ((const float4*)src)[0];
    f[1] = ((const float4*)src)[1];
    f[2] = ((const float4*)src)[2];
    f[3] = ((const float4*)src)[3];
}
__device__ __forceinline__ void write_a_lds(unsigned short* As, int tid,
                                            const float4 f[4])
{
    int row = tid >> 1;
    int cc0 = (tid & 1) * 2;
    int sw = row & 3;
    union { short8 v; __hip_bfloat162 b[4]; } u0, u1;
    u0.b[0] = __float22bfloat162_rn(make_float2(f[0].x, f[0].y));
    u0.b[1] = __float22bfloat162_rn(make_float2(f[0].z, f[0].w));
    u0.b[2] = __float22bfloat162_rn(make_float2(f[1].x, f[1].y));
    u0.b[3] = __float22bfloat162_rn(make_float2(f[1].z, f[1].w));
    u1.b[0] = __float22bfloat162_rn(make_float2(f[2].x, f[2].y));
    u1.b[1] = __float22bfloat162_rn(make_float2(f[2].z, f[2].w));
    u1.b[2] = __float22bfloat162_rn(make_float2(f[3].x, f[3].y));
    u1.b[3] = __float22bfloat162_rn(make_float2(f[3].z, f[3].w));
    *(short8*)&As[row * 32 + ((cc0 ^ sw) << 3)]       = u0.v;
    *(short8*)&As[row * 32 + (((cc0 + 1) ^ sw) << 3)] = u1.v;
}
__device__ __forceinline__ void stage_b(const unsigned short* __restrict__ W,
                                        unsigned short* dst, int bn, int k0,
                                        int wv, int lane)
{
#pragma unroll
    for (int p = 0; p < 2; p++) {
        int ci = (p * 4 + wv) * 64 + lane;            // chunk 0..511
        int col = ci >> 2, cc = ci & 3;
        const unsigned short* src = W + (size_t)(bn + col) * 256 + k0 +
                                    ((cc ^ (col & 3)) << 3);
        GLDS(src, (char*)dst + (size_t)(p * 4 + wv) * 1024);
    }
}

// ---------- MFMA GEMM (fused logits epilogue) + edge_hist heterogeneous blocks ----------
template <bool RB16>
__global__ __launch_bounds__(256) void gemm_hist(
    const float* __restrict__ x, const unsigned short* __restrict__ Wb,
    const float* __restrict__ b_l, const float* __restrict__ b_r,
    const float* __restrict__ attn, const float* __restrict__ rel_l,
    const float* __restrict__ rel_r,
    unsigned short* __restrict__ lout, void* __restrict__ rout,
    float2* __restrict__ ej2, float* __restrict__ al, float* __restrict__ rd,
    const int* __restrict__ ei0, const int* __restrict__ ei1,
    int* __restrict__ hist,
    int Mrows, int nblk, int E_)
{
    const int tid = threadIdx.x;

    // ---- heterogeneous tail: edge histogram ----
    if ((int)blockIdx.x >= nblk) {
        int e = ((int)blockIdx.x - nblk) * 256 + tid;
        if (e < E_) {
            atomicAdd(&hist[ei0[E_ + e]], 1);
            atomicAdd(&hist[Mrows + ei1[E_ + e]], 1);
        }
        return;
    }

    int hw = blockIdx.x;
    int orig = hw;
    if ((nblk & 7) == 0) {                 // bijective chunked XCD swizzle
        int cpx = nblk >> 3;
        orig = (hw & 7) * cpx + (hw >> 3);
    }
    const int sel = (orig & 3) >> 1;       // 0 = l, 1 = r
    const int bn = (orig & 1) * 128;
    const int bm = (orig >> 2) * 128;

    __shared__ unsigned short As[2][128 * 32];
    __shared__ unsigned short Bs[2][128 * 32];
    const int lane = tid & 63, wv = tid >> 6;
    const int wr = wv >> 1, wc = wv & 1;
    const unsigned short* W = Wb + (size_t)sel * 65536;

    f32x4 acc[4][4];
#pragma unroll
    for (int m = 0; m < 4; m++)
#pragma unroll
        for (int n = 0; n < 4; n++) acc[m][n] = (f32x4)0.f;

    float4 fr[4];
    load_a_regs(x, bm, 0, tid, Mrows, fr);
    stage_b(W, Bs[0], bn, 0, wv, lane);
    write_a_lds(As[0], tid, fr);
    __syncthreads();

    int cur = 0;
#pragma unroll
    for (int t = 0; t < 8; t++) {
        if (t < 7) {
            load_a_regs(x, bm, (t + 1) * 32, tid, Mrows, fr);   // issue early
            stage_b(W, Bs[cur ^ 1], bn, (t + 1) * 32, wv, lane);
        }
        short8 bfr[4], afr[4];
#pragma unroll
        for (int n = 0; n < 4; n++) {
            int col = wc * 64 + n * 16 + (lane & 15);
            int sc = (lane >> 4) ^ (col & 3);
            bfr[n] = *(const short8*)&Bs[cur][col * 32 + sc * 8];
        }
#pragma unroll
        for (int m = 0; m < 4; m++) {
            int row = wr * 64 + m * 16 + (lane & 15);
            int sa = (lane >> 4) ^ (row & 3);
            afr[m] = *(const short8*)&As[cur][row * 32 + sa * 8];
        }
#pragma unroll
        for (int m = 0; m < 4; m++)
#pragma unroll
            for (int n = 0; n < 4; n++)
                acc[m][n] = __builtin_amdgcn_mfma_f32_16x16x32_bf16(
                    afr[m], bfr[n], acc[m][n], 0, 0, 0);
        if (t < 7) write_a_lds(As[cur ^ 1], tid, fr);   // write-late (T14)
        __syncthreads();
        cur ^= 1;
    }

    // ---- fused epilogue: stores + per-node logit partials ----
    const float* bias = sel ? b_r : b_l;
    const int NH = Mrows * H_;
    const int h = (bn >> 6) + wc;          // this wave's head
    float bv[4], w0[4], w1[4], w2[4];
    int gcol[4];
#pragma unroll
    for (int n = 0; n < 4; n++) {
        int c = n * 16 + (lane & 15);
        gcol[n] = bn + wc * 64 + c;
        bv[n] = bias[gcol[n]];
        if (sel == 0) {
            w0[n] = attn[(0 * H_ + h) * 128 + 64 + c];
            w1[n] = attn[(1 * H_ + h) * 128 + 64 + c];
            w2[n] = rel_r[h * C_ + c];
        } else {
            w0[n] = rel_l[h * C_ + c];
            w1[n] = rel_r[h * C_ + c];
        }
    }
#pragma unroll
    for (int m = 0; m < 4; m++) {
#pragma unroll
        for (int q = 0; q < 4; q++) {
            int grow = bm + wr * 64 + m * 16 + (lane >> 4) * 4 + q;
            bool ok = grow < Mrows;
            float p0 = 0.f, p1 = 0.f, p2 = 0.f;
#pragma unroll
            for (int n = 0; n < 4; n++) {
                float v = acc[m][n][q] + bv[n];
                if (ok) {
                    if (sel == 0) {
                        lout[(size_t)grow * 256 + gcol[n]] = f2b(v);
                    } else {
                        if (RB16) ((unsigned short*)rout)[(size_t)grow * 256 + gcol[n]] = f2b(v);
                        else      ((float*)rout)[(size_t)grow * 256 + gcol[n]] = v;
                    }
                }
                if (sel == 0) {
                    float lr = lrelu(v);
                    p0 = fmaf(lr, w0[n], p0);
                    p1 = fmaf(lr, w1[n], p1);
                    p2 = fmaf(v, w2[n], p2);
                } else {
                    p0 = fmaf(v, w0[n], p0);
                    p1 = fmaf(v, w1[n], p1);
                }
            }
#pragma unroll
            for (int off = 1; off < 16; off <<= 1) {
                p0 += __shfl_xor(p0, off);
                p1 += __shfl_xor(p1, off);
                if (sel == 0) p2 += __shfl_xor(p2, off);
            }
            if (ok && (lane & 15) == 0) {
                int nh = grow * H_ + h;
                if (sel == 0) {
                    float e0 = __expf(p0), e1 = __expf(p1);
                    ej2[nh]      = make_float2(e0, e0 * p2);
                    ej2[NH + nh] = make_float2(e1, e1 * p2);
                } else {
                    al[nh] = p0;
                    rd[nh] = p1;
                }
            }
        }
    }
}

// ---------- CSR build: 2-kernel exclusive scan (block sums folded downstream) ----------
__global__ __launch_bounds__(256) void scan_a(
    const int* __restrict__ hist, int* __restrict__ segoff,
    int* __restrict__ bsum, int Nn)
{
    int m = blockIdx.y;
    int gid = blockIdx.x * 256 + threadIdx.x;
    int lane = threadIdx.x & 63, wid = threadIdx.x >> 6;
    int v = (gid < Nn) ? hist[m * Nn + gid] : 0;
    int incl = v;
#pragma unroll
    for (int off = 1; off < 64; off <<= 1) {
        int u = __shfl_up(incl, off);
        if (lane >= off) incl += u;
    }
    __shared__ int ws[4], wo[4];
    if (lane == 63) ws[wid] = incl;
    __syncthreads();
    if (threadIdx.x == 0) {
        int run = 0;
#pragma unroll
        for (int i = 0; i < 4; i++) { wo[i] = run; run += ws[i]; }
        bsum[m * 512 + blockIdx.x] = run;
    }
    __syncthreads();
    if (gid < Nn) segoff[m * Nn + gid] = incl - v + wo[wid];
}

__global__ __launch_bounds__(512) void scan_b(int* __restrict__ bsum, int nb)
{
    int m = blockIdx.x;
    int* b = bsum + m * 512;
    int tid = threadIdx.x, lane = tid & 63, wid = tid >> 6;
    int v = (tid < nb) ? b[tid] : 0;
    int incl = v;
#pragma unroll
    for (int off = 1; off < 64; off <<= 1) {
        int u = __shfl_up(incl, off);
        if (lane >= off) incl += u;
    }
    __shared__ int ws[8], wo[8];
    if (lane == 63) ws[wid] = incl;
    __syncthreads();
    if (tid == 0) {
        int run = 0;
#pragma unroll
        for (int i = 0; i < 8; i++) { wo[i] = run; run += ws[i]; }
    }
    __syncthreads();
    if (tid < nb) b[tid] = incl - v + wo[wid];
}

// ---------- CSR build: scatter (adds bsum inline) ----------
__global__ __launch_bounds__(256) void edge_scatter(
    const int* __restrict__ ei0, const int* __restrict__ ei1,
    const int* __restrict__ segoff, const int* __restrict__ bsum,
    int* __restrict__ cursor, int* __restrict__ srcs, int E_, int Nn)
{
    int e = blockIdx.x * 256 + threadIdx.x;
    if (e >= E_) return;
    int t0 = ei0[E_ + e];
    int p0 = segoff[t0] + bsum[t0 >> 8] + atomicAdd(&cursor[t0], 1);
    srcs[p0] = ei0[e];
    int t1 = ei1[E_ + e];
    int p1 = segoff[Nn + t1] + bsum[512 + (t1 >> 8)] + atomicAdd(&cursor[Nn + t1], 1);
    srcs[E_ + p1] = ei1[e];
}

// ---------- single-pass aggregation: wave per target, dual accumulators ----------
template <bool RB16>
__global__ __launch_bounds__(256) void aggregate(
    const int* __restrict__ hist, const int* __restrict__ segoff,
    const int* __restrict__ bsum,
    const int* __restrict__ srcs, const float2* __restrict__ ej2,
    const float* __restrict__ al, const float* __restrict__ rd,
    const void* __restrict__ rv, const unsigned short* __restrict__ l,
    float* __restrict__ out, int Nn, int E_)
{
    int lane = threadIdx.x & 63;
    int t = blockIdx.x * 4 + (threadIdx.x >> 6);
    if (t >= Nn) return;
    int h = lane >> 4;
    int NH = Nn * H_;
    int nh = t * H_ + h;

    // issue these early: consumed only after the edge loops
    float4 rrow;
    if (RB16) {
        ushort4 ru = ((const ushort4*)rv)[(size_t)t * 64 + lane];
        rrow = make_float4(b2f(ru.x), b2f(ru.y), b2f(ru.z), b2f(ru.w));
    } else {
        rrow = ((const float4*)rv)[(size_t)t * 64 + lane];
    }
    float a = al[nh];
    float rdv = rd[nh];

    float4 accm[2];
    float denm[2], pnm[2];
#pragma unroll
    for (int m = 0; m < 2; m++) {
        const int* sp = srcs + (size_t)m * E_;
        const float2* ep = ej2 + (size_t)m * NH;
        int beg = segoff[m * Nn + t] + bsum[m * 512 + (t >> 8)];
        int deg = hist[m * Nn + t];

        float4 aA = make_float4(0.f, 0.f, 0.f, 0.f);
        float4 aB = make_float4(0.f, 0.f, 0.f, 0.f);
        float dA = 0.f, dB = 0.f, pA = 0.f, pB = 0.f;
        int j = 0;
#pragma unroll 2
        for (; j + 1 < deg; j += 2) {
            int s0 = sp[beg + j];
            int s1 = sp[beg + j + 1];
            float2 v0 = ep[(size_t)s0 * H_ + h];
            float2 v1 = ep[(size_t)s1 * H_ + h];
            ushort4 l0 = *(const ushort4*)&l[(size_t)s0 * D_ + lane * 4];
            ushort4 l1 = *(const ushort4*)&l[(size_t)s1 * D_ + lane * 4];
            dA += v0.x; pA += v0.y;
            dB += v1.x; pB += v1.y;
            aA.x = fmaf(b2f(l0.x), v0.x, aA.x);
            aA.y = fmaf(b2f(l0.y), v0.x, aA.y);
            aA.z = fmaf(b2f(l0.z), v0.x, aA.z);
            aA.w = fmaf(b2f(l0.w), v0.x, aA.w);
            aB.x = fmaf(b2f(l1.x), v1.x, aB.x);
            aB.y = fmaf(b2f(l1.y), v1.x, aB.y);
            aB.z = fmaf(b2f(l1.z), v1.x, aB.z);
            aB.w = fmaf(b2f(l1.w), v1.x, aB.w);
        }
        if (j < deg) {
            int s0 = sp[beg + j];
            float2 v0 = ep[(size_t)s0 * H_ + h];
            ushort4 l0 = *(const ushort4*)&l[(size_t)s0 * D_ + lane * 4];
            dA += v0.x; pA += v0.y;
            aA.x = fmaf(b2f(l0.x), v0.x, aA.x);
            aA.y = fmaf(b2f(l0.y), v0.x, aA.y);
            aA.z = fmaf(b2f(l0.z), v0.x, aA.z);
            aA.w = fmaf(b2f(l0.w), v0.x, aA.w);
        }
        accm[m] = make_float4(aA.x + aB.x, aA.y + aB.y, aA.z + aB.z, aA.w + aB.w);
        denm[m] = dA + dB;
        pnm[m] = pA + pB;
    }

    float b0 = lrelu(a + pnm[0] / (denm[0] + 1e-16f));
    float b1 = lrelu(a + pnm[1] / (denm[1] + 1e-16f));
    float b2 = lrelu(a + rdv);
    float mm = fmaxf(b0, fmaxf(b1, b2));
    float e0 = __expf(b0 - mm), e1 = __expf(b1 - mm), e2 = __expf(b2 - mm);
    float inv = 1.f / (e0 + e1 + e2);
    float wm0 = e0 * inv / (denm[0] + 1e-16f);
    float wm1 = e1 * inv / (denm[1] + 1e-16f);
    float b2v = e2 * inv;

    float4 o;
    o.x = fmaxf(fmaf(wm0, accm[0].x, fmaf(wm1, accm[1].x, b2v * rrow.x)), 0.f);
    o.y = fmaxf(fmaf(wm0, accm[0].y, fmaf(wm1, accm[1].y, b2v * rrow.y)), 0.f);
    o.z = fmaxf(fmaf(wm0, accm[0].z, fmaf(wm1, accm[1].z, b2v * rrow.z)), 0.f);
    o.w = fmaxf(fmaf(wm0, accm[0].w, fmaf(wm1, accm[1].w, b2v * rrow.w)), 0.f);
    *(float4*)&out[(size_t)t * D_ + lane * 4] = o;
}

extern "C" void kernel_launch(void* const* d_in, const int* in_sizes, int n_in,
                              void* d_out, int out_size, void* d_ws, size_t ws_size,
                              hipStream_t stream) {
    const float* x     = (const float*)d_in[0];
    const int*   ei0   = (const int*)d_in[1];
    const int*   ei1   = (const int*)d_in[2];
    const float* W_l   = (const float*)d_in[3];
    const float* b_l   = (const float*)d_in[4];
    const float* W_r   = (const float*)d_in[5];
    const float* b_r   = (const float*)d_in[6];
    const float* attn  = (const float*)d_in[7];
    const float* rel_l = (const float*)d_in[8];
    const float* rel_r = (const float*)d_in[9];
    float* out = (float*)d_out;

    const int Nn = in_sizes[0] / D_;        // 100000
    const int E_ = in_sizes[1] / 2;         // 800000
    const size_t ND = (size_t)Nn * D_;
    const int NH = Nn * H_;

    // ---- workspace layout (~70 MB base; +51 MB rb if it fits — proven) ----
    char* base = (char*)d_ws;
    unsigned short* l = (unsigned short*)base;      size_t off = ND * 2;
    float2* ej2  = (float2*)(base + off); off += (size_t)2 * NH * 8;  // [M][N][H]
    float* al    = (float*)(base + off);  off += (size_t)NH * 4;
    float* rd    = (float*)(base + off);  off += (size_t)NH * 4;
    int* hist    = (int*)(base + off);    off += (size_t)2 * Nn * 4;  // [M][Nn]
    int* cursor  = (int*)(base + off);    off += (size_t)2 * Nn * 4;
    int* segoff  = (int*)(base + off);    off += (size_t)2 * Nn * 4;
    int* bsum    = (int*)(base + off);    off += (size_t)1024 * 4;
    int* srcs    = (int*)(base + off);    off += (size_t)2 * E_ * 4;  // [M][E]
    unsigned short* Wb = (unsigned short*)(base + off); off += (size_t)2 * 65536 * 2;
    unsigned short* rb = (unsigned short*)(base + off);
    const bool rb16 = (ws_size >= off + ND * 2);
    void* r_any = rb16 ? (void*)rb : (void*)out;

    // zero hist + cursor (contiguous)
    hipMemsetAsync(hist, 0, (size_t)4 * Nn * 4, stream);

    convert_w<<<128, 256, 0, stream>>>(W_l, W_r, Wb);

    int rowTiles = (Nn + 127) / 128;   // 782
    int nblk = 4 * rowTiles;           // 3128 (divisible by 8)
    int eb = (E_ + 255) / 256;         // 3125 hist blocks ride along
    if (rb16)
        gemm_hist<true ><<<nblk + eb, 256, 0, stream>>>(
            x, Wb, b_l, b_r, attn, rel_l, rel_r, l, r_any, ej2, al, rd,
            ei0, ei1, hist, Nn, nblk, E_);
    else
        gemm_hist<false><<<nblk + eb, 256, 0, stream>>>(
            x, Wb, b_l, b_r, attn, rel_l, rel_r, l, r_any, ej2, al, rd,
            ei0, ei1, hist, Nn, nblk, E_);

    int nb = (Nn + 255) / 256;   // 391
    scan_a<<<dim3(nb, 2), 256, 0, stream>>>(hist, segoff, bsum, Nn);
    scan_b<<<2, 512, 0, stream>>>(bsum, nb);
    edge_scatter<<<eb, 256, 0, stream>>>(ei0, ei1, segoff, bsum, cursor, srcs, E_, Nn);

    if (rb16)
        aggregate<true ><<<(Nn + 3) / 4, 256, 0, stream>>>(
            hist, segoff, bsum, srcs, ej2, al, rd, r_any, l, out, Nn, E_);
    else
        aggregate<false><<<(Nn + 3) / 4, 256, 0, stream>>>(
            hist, segoff, bsum, srcs, ej2, al, rd, r_any, l, out, Nn, E_);
}

// Round 13
// 424.844 us; speedup vs baseline: 16.1410x; 1.0066x over previous
//
#include <hip/hip_runtime.h>
#include <hip/hip_bf16.h>
#include <math.h>

#define D_ 256
#define H_ 4
#define C_ 64

typedef __attribute__((ext_vector_type(8))) short short8;
typedef __attribute__((ext_vector_type(4))) float f32x4;

// ---------- helpers ----------
__device__ inline float lrelu(float v) { return v >= 0.f ? v : 0.2f * v; }

// bf16 bit helpers
__device__ inline unsigned short f2b(float f) {
    unsigned u = __float_as_uint(f);
    u = (u + 0x7FFFu + ((u >> 16) & 1u)) >> 16;   // round-to-nearest-even
    return (unsigned short)u;
}
__device__ inline float b2f(unsigned short u) {
    return __uint_as_float(((unsigned)u) << 16);
}

#define GLDS(src, dst) __builtin_amdgcn_global_load_lds(                      \
    (const __attribute__((address_space(1))) void*)(src),                     \
    (__attribute__((address_space(3))) void*)(dst), 16, 0, 0)

// ---------- W -> bf16 ----------
__global__ __launch_bounds__(256) void convert_w(
    const float* __restrict__ Wl, const float* __restrict__ Wr,
    unsigned short* __restrict__ Wb)
{
    int i4 = blockIdx.x * 256 + threadIdx.x;          // 0..32767 float4s
    float4 v = (i4 < 16384) ? ((const float4*)Wl)[i4]
                            : ((const float4*)Wr)[i4 - 16384];
    ushort4 u;
    u.x = f2b(v.x); u.y = f2b(v.y); u.z = f2b(v.z); u.w = f2b(v.w);
    ((ushort4*)Wb)[i4] = u;
}

// ---------- staging ----------
// Swizzle note: bank = 16*(row&1) + 4*slot. Using slot = cc ^ ((row>>1)&3)
// makes (row&1, slot) independent -> all 32 banks covered, 8 acc/bank/wave
// (hardware minimum for b128). The old cc^(row&3) correlated slot with
// row parity -> half the banks idle, 2x conflict (4.8M cycles, round 12).
__device__ __forceinline__ void load_a_regs(const float* __restrict__ x,
                                            int bm, int k0, int tid, int Mrows,
                                            float4 f[4])
{
    int row = tid >> 1;
    int gr = bm + row; if (gr >= Mrows) gr = Mrows - 1;
    const float* src = x + (size_t)gr * 256 + k0 + (tid & 1) * 16;
    f[0] = ((const float4*)src)[0];
    f[1] = ((const float4*)src)[1];
    f[2] = ((const float4*)src)[2];
    f[3] = ((const float4*)src)[3];
}
__device__ __forceinline__ void write_a_lds(unsigned short* As, int tid,
                                            const float4 f[4])
{
    int row = tid >> 1;
    int cc0 = (tid & 1) * 2;
    int sw = (row >> 1) & 3;
    union { short8 v; __hip_bfloat162 b[4]; } u0, u1;
    u0.b[0] = __float22bfloat162_rn(make_float2(f[0].x, f[0].y));
    u0.b[1] = __float22bfloat162_rn(make_float2(f[0].z, f[0].w));
    u0.b[2] = __float22bfloat162_rn(make_float2(f[1].x, f[1].y));
    u0.b[3] = __float22bfloat162_rn(make_float2(f[1].z, f[1].w));
    u1.b[0] = __float22bfloat162_rn(make_float2(f[2].x, f[2].y));
    u1.b[1] = __float22bfloat162_rn(make_float2(f[2].z, f[2].w));
    u1.b[2] = __float22bfloat162_rn(make_float2(f[3].x, f[3].y));
    u1.b[3] = __float22bfloat162_rn(make_float2(f[3].z, f[3].w));
    *(short8*)&As[row * 32 + ((cc0 ^ sw) << 3)]       = u0.v;
    *(short8*)&As[row * 32 + (((cc0 + 1) ^ sw) << 3)] = u1.v;
}
__device__ __forceinline__ void stage_b(const unsigned short* __restrict__ W,
                                        unsigned short* dst, int bn, int k0,
                                        int wv, int lane)
{
#pragma unroll
    for (int p = 0; p < 2; p++) {
        int ci = (p * 4 + wv) * 64 + lane;            // chunk 0..511
        int col = ci >> 2, cc = ci & 3;
        const unsigned short* src = W + (size_t)(bn + col) * 256 + k0 +
                                    ((cc ^ ((col >> 1) & 3)) << 3);
        GLDS(src, (char*)dst + (size_t)(p * 4 + wv) * 1024);
    }
}

// ---------- MFMA GEMM (fused logits epilogue) + edge_hist heterogeneous blocks ----------
template <bool RB16>
__global__ __launch_bounds__(256) void gemm_hist(
    const float* __restrict__ x, const unsigned short* __restrict__ Wb,
    const float* __restrict__ b_l, const float* __restrict__ b_r,
    const float* __restrict__ attn, const float* __restrict__ rel_l,
    const float* __restrict__ rel_r,
    unsigned short* __restrict__ lout, void* __restrict__ rout,
    float2* __restrict__ ej2, float* __restrict__ al, float* __restrict__ rd,
    const int* __restrict__ ei0, const int* __restrict__ ei1,
    int* __restrict__ hist,
    int Mrows, int nblk, int E_)
{
    const int tid = threadIdx.x;

    // ---- heterogeneous tail: edge histogram ----
    if ((int)blockIdx.x >= nblk) {
        int e = ((int)blockIdx.x - nblk) * 256 + tid;
        if (e < E_) {
            atomicAdd(&hist[ei0[E_ + e]], 1);
            atomicAdd(&hist[Mrows + ei1[E_ + e]], 1);
        }
        return;
    }

    int hw = blockIdx.x;
    int orig = hw;
    if ((nblk & 7) == 0) {                 // bijective chunked XCD swizzle
        int cpx = nblk >> 3;
        orig = (hw & 7) * cpx + (hw >> 3);
    }
    const int sel = (orig & 3) >> 1;       // 0 = l, 1 = r
    const int bn = (orig & 1) * 128;
    const int bm = (orig >> 2) * 128;

    __shared__ unsigned short As[2][128 * 32];
    __shared__ unsigned short Bs[2][128 * 32];
    const int lane = tid & 63, wv = tid >> 6;
    const int wr = wv >> 1, wc = wv & 1;
    const unsigned short* W = Wb + (size_t)sel * 65536;

    f32x4 acc[4][4];
#pragma unroll
    for (int m = 0; m < 4; m++)
#pragma unroll
        for (int n = 0; n < 4; n++) acc[m][n] = (f32x4)0.f;

    float4 fr[4];
    load_a_regs(x, bm, 0, tid, Mrows, fr);
    stage_b(W, Bs[0], bn, 0, wv, lane);
    write_a_lds(As[0], tid, fr);
    __syncthreads();

    int cur = 0;
#pragma unroll
    for (int t = 0; t < 8; t++) {
        if (t < 7) {
            load_a_regs(x, bm, (t + 1) * 32, tid, Mrows, fr);   // issue early
            stage_b(W, Bs[cur ^ 1], bn, (t + 1) * 32, wv, lane);
        }
        short8 bfr[4], afr[4];
#pragma unroll
        for (int n = 0; n < 4; n++) {
            int col = wc * 64 + n * 16 + (lane & 15);
            int sc = (lane >> 4) ^ ((col >> 1) & 3);
            bfr[n] = *(const short8*)&Bs[cur][col * 32 + sc * 8];
        }
#pragma unroll
        for (int m = 0; m < 4; m++) {
            int row = wr * 64 + m * 16 + (lane & 15);
            int sa = (lane >> 4) ^ ((row >> 1) & 3);
            afr[m] = *(const short8*)&As[cur][row * 32 + sa * 8];
        }
#pragma unroll
        for (int m = 0; m < 4; m++)
#pragma unroll
            for (int n = 0; n < 4; n++)
                acc[m][n] = __builtin_amdgcn_mfma_f32_16x16x32_bf16(
                    afr[m], bfr[n], acc[m][n], 0, 0, 0);
        if (t < 7) write_a_lds(As[cur ^ 1], tid, fr);   // write-late (T14)
        __syncthreads();
        cur ^= 1;
    }

    // ---- fused epilogue: stores + per-node logit partials ----
    const float* bias = sel ? b_r : b_l;
    const int NH = Mrows * H_;
    const int h = (bn >> 6) + wc;          // this wave's head
    float bv[4], w0[4], w1[4], w2[4];
    int gcol[4];
#pragma unroll
    for (int n = 0; n < 4; n++) {
        int c = n * 16 + (lane & 15);
        gcol[n] = bn + wc * 64 + c;
        bv[n] = bias[gcol[n]];
        if (sel == 0) {
            w0[n] = attn[(0 * H_ + h) * 128 + 64 + c];
            w1[n] = attn[(1 * H_ + h) * 128 + 64 + c];
            w2[n] = rel_r[h * C_ + c];
        } else {
            w0[n] = rel_l[h * C_ + c];
            w1[n] = rel_r[h * C_ + c];
        }
    }
#pragma unroll
    for (int m = 0; m < 4; m++) {
#pragma unroll
        for (int q = 0; q < 4; q++) {
            int grow = bm + wr * 64 + m * 16 + (lane >> 4) * 4 + q;
            bool ok = grow < Mrows;
            float p0 = 0.f, p1 = 0.f, p2 = 0.f;
#pragma unroll
            for (int n = 0; n < 4; n++) {
                float v = acc[m][n][q] + bv[n];
                if (ok) {
                    if (sel == 0) {
                        lout[(size_t)grow * 256 + gcol[n]] = f2b(v);
                    } else {
                        if (RB16) ((unsigned short*)rout)[(size_t)grow * 256 + gcol[n]] = f2b(v);
                        else      ((float*)rout)[(size_t)grow * 256 + gcol[n]] = v;
                    }
                }
                if (sel == 0) {
                    float lr = lrelu(v);
                    p0 = fmaf(lr, w0[n], p0);
                    p1 = fmaf(lr, w1[n], p1);
                    p2 = fmaf(v, w2[n], p2);
                } else {
                    p0 = fmaf(v, w0[n], p0);
                    p1 = fmaf(v, w1[n], p1);
                }
            }
#pragma unroll
            for (int off = 1; off < 16; off <<= 1) {
                p0 += __shfl_xor(p0, off);
                p1 += __shfl_xor(p1, off);
                if (sel == 0) p2 += __shfl_xor(p2, off);
            }
            if (ok && (lane & 15) == 0) {
                int nh = grow * H_ + h;
                if (sel == 0) {
                    float e0 = __expf(p0), e1 = __expf(p1);
                    ej2[nh]      = make_float2(e0, e0 * p2);
                    ej2[NH + nh] = make_float2(e1, e1 * p2);
                } else {
                    al[nh] = p0;
                    rd[nh] = p1;
                }
            }
        }
    }
}

// ---------- CSR build: 2-kernel exclusive scan (block sums folded downstream) ----------
__global__ __launch_bounds__(256) void scan_a(
    const int* __restrict__ hist, int* __restrict__ segoff,
    int* __restrict__ bsum, int Nn)
{
    int m = blockIdx.y;
    int gid = blockIdx.x * 256 + threadIdx.x;
    int lane = threadIdx.x & 63, wid = threadIdx.x >> 6;
    int v = (gid < Nn) ? hist[m * Nn + gid] : 0;
    int incl = v;
#pragma unroll
    for (int off = 1; off < 64; off <<= 1) {
        int u = __shfl_up(incl, off);
        if (lane >= off) incl += u;
    }
    __shared__ int ws[4], wo[4];
    if (lane == 63) ws[wid] = incl;
    __syncthreads();
    if (threadIdx.x == 0) {
        int run = 0;
#pragma unroll
        for (int i = 0; i < 4; i++) { wo[i] = run; run += ws[i]; }
        bsum[m * 512 + blockIdx.x] = run;
    }
    __syncthreads();
    if (gid < Nn) segoff[m * Nn + gid] = incl - v + wo[wid];
}

__global__ __launch_bounds__(512) void scan_b(int* __restrict__ bsum, int nb)
{
    int m = blockIdx.x;
    int* b = bsum + m * 512;
    int tid = threadIdx.x, lane = tid & 63, wid = tid >> 6;
    int v = (tid < nb) ? b[tid] : 0;
    int incl = v;
#pragma unroll
    for (int off = 1; off < 64; off <<= 1) {
        int u = __shfl_up(incl, off);
        if (lane >= off) incl += u;
    }
    __shared__ int ws[8], wo[8];
    if (lane == 63) ws[wid] = incl;
    __syncthreads();
    if (tid == 0) {
        int run = 0;
#pragma unroll
        for (int i = 0; i < 8; i++) { wo[i] = run; run += ws[i]; }
    }
    __syncthreads();
    if (tid < nb) b[tid] = incl - v + wo[wid];
}

// ---------- CSR build: scatter (adds bsum inline) ----------
__global__ __launch_bounds__(256) void edge_scatter(
    const int* __restrict__ ei0, const int* __restrict__ ei1,
    const int* __restrict__ segoff, const int* __restrict__ bsum,
    int* __restrict__ cursor, int* __restrict__ srcs, int E_, int Nn)
{
    int e = blockIdx.x * 256 + threadIdx.x;
    if (e >= E_) return;
    int t0 = ei0[E_ + e];
    int p0 = segoff[t0] + bsum[t0 >> 8] + atomicAdd(&cursor[t0], 1);
    srcs[p0] = ei0[e];
    int t1 = ei1[E_ + e];
    int p1 = segoff[Nn + t1] + bsum[512 + (t1 >> 8)] + atomicAdd(&cursor[Nn + t1], 1);
    srcs[E_ + p1] = ei1[e];
}

// ---------- single-pass aggregation: wave per target, dual accumulators ----------
template <bool RB16>
__global__ __launch_bounds__(256) void aggregate(
    const int* __restrict__ hist, const int* __restrict__ segoff,
    const int* __restrict__ bsum,
    const int* __restrict__ srcs, const float2* __restrict__ ej2,
    const float* __restrict__ al, const float* __restrict__ rd,
    const void* __restrict__ rv, const unsigned short* __restrict__ l,
    float* __restrict__ out, int Nn, int E_)
{
    int lane = threadIdx.x & 63;
    int t = blockIdx.x * 4 + (threadIdx.x >> 6);
    if (t >= Nn) return;
    int h = lane >> 4;
    int NH = Nn * H_;
    int nh = t * H_ + h;

    // issue these early: consumed only after the edge loops
    float4 rrow;
    if (RB16) {
        ushort4 ru = ((const ushort4*)rv)[(size_t)t * 64 + lane];
        rrow = make_float4(b2f(ru.x), b2f(ru.y), b2f(ru.z), b2f(ru.w));
    } else {
        rrow = ((const float4*)rv)[(size_t)t * 64 + lane];
    }
    float a = al[nh];
    float rdv = rd[nh];

    float4 accm[2];
    float denm[2], pnm[2];
#pragma unroll
    for (int m = 0; m < 2; m++) {
        const int* sp = srcs + (size_t)m * E_;
        const float2* ep = ej2 + (size_t)m * NH;
        int beg = segoff[m * Nn + t] + bsum[m * 512 + (t >> 8)];
        int deg = hist[m * Nn + t];

        float4 aA = make_float4(0.f, 0.f, 0.f, 0.f);
        float4 aB = make_float4(0.f, 0.f, 0.f, 0.f);
        float dA = 0.f, dB = 0.f, pA = 0.f, pB = 0.f;
        int j = 0;
#pragma unroll 2
        for (; j + 1 < deg; j += 2) {
            int s0 = sp[beg + j];
            int s1 = sp[beg + j + 1];
            float2 v0 = ep[(size_t)s0 * H_ + h];
            float2 v1 = ep[(size_t)s1 * H_ + h];
            ushort4 l0 = *(const ushort4*)&l[(size_t)s0 * D_ + lane * 4];
            ushort4 l1 = *(const ushort4*)&l[(size_t)s1 * D_ + lane * 4];
            dA += v0.x; pA += v0.y;
            dB += v1.x; pB += v1.y;
            aA.x = fmaf(b2f(l0.x), v0.x, aA.x);
            aA.y = fmaf(b2f(l0.y), v0.x, aA.y);
            aA.z = fmaf(b2f(l0.z), v0.x, aA.z);
            aA.w = fmaf(b2f(l0.w), v0.x, aA.w);
            aB.x = fmaf(b2f(l1.x), v1.x, aB.x);
            aB.y = fmaf(b2f(l1.y), v1.x, aB.y);
            aB.z = fmaf(b2f(l1.z), v1.x, aB.z);
            aB.w = fmaf(b2f(l1.w), v1.x, aB.w);
        }
        if (j < deg) {
            int s0 = sp[beg + j];
            float2 v0 = ep[(size_t)s0 * H_ + h];
            ushort4 l0 = *(const ushort4*)&l[(size_t)s0 * D_ + lane * 4];
            dA += v0.x; pA += v0.y;
            aA.x = fmaf(b2f(l0.x), v0.x, aA.x);
            aA.y = fmaf(b2f(l0.y), v0.x, aA.y);
            aA.z = fmaf(b2f(l0.z), v0.x, aA.z);
            aA.w = fmaf(b2f(l0.w), v0.x, aA.w);
        }
        accm[m] = make_float4(aA.x + aB.x, aA.y + aB.y, aA.z + aB.z, aA.w + aB.w);
        denm[m] = dA + dB;
        pnm[m] = pA + pB;
    }

    float b0 = lrelu(a + pnm[0] / (denm[0] + 1e-16f));
    float b1 = lrelu(a + pnm[1] / (denm[1] + 1e-16f));
    float b2 = lrelu(a + rdv);
    float mm = fmaxf(b0, fmaxf(b1, b2));
    float e0 = __expf(b0 - mm), e1 = __expf(b1 - mm), e2 = __expf(b2 - mm);
    float inv = 1.f / (e0 + e1 + e2);
    float wm0 = e0 * inv / (denm[0] + 1e-16f);
    float wm1 = e1 * inv / (denm[1] + 1e-16f);
    float b2v = e2 * inv;

    float4 o;
    o.x = fmaxf(fmaf(wm0, accm[0].x, fmaf(wm1, accm[1].x, b2v * rrow.x)), 0.f);
    o.y = fmaxf(fmaf(wm0, accm[0].y, fmaf(wm1, accm[1].y, b2v * rrow.y)), 0.f);
    o.z = fmaxf(fmaf(wm0, accm[0].z, fmaf(wm1, accm[1].z, b2v * rrow.z)), 0.f);
    o.w = fmaxf(fmaf(wm0, accm[0].w, fmaf(wm1, accm[1].w, b2v * rrow.w)), 0.f);
    *(float4*)&out[(size_t)t * D_ + lane * 4] = o;
}

extern "C" void kernel_launch(void* const* d_in, const int* in_sizes, int n_in,
                              void* d_out, int out_size, void* d_ws, size_t ws_size,
                              hipStream_t stream) {
    const float* x     = (const float*)d_in[0];
    const int*   ei0   = (const int*)d_in[1];
    const int*   ei1   = (const int*)d_in[2];
    const float* W_l   = (const float*)d_in[3];
    const float* b_l   = (const float*)d_in[4];
    const float* W_r   = (const float*)d_in[5];
    const float* b_r   = (const float*)d_in[6];
    const float* attn  = (const float*)d_in[7];
    const float* rel_l = (const float*)d_in[8];
    const float* rel_r = (const float*)d_in[9];
    float* out = (float*)d_out;

    const int Nn = in_sizes[0] / D_;        // 100000
    const int E_ = in_sizes[1] / 2;         // 800000
    const size_t ND = (size_t)Nn * D_;
    const int NH = Nn * H_;

    // ---- workspace layout (~70 MB base; +51 MB rb if it fits — proven) ----
    char* base = (char*)d_ws;
    unsigned short* l = (unsigned short*)base;      size_t off = ND * 2;
    float2* ej2  = (float2*)(base + off); off += (size_t)2 * NH * 8;  // [M][N][H]
    float* al    = (float*)(base + off);  off += (size_t)NH * 4;
    float* rd    = (float*)(base + off);  off += (size_t)NH * 4;
    int* hist    = (int*)(base + off);    off += (size_t)2 * Nn * 4;  // [M][Nn]
    int* cursor  = (int*)(base + off);    off += (size_t)2 * Nn * 4;
    int* segoff  = (int*)(base + off);    off += (size_t)2 * Nn * 4;
    int* bsum    = (int*)(base + off);    off += (size_t)1024 * 4;
    int* srcs    = (int*)(base + off);    off += (size_t)2 * E_ * 4;  // [M][E]
    unsigned short* Wb = (unsigned short*)(base + off); off += (size_t)2 * 65536 * 2;
    unsigned short* rb = (unsigned short*)(base + off);
    const bool rb16 = (ws_size >= off + ND * 2);
    void* r_any = rb16 ? (void*)rb : (void*)out;

    // zero hist + cursor (contiguous)
    hipMemsetAsync(hist, 0, (size_t)4 * Nn * 4, stream);

    convert_w<<<128, 256, 0, stream>>>(W_l, W_r, Wb);

    int rowTiles = (Nn + 127) / 128;   // 782
    int nblk = 4 * rowTiles;           // 3128 (divisible by 8)
    int eb = (E_ + 255) / 256;         // 3125 hist blocks ride along
    if (rb16)
        gemm_hist<true ><<<nblk + eb, 256, 0, stream>>>(
            x, Wb, b_l, b_r, attn, rel_l, rel_r, l, r_any, ej2, al, rd,
            ei0, ei1, hist, Nn, nblk, E_);
    else
        gemm_hist<false><<<nblk + eb, 256, 0, stream>>>(
            x, Wb, b_l, b_r, attn, rel_l, rel_r, l, r_any, ej2, al, rd,
            ei0, ei1, hist, Nn, nblk, E_);

    int nb = (Nn + 255) / 256;   // 391
    scan_a<<<dim3(nb, 2), 256, 0, stream>>>(hist, segoff, bsum, Nn);
    scan_b<<<2, 512, 0, stream>>>(bsum, nb);
    edge_scatter<<<eb, 256, 0, stream>>>(ei0, ei1, segoff, bsum, cursor, srcs, E_, Nn);

    if (rb16)
        aggregate<true ><<<(Nn + 3) / 4, 256, 0, stream>>>(
            hist, segoff, bsum, srcs, ej2, al, rd, r_any, l, out, Nn, E_);
    else
        aggregate<false><<<(Nn + 3) / 4, 256, 0, stream>>>(
            hist, segoff, bsum, srcs, ej2, al, rd, r_any, l, out, Nn, E_);
}

// Round 14
// 420.512 us; speedup vs baseline: 16.3074x; 1.0103x over previous
//
#include <hip/hip_runtime.h>
#include <hip/hip_bf16.h>
#include <math.h>

#define D_ 256
#define H_ 4
#define C_ 64

typedef __attribute__((ext_vector_type(8))) short short8;
typedef __attribute__((ext_vector_type(4))) float f32x4;

// ---------- helpers ----------
__device__ inline float lrelu(float v) { return v >= 0.f ? v : 0.2f * v; }

// bf16 bit helpers
__device__ inline unsigned short f2b(float f) {
    unsigned u = __float_as_uint(f);
    u = (u + 0x7FFFu + ((u >> 16) & 1u)) >> 16;   // round-to-nearest-even
    return (unsigned short)u;
}
__device__ inline float b2f(unsigned short u) {
    return __uint_as_float(((unsigned)u) << 16);
}

#define GLDS(src, dst) __builtin_amdgcn_global_load_lds(                      \
    (const __attribute__((address_space(1))) void*)(src),                     \
    (__attribute__((address_space(3))) void*)(dst), 16, 0, 0)

// ---------- W -> bf16 ----------
__global__ __launch_bounds__(256) void convert_w(
    const float* __restrict__ Wl, const float* __restrict__ Wr,
    unsigned short* __restrict__ Wb)
{
    int i4 = blockIdx.x * 256 + threadIdx.x;          // 0..32767 float4s
    float4 v = (i4 < 16384) ? ((const float4*)Wl)[i4]
                            : ((const float4*)Wr)[i4 - 16384];
    ushort4 u;
    u.x = f2b(v.x); u.y = f2b(v.y); u.z = f2b(v.z); u.w = f2b(v.w);
    ((ushort4*)Wb)[i4] = u;
}

// ---------- staging ----------
// A: f32 via global_load_lds (GLDS) — proven path (rounds 4-11; gemm never in
// top-5). Reg-staged A (r12-13) regressed: mid-loop vmcnt drain serialized
// each K-step on global latency (MfmaUtil 5.7%, occ 29%, 185us).
__device__ __forceinline__ void stage_a(const float* __restrict__ x, float* dst,
                                        int bm, int k0, int wv, int lane, int Mrows)
{
#pragma unroll
    for (int p = 0; p < 4; p++) {
        int ci = (p * 4 + wv) * 64 + lane;            // chunk 0..1023
        int row = ci >> 3, cc = ci & 7;
        int gr = bm + row; if (gr >= Mrows) gr = Mrows - 1;
        const float* src = x + (size_t)gr * 256 + k0 + ((cc ^ (row & 7)) << 2);
        GLDS(src, (char*)dst + (size_t)(p * 4 + wv) * 1024);
    }
}
// B: bank-independent swizzle (col>>1)&3 — (col&1 bank-half, slot) independent
// -> 2-way max on b128 reads (free, m136).
__device__ __forceinline__ void stage_b(const unsigned short* __restrict__ W,
                                        unsigned short* dst, int bn, int k0,
                                        int wv, int lane)
{
#pragma unroll
    for (int p = 0; p < 2; p++) {
        int ci = (p * 4 + wv) * 64 + lane;            // chunk 0..511
        int col = ci >> 2, cc = ci & 3;
        const unsigned short* src = W + (size_t)(bn + col) * 256 + k0 +
                                    ((cc ^ ((col >> 1) & 3)) << 3);
        GLDS(src, (char*)dst + (size_t)(p * 4 + wv) * 1024);
    }
}

// ---------- MFMA GEMM (fused logits epilogue) + edge_hist heterogeneous blocks ----------
template <bool RB16>
__global__ __launch_bounds__(256) void gemm_hist(
    const float* __restrict__ x, const unsigned short* __restrict__ Wb,
    const float* __restrict__ b_l, const float* __restrict__ b_r,
    const float* __restrict__ attn, const float* __restrict__ rel_l,
    const float* __restrict__ rel_r,
    unsigned short* __restrict__ lout, void* __restrict__ rout,
    float2* __restrict__ ej2, float* __restrict__ al, float* __restrict__ rd,
    const int* __restrict__ ei0, const int* __restrict__ ei1,
    int* __restrict__ hist,
    int Mrows, int nblk, int E_)
{
    const int tid = threadIdx.x;

    // ---- heterogeneous tail: edge histogram ----
    if ((int)blockIdx.x >= nblk) {
        int e = ((int)blockIdx.x - nblk) * 256 + tid;
        if (e < E_) {
            atomicAdd(&hist[ei0[E_ + e]], 1);
            atomicAdd(&hist[Mrows + ei1[E_ + e]], 1);
        }
        return;
    }

    int hw = blockIdx.x;
    int orig = hw;
    if ((nblk & 7) == 0) {                 // bijective chunked XCD swizzle
        int cpx = nblk >> 3;
        orig = (hw & 7) * cpx + (hw >> 3);
    }
    const int sel = (orig & 3) >> 1;       // 0 = l, 1 = r
    const int bn = (orig & 1) * 128;
    const int bm = (orig >> 2) * 128;

    __shared__ float As[2][128 * 32];
    __shared__ unsigned short Bs[2][128 * 32];
    const int lane = tid & 63, wv = tid >> 6;
    const int wr = wv >> 1, wc = wv & 1;
    const unsigned short* W = Wb + (size_t)sel * 65536;

    f32x4 acc[4][4];
#pragma unroll
    for (int m = 0; m < 4; m++)
#pragma unroll
        for (int n = 0; n < 4; n++) acc[m][n] = (f32x4)0.f;

    stage_a(x, As[0], bm, 0, wv, lane, Mrows);
    stage_b(W, Bs[0], bn, 0, wv, lane);
    __syncthreads();

    int cur = 0;
#pragma unroll
    for (int t = 0; t < 8; t++) {
        if (t < 7) {
            stage_a(x, As[cur ^ 1], bm, (t + 1) * 32, wv, lane, Mrows);
            stage_b(W, Bs[cur ^ 1], bn, (t + 1) * 32, wv, lane);
        }
        short8 bfr[4];
#pragma unroll
        for (int n = 0; n < 4; n++) {
            int col = wc * 64 + n * 16 + (lane & 15);
            int sc = (lane >> 4) ^ ((col >> 1) & 3);
            bfr[n] = *(const short8*)&Bs[cur][col * 32 + sc * 8];
        }
        short8 afr[4];
#pragma unroll
        for (int m = 0; m < 4; m++) {
            int row = wr * 64 + m * 16 + (lane & 15);
            int c0 = (lane >> 4) * 2;
            const float* ap = &As[cur][row * 32];
            float4 f0 = *(const float4*)&ap[(c0 ^ (row & 7)) << 2];
            float4 f1 = *(const float4*)&ap[((c0 + 1) ^ (row & 7)) << 2];
            union { short8 v; __hip_bfloat162 b2[4]; } u;
            u.b2[0] = __float22bfloat162_rn(make_float2(f0.x, f0.y));
            u.b2[1] = __float22bfloat162_rn(make_float2(f0.z, f0.w));
            u.b2[2] = __float22bfloat162_rn(make_float2(f1.x, f1.y));
            u.b2[3] = __float22bfloat162_rn(make_float2(f1.z, f1.w));
            afr[m] = u.v;
        }
#pragma unroll
        for (int m = 0; m < 4; m++)
#pragma unroll
            for (int n = 0; n < 4; n++)
                acc[m][n] = __builtin_amdgcn_mfma_f32_16x16x32_bf16(
                    afr[m], bfr[n], acc[m][n], 0, 0, 0);
        __syncthreads();
        cur ^= 1;
    }

    // ---- fused epilogue: stores + per-node logit partials ----
    const float* bias = sel ? b_r : b_l;
    const int NH = Mrows * H_;
    const int h = (bn >> 6) + wc;          // this wave's head
    float bv[4], w0[4], w1[4], w2[4];
    int gcol[4];
#pragma unroll
    for (int n = 0; n < 4; n++) {
        int c = n * 16 + (lane & 15);
        gcol[n] = bn + wc * 64 + c;
        bv[n] = bias[gcol[n]];
        if (sel == 0) {
            w0[n] = attn[(0 * H_ + h) * 128 + 64 + c];
            w1[n] = attn[(1 * H_ + h) * 128 + 64 + c];
            w2[n] = rel_r[h * C_ + c];
        } else {
            w0[n] = rel_l[h * C_ + c];
            w1[n] = rel_r[h * C_ + c];
        }
    }
#pragma unroll
    for (int m = 0; m < 4; m++) {
#pragma unroll
        for (int q = 0; q < 4; q++) {
            int grow = bm + wr * 64 + m * 16 + (lane >> 4) * 4 + q;
            bool ok = grow < Mrows;
            float p0 = 0.f, p1 = 0.f, p2 = 0.f;
#pragma unroll
            for (int n = 0; n < 4; n++) {
                float v = acc[m][n][q] + bv[n];
                if (ok) {
                    if (sel == 0) {
                        lout[(size_t)grow * 256 + gcol[n]] = f2b(v);
                    } else {
                        if (RB16) ((unsigned short*)rout)[(size_t)grow * 256 + gcol[n]] = f2b(v);
                        else      ((float*)rout)[(size_t)grow * 256 + gcol[n]] = v;
                    }
                }
                if (sel == 0) {
                    float lr = lrelu(v);
                    p0 = fmaf(lr, w0[n], p0);
                    p1 = fmaf(lr, w1[n], p1);
                    p2 = fmaf(v, w2[n], p2);
                } else {
                    p0 = fmaf(v, w0[n], p0);
                    p1 = fmaf(v, w1[n], p1);
                }
            }
#pragma unroll
            for (int off = 1; off < 16; off <<= 1) {
                p0 += __shfl_xor(p0, off);
                p1 += __shfl_xor(p1, off);
                if (sel == 0) p2 += __shfl_xor(p2, off);
            }
            if (ok && (lane & 15) == 0) {
                int nh = grow * H_ + h;
                if (sel == 0) {
                    float e0 = __expf(p0), e1 = __expf(p1);
                    ej2[nh]      = make_float2(e0, e0 * p2);
                    ej2[NH + nh] = make_float2(e1, e1 * p2);
                } else {
                    al[nh] = p0;
                    rd[nh] = p1;
                }
            }
        }
    }
}

// ---------- CSR build: 2-kernel exclusive scan (block sums folded downstream) ----------
__global__ __launch_bounds__(256) void scan_a(
    const int* __restrict__ hist, int* __restrict__ segoff,
    int* __restrict__ bsum, int Nn)
{
    int m = blockIdx.y;
    int gid = blockIdx.x * 256 + threadIdx.x;
    int lane = threadIdx.x & 63, wid = threadIdx.x >> 6;
    int v = (gid < Nn) ? hist[m * Nn + gid] : 0;
    int incl = v;
#pragma unroll
    for (int off = 1; off < 64; off <<= 1) {
        int u = __shfl_up(incl, off);
        if (lane >= off) incl += u;
    }
    __shared__ int ws[4], wo[4];
    if (lane == 63) ws[wid] = incl;
    __syncthreads();
    if (threadIdx.x == 0) {
        int run = 0;
#pragma unroll
        for (int i = 0; i < 4; i++) { wo[i] = run; run += ws[i]; }
        bsum[m * 512 + blockIdx.x] = run;
    }
    __syncthreads();
    if (gid < Nn) segoff[m * Nn + gid] = incl - v + wo[wid];
}

__global__ __launch_bounds__(512) void scan_b(int* __restrict__ bsum, int nb)
{
    int m = blockIdx.x;
    int* b = bsum + m * 512;
    int tid = threadIdx.x, lane = tid & 63, wid = tid >> 6;
    int v = (tid < nb) ? b[tid] : 0;
    int incl = v;
#pragma unroll
    for (int off = 1; off < 64; off <<= 1) {
        int u = __shfl_up(incl, off);
        if (lane >= off) incl += u;
    }
    __shared__ int ws[8], wo[8];
    if (lane == 63) ws[wid] = incl;
    __syncthreads();
    if (tid == 0) {
        int run = 0;
#pragma unroll
        for (int i = 0; i < 8; i++) { wo[i] = run; run += ws[i]; }
    }
    __syncthreads();
    if (tid < nb) b[tid] = incl - v + wo[wid];
}

// ---------- CSR build: scatter (adds bsum inline) ----------
__global__ __launch_bounds__(256) void edge_scatter(
    const int* __restrict__ ei0, const int* __restrict__ ei1,
    const int* __restrict__ segoff, const int* __restrict__ bsum,
    int* __restrict__ cursor, int* __restrict__ srcs, int E_, int Nn)
{
    int e = blockIdx.x * 256 + threadIdx.x;
    if (e >= E_) return;
    int t0 = ei0[E_ + e];
    int p0 = segoff[t0] + bsum[t0 >> 8] + atomicAdd(&cursor[t0], 1);
    srcs[p0] = ei0[e];
    int t1 = ei1[E_ + e];
    int p1 = segoff[Nn + t1] + bsum[512 + (t1 >> 8)] + atomicAdd(&cursor[Nn + t1], 1);
    srcs[E_ + p1] = ei1[e];
}

// ---------- single-pass aggregation: wave per target, dual accumulators ----------
template <bool RB16>
__global__ __launch_bounds__(256) void aggregate(
    const int* __restrict__ hist, const int* __restrict__ segoff,
    const int* __restrict__ bsum,
    const int* __restrict__ srcs, const float2* __restrict__ ej2,
    const float* __restrict__ al, const float* __restrict__ rd,
    const void* __restrict__ rv, const unsigned short* __restrict__ l,
    float* __restrict__ out, int Nn, int E_)
{
    int lane = threadIdx.x & 63;
    int t = blockIdx.x * 4 + (threadIdx.x >> 6);
    if (t >= Nn) return;
    int h = lane >> 4;
    int NH = Nn * H_;
    int nh = t * H_ + h;

    // issue these early: consumed only after the edge loops
    float4 rrow;
    if (RB16) {
        ushort4 ru = ((const ushort4*)rv)[(size_t)t * 64 + lane];
        rrow = make_float4(b2f(ru.x), b2f(ru.y), b2f(ru.z), b2f(ru.w));
    } else {
        rrow = ((const float4*)rv)[(size_t)t * 64 + lane];
    }
    float a = al[nh];
    float rdv = rd[nh];

    float4 accm[2];
    float denm[2], pnm[2];
#pragma unroll
    for (int m = 0; m < 2; m++) {
        const int* sp = srcs + (size_t)m * E_;
        const float2* ep = ej2 + (size_t)m * NH;
        int beg = segoff[m * Nn + t] + bsum[m * 512 + (t >> 8)];
        int deg = hist[m * Nn + t];

        float4 aA = make_float4(0.f, 0.f, 0.f, 0.f);
        float4 aB = make_float4(0.f, 0.f, 0.f, 0.f);
        float dA = 0.f, dB = 0.f, pA = 0.f, pB = 0.f;
        int j = 0;
#pragma unroll 2
        for (; j + 1 < deg; j += 2) {
            int s0 = sp[beg + j];
            int s1 = sp[beg + j + 1];
            float2 v0 = ep[(size_t)s0 * H_ + h];
            float2 v1 = ep[(size_t)s1 * H_ + h];
            ushort4 l0 = *(const ushort4*)&l[(size_t)s0 * D_ + lane * 4];
            ushort4 l1 = *(const ushort4*)&l[(size_t)s1 * D_ + lane * 4];
            dA += v0.x; pA += v0.y;
            dB += v1.x; pB += v1.y;
            aA.x = fmaf(b2f(l0.x), v0.x, aA.x);
            aA.y = fmaf(b2f(l0.y), v0.x, aA.y);
            aA.z = fmaf(b2f(l0.z), v0.x, aA.z);
            aA.w = fmaf(b2f(l0.w), v0.x, aA.w);
            aB.x = fmaf(b2f(l1.x), v1.x, aB.x);
            aB.y = fmaf(b2f(l1.y), v1.x, aB.y);
            aB.z = fmaf(b2f(l1.z), v1.x, aB.z);
            aB.w = fmaf(b2f(l1.w), v1.x, aB.w);
        }
        if (j < deg) {
            int s0 = sp[beg + j];
            float2 v0 = ep[(size_t)s0 * H_ + h];
            ushort4 l0 = *(const ushort4*)&l[(size_t)s0 * D_ + lane * 4];
            dA += v0.x; pA += v0.y;
            aA.x = fmaf(b2f(l0.x), v0.x, aA.x);
            aA.y = fmaf(b2f(l0.y), v0.x, aA.y);
            aA.z = fmaf(b2f(l0.z), v0.x, aA.z);
            aA.w = fmaf(b2f(l0.w), v0.x, aA.w);
        }
        accm[m] = make_float4(aA.x + aB.x, aA.y + aB.y, aA.z + aB.z, aA.w + aB.w);
        denm[m] = dA + dB;
        pnm[m] = pA + pB;
    }

    float b0 = lrelu(a + pnm[0] / (denm[0] + 1e-16f));
    float b1 = lrelu(a + pnm[1] / (denm[1] + 1e-16f));
    float b2 = lrelu(a + rdv);
    float mm = fmaxf(b0, fmaxf(b1, b2));
    float e0 = __expf(b0 - mm), e1 = __expf(b1 - mm), e2 = __expf(b2 - mm);
    float inv = 1.f / (e0 + e1 + e2);
    float wm0 = e0 * inv / (denm[0] + 1e-16f);
    float wm1 = e1 * inv / (denm[1] + 1e-16f);
    float b2v = e2 * inv;

    float4 o;
    o.x = fmaxf(fmaf(wm0, accm[0].x, fmaf(wm1, accm[1].x, b2v * rrow.x)), 0.f);
    o.y = fmaxf(fmaf(wm0, accm[0].y, fmaf(wm1, accm[1].y, b2v * rrow.y)), 0.f);
    o.z = fmaxf(fmaf(wm0, accm[0].z, fmaf(wm1, accm[1].z, b2v * rrow.z)), 0.f);
    o.w = fmaxf(fmaf(wm0, accm[0].w, fmaf(wm1, accm[1].w, b2v * rrow.w)), 0.f);
    *(float4*)&out[(size_t)t * D_ + lane * 4] = o;
}

extern "C" void kernel_launch(void* const* d_in, const int* in_sizes, int n_in,
                              void* d_out, int out_size, void* d_ws, size_t ws_size,
                              hipStream_t stream) {
    const float* x     = (const float*)d_in[0];
    const int*   ei0   = (const int*)d_in[1];
    const int*   ei1   = (const int*)d_in[2];
    const float* W_l   = (const float*)d_in[3];
    const float* b_l   = (const float*)d_in[4];
    const float* W_r   = (const float*)d_in[5];
    const float* b_r   = (const float*)d_in[6];
    const float* attn  = (const float*)d_in[7];
    const float* rel_l = (const float*)d_in[8];
    const float* rel_r = (const float*)d_in[9];
    float* out = (float*)d_out;

    const int Nn = in_sizes[0] / D_;        // 100000
    const int E_ = in_sizes[1] / 2;         // 800000
    const size_t ND = (size_t)Nn * D_;
    const int NH = Nn * H_;

    // ---- workspace layout (~70 MB base; +51 MB rb if it fits — proven) ----
    char* base = (char*)d_ws;
    unsigned short* l = (unsigned short*)base;      size_t off = ND * 2;
    float2* ej2  = (float2*)(base + off); off += (size_t)2 * NH * 8;  // [M][N][H]
    float* al    = (float*)(base + off);  off += (size_t)NH * 4;
    float* rd    = (float*)(base + off);  off += (size_t)NH * 4;
    int* hist    = (int*)(base + off);    off += (size_t)2 * Nn * 4;  // [M][Nn]
    int* cursor  = (int*)(base + off);    off += (size_t)2 * Nn * 4;
    int* segoff  = (int*)(base + off);    off += (size_t)2 * Nn * 4;
    int* bsum    = (int*)(base + off);    off += (size_t)1024 * 4;
    int* srcs    = (int*)(base + off);    off += (size_t)2 * E_ * 4;  // [M][E]
    unsigned short* Wb = (unsigned short*)(base + off); off += (size_t)2 * 65536 * 2;
    unsigned short* rb = (unsigned short*)(base + off);
    const bool rb16 = (ws_size >= off + ND * 2);
    void* r_any = rb16 ? (void*)rb : (void*)out;

    // zero hist + cursor (contiguous)
    hipMemsetAsync(hist, 0, (size_t)4 * Nn * 4, stream);

    convert_w<<<128, 256, 0, stream>>>(W_l, W_r, Wb);

    int rowTiles = (Nn + 127) / 128;   // 782
    int nblk = 4 * rowTiles;           // 3128 (divisible by 8)
    int eb = (E_ + 255) / 256;         // 3125 hist blocks ride along
    if (rb16)
        gemm_hist<true ><<<nblk + eb, 256, 0, stream>>>(
            x, Wb, b_l, b_r, attn, rel_l, rel_r, l, r_any, ej2, al, rd,
            ei0, ei1, hist, Nn, nblk, E_);
    else
        gemm_hist<false><<<nblk + eb, 256, 0, stream>>>(
            x, Wb, b_l, b_r, attn, rel_l, rel_r, l, r_any, ej2, al, rd,
            ei0, ei1, hist, Nn, nblk, E_);

    int nb = (Nn + 255) / 256;   // 391
    scan_a<<<dim3(nb, 2), 256, 0, stream>>>(hist, segoff, bsum, Nn);
    scan_b<<<2, 512, 0, stream>>>(bsum, nb);
    edge_scatter<<<eb, 256, 0, stream>>>(ei0, ei1, segoff, bsum, cursor, srcs, E_, Nn);

    if (rb16)
        aggregate<true ><<<(Nn + 3) / 4, 256, 0, stream>>>(
            hist, segoff, bsum, srcs, ej2, al, rd, r_any, l, out, Nn, E_);
    else
        aggregate<false><<<(Nn + 3) / 4, 256, 0, stream>>>(
            hist, segoff, bsum, srcs, ej2, al, rd, r_any, l, out, Nn, E_);
}